// Round 13
// baseline (512.986 us; speedup 1.0000x reference)
//
#include <hip/hip_runtime.h>
#include <hip/hip_fp16.h>
#include <math.h>

// ---------------------------------------------------------------------------
// NetGlobGATFix. R29: dispatch-count reduction (launch-gap recovery).
//   - pad_input deleted: conv3x3_first reads raw cf with boundary guards
//     (skip-vs-add-zero is fp-exact, term order preserved). memset now
//     covers c1p..c4p borders only.
//   - scan_blocks+scan_sums+scan_apply fused into one 1024-thread
//     single-block scan_all (10 elems/thread, static-indexed).
//   - Net -3 dispatches. Everything else identical to R28 (506.8us).
// ---------------------------------------------------------------------------

#define DEVFN static __device__ __forceinline__

typedef __attribute__((ext_vector_type(8))) _Float16 half8;
typedef __attribute__((ext_vector_type(4))) _Float16 half4v;
typedef __attribute__((ext_vector_type(4))) float f32x4;

DEVFN float selu_f(float v) {
    const float scale = 1.0507009873554805f;
    const float alpha = 1.6732632423543772f;
    return v > 0.f ? scale * v : scale * alpha * (expf(v) - 1.f);
}

DEVFN float lrelu02(float v) { return v > 0.f ? v : 0.2f * v; }

// ---------------- CNN (padded 66x66 layout) ----------------
#define PST 66
#define PSZ (66 * 66)

// first conv: reads raw 4x64x64 input with boundary guards, writes padded c1p
__global__ __launch_bounds__(256) void conv3x3_first(const float* __restrict__ cf,
                                                     const float* __restrict__ w,
                                                     const float* __restrict__ b,
                                                     float* __restrict__ out) {
    int x  = threadIdx.x & 63;
    int yg = threadIdx.x >> 6;
    int y  = blockIdx.x * 4 + yg;          // 0..63
    int co = blockIdx.y;
    float acc = b[co];
    const float* wp = w + (size_t)co * 4 * 9;
#pragma unroll
    for (int ci = 0; ci < 4; ++ci) {
        const float* ip = cf + ci * 4096;
        const float* wr = wp + ci * 9;
#pragma unroll
        for (int ky = 0; ky < 3; ++ky) {
            int yy = y + ky - 1;
            if (yy < 0 || yy >= 64) continue;
#pragma unroll
            for (int kx = 0; kx < 3; ++kx) {
                int xx = x + kx - 1;
                if (xx < 0 || xx >= 64) continue;
                acc += wr[ky * 3 + kx] * ip[yy * 64 + xx];
            }
        }
    }
    out[(size_t)co * PSZ + (y + 1) * PST + (x + 1)] = selu_f(acc);
}

template <int CIN>
__global__ __launch_bounds__(256) void conv3x3_pad(const float* __restrict__ in,
                                                   const float* __restrict__ w,
                                                   const float* __restrict__ b,
                                                   float* __restrict__ out) {
    int x  = threadIdx.x & 63;
    int yg = threadIdx.x >> 6;
    int y  = blockIdx.x * 4 + yg;          // 0..63
    int co = blockIdx.y;
    float acc = b[co];
    const float* wp = w + (size_t)co * CIN * 9;
#pragma unroll 4
    for (int ci = 0; ci < CIN; ++ci) {
        const float* ip = in + ci * PSZ + y * PST + x;
        const float* wr = wp + ci * 9;
        acc += wr[0] * ip[0]           + wr[1] * ip[1]           + wr[2] * ip[2]
             + wr[3] * ip[PST]         + wr[4] * ip[PST + 1]     + wr[5] * ip[PST + 2]
             + wr[6] * ip[2 * PST]     + wr[7] * ip[2 * PST + 1] + wr[8] * ip[2 * PST + 2];
    }
    out[(size_t)co * PSZ + (y + 1) * PST + (x + 1)] = selu_f(acc);
}

__global__ void avgpool_c(const float* __restrict__ in, float* __restrict__ gfeat) {
    int c = blockIdx.x;            // 24 blocks
    int t = threadIdx.x;           // 256 threads
    float s = 0.f;
    for (int i = t; i < 4096; i += 256) {
        int y = i >> 6, x = i & 63;
        s += in[c * PSZ + (y + 1) * PST + (x + 1)];
    }
#pragma unroll
    for (int off = 32; off >= 1; off >>= 1) s += __shfl_xor(s, off);
    __shared__ float red[4];
    int wave = t >> 6, lane = t & 63;
    if (lane == 0) red[wave] = s;
    __syncthreads();
    if (t == 0) gfeat[c] = (red[0] + red[1] + red[2] + red[3]) * (1.f / 4096.f);
}

// ---------------- node feature init (padded to 64 ch, fp16) + masks ---------
__global__ void build_h0(const float* __restrict__ x, const float* __restrict__ gfeat,
                         __half* __restrict__ h0f, unsigned* __restrict__ masks, int N) {
    int n = blockIdx.x * blockDim.x + threadIdx.x;
    if (n >= N) return;
    float x0 = x[n * 10 + 0], x1 = x[n * 10 + 1];
    unsigned mk = (x0 == 1.f ? 1u : 0u) | (x0 == 0.f ? 2u : 0u) |
                  (x1 == 0.f ? 4u : 0u) | (x1 == 1.f ? 8u : 0u);
    masks[n] = mk;
    __half* hq = h0f + (size_t)n * 64;
#pragma unroll
    for (int j = 0; j < 64; ++j) {
        float v = (j < 24) ? gfeat[j] : (j < 34 ? x[n * 10 + (j - 24)] : 0.f);
        hq[j] = __float2half(v);
    }
}

// ---------------- CSR build ----------------
__global__ void count_dst(const int* __restrict__ ei, int* __restrict__ cnt, int E, int N) {
    int t = blockIdx.x * blockDim.x + threadIdx.x;
    if (t >= E + N) return;
    int dst = (t < E) ? ei[E + t] : (t - E);
    atomicAdd(&cnt[dst], 1);
}

// single-block exclusive scan over n<=10240 counts (10 elems/thread, 1024 thr)
__global__ __launch_bounds__(1024) void scan_all(const int* __restrict__ cnt,
                                                 int* __restrict__ indptr,
                                                 int* __restrict__ cursor,
                                                 int n, int total) {
    __shared__ int sdata[1024];
    int t = threadIdx.x;
    int base = t * 10;
    int loc[10];
    int s = 0;
#pragma unroll
    for (int i = 0; i < 10; ++i) {
        int idx = base + i;
        int v = (idx < n) ? cnt[idx] : 0;
        loc[i] = s;                     // exclusive prefix within thread
        s += v;
    }
    sdata[t] = s;
    __syncthreads();
    for (int off = 1; off < 1024; off <<= 1) {
        int tmp = (t >= off) ? sdata[t - off] : 0;
        __syncthreads();
        sdata[t] += tmp;
        __syncthreads();
    }
    int excl = (t == 0) ? 0 : sdata[t - 1];
#pragma unroll
    for (int i = 0; i < 10; ++i) {
        int idx = base + i;
        if (idx < n) {
            int e = excl + loc[i];
            indptr[idx] = e;
            cursor[idx] = e;
        }
    }
    if (t == 0) indptr[n] = total;
}

__global__ void scatter_edges(const int* __restrict__ ei, int* __restrict__ cursor,
                              int* __restrict__ col, int E, int N) {
    int t = blockIdx.x * blockDim.x + threadIdx.x;
    if (t >= E + N) return;
    int src, dst;
    if (t < E) { src = ei[t]; dst = ei[E + t]; }
    else       { src = dst = t - E; }
    int pos = atomicAdd(&cursor[dst], 1);
    col[pos] = src;
}

// ---------------- fused one-shot weight prep --------------------------------
// bt layout per layer: bt[btOff + m*KA + h*Kp + k] = fp16(W[k*HC + h*C + m])
// wesed[weOff + k*2H + o] = sum_c W[k,h*C+c]*a[h,c]  (h=o%H, a=as/ad by o<H).
// wcomb (layer 4, 128x64): cols 0..31 = es/ed weights, cols 32..63 = W4 cols.
__global__ __launch_bounds__(256) void prep_all(
        const float* __restrict__ W0, const float* __restrict__ W1,
        const float* __restrict__ W2, const float* __restrict__ W3,
        const float* __restrict__ W4,
        const float* __restrict__ as0, const float* __restrict__ as1,
        const float* __restrict__ as2, const float* __restrict__ as3,
        const float* __restrict__ as4,
        const float* __restrict__ ad0, const float* __restrict__ ad1,
        const float* __restrict__ ad2, const float* __restrict__ ad3,
        const float* __restrict__ ad4,
        unsigned short* __restrict__ bt, float* __restrict__ wesed,
        float* __restrict__ wcomb) {
    const int Kc[5]  = {34, 64, 128, 256, 128};
    const int Kpc[5] = {64, 64, 128, 256, 128};        // L0 padded to 64
    const int Hc[5]  = {8, 16, 8, 8, 16};
    const int Cc[5]  = {64, 128, 256, 128, 2};
    const int HCc[5] = {512, 2048, 2048, 1024, 32};
    const int KAc[5] = {512, 1024, 1024, 2048, 2048};  // L0 KA = 8*64
    const int btOff[5] = {0, 32768, 163840, 425984, 0};
    const int weOff[5] = {0, 1024, 3072, 5120, 9216};

    int b = blockIdx.x, tid = threadIdx.x;

    if (b < 168) {
        // ---- LDS-tiled transpose, one (layer, head, 64x64 tile) per block --
        int lyr, tloc;
        if (b < 8)        { lyr = 0; tloc = b; }
        else if (b < 40)  { lyr = 1; tloc = b - 8; }
        else if (b < 104) { lyr = 2; tloc = b - 40; }
        else              { lyr = 3; tloc = b - 104; }
        const int ktl[4] = {1, 1, 2, 4};   // ceil(Kp/64)
        const int mtl[4] = {1, 2, 4, 2};   // ceil(C/64)
        int kt = ktl[lyr], mt = mtl[lyr];
        int per_h = kt * mt;
        int h = tloc / per_h, r = tloc - h * per_h;
        int ki = r % kt, mi = r / kt;
        int k0 = ki * 64, m0 = mi * 64;
        int K = Kc[lyr], Kp = Kpc[lyr], C = Cc[lyr], HC = HCc[lyr], KA = KAc[lyr];
        const float* W;
        if (lyr == 0) W = W0; else if (lyr == 1) W = W1;
        else if (lyr == 2) W = W2; else W = W3;

        __shared__ float tile[64][65];
        int c = tid & 63, rg = tid >> 6;
        for (int r2 = rg; r2 < 64; r2 += 4) {       // coalesced 256B reads
            int k = k0 + r2, m = m0 + c;
            float v = (k < K && m < C) ? W[(size_t)k * HC + h * C + m] : 0.f;
            tile[r2][c] = v;
        }
        __syncthreads();
        unsigned short* bp = bt + btOff[lyr];
        for (int mr = rg; mr < 64; mr += 4) {       // coalesced 128B fp16 writes
            int m = m0 + mr, k = k0 + c;
            if (m < C && k < Kp)
                bp[(size_t)m * KA + h * Kp + k] =
                    __half_as_ushort(__float2half(tile[c][mr]));
        }
    } else if (b < 200) {
        // ---- wcomb for layer 4: 8192 outputs (128 x 64) ----
        int u = (b - 168) * 256 + tid;
        int k = u >> 6, o = u & 63;
        float s;
        if (o < 32) {                       // es/ed weights
            int h = (o < 16) ? o : o - 16;
            const float* av = ((o < 16) ? as4 : ad4) + h * 2;
            s = W4[k * 32 + h * 2 + 0] * av[0] + W4[k * 32 + h * 2 + 1] * av[1];
        } else {                            // y projection: raw W4 column
            s = W4[k * 32 + (o - 32)];
        }
        wcomb[u] = s;
    } else {
        // ---- wesed dots: sizes {1024,2048,2048,4096,4096} -> 52 blocks ----
        int wb = b - 200;
        int lyr, u0;
        if (wb < 4)       { lyr = 0; u0 = wb * 256; }
        else if (wb < 12) { lyr = 1; u0 = (wb - 4) * 256; }
        else if (wb < 20) { lyr = 2; u0 = (wb - 12) * 256; }
        else if (wb < 36) { lyr = 3; u0 = (wb - 20) * 256; }
        else              { lyr = 4; u0 = (wb - 36) * 256; }
        int u = u0 + tid;
        int K = Kc[lyr], Kp = Kpc[lyr], H = Hc[lyr], C = Cc[lyr], HC = HCc[lyr];
        int H2 = 2 * H;
        if (u < Kp * H2) {
            int k = u / H2, o = u - k * H2;
            float s = 0.f;
            if (k < K) {
                int h = (o < H) ? o : o - H;
                const float *W, *as_, *ad_;
                if (lyr == 0)      { W = W0; as_ = as0; ad_ = ad0; }
                else if (lyr == 1) { W = W1; as_ = as1; ad_ = ad1; }
                else if (lyr == 2) { W = W2; as_ = as2; ad_ = ad2; }
                else if (lyr == 3) { W = W3; as_ = as3; ad_ = ad3; }
                else               { W = W4; as_ = as4; ad_ = ad4; }
                const float* av = ((o < H) ? as_ : ad_) + h * C;
                const float* wp = W + (size_t)k * HC + h * C;
#pragma unroll 4
                for (int c2 = 0; c2 < C; ++c2) s += wp[c2] * av[c2];
            }
            wesed[weOff[lyr] + u] = s;
        }
    }
}

// ---------------- es/ed (and eyp): out[n,o] = hin16[n,:] @ w[:,o] -----------
__global__ void esed_kernel(const __half* __restrict__ hin, const float* __restrict__ wesed,
                            float* __restrict__ esed, int N, int Kp, int H2) {
    int t = blockIdx.x * blockDim.x + threadIdx.x;
    if (t >= N * H2) return;
    int n = t / H2, o = t - n * H2;
    const __half2* hp = (const __half2*)(hin + (size_t)n * Kp);
    float s = 0.f;
    for (int k2 = 0; k2 < Kp / 2; ++k2) {
        float2 f = __half22float2(hp[k2]);
        s += f.x * wesed[(2 * k2) * H2 + o] + f.y * wesed[(2 * k2 + 1) * H2 + o];
    }
    esed[t] = s;
}

// -------- fused attn+gather via LDS broadcast, pipelined (layers 0-3) -------
template <int H, int KP, int CH, int NPB>
__global__ __launch_bounds__(NPB * (KP / CH)) void gat_fused_lds(
        const __half* __restrict__ hinf, const float* __restrict__ esed,
        const int* __restrict__ indptr, const int* __restrict__ col,
        __half* __restrict__ g, int N) {
    const int TPN = KP / CH;
    const int EC  = TPN / H;
    const int H2  = 2 * H;
    __shared__ float lds_p[NPB][2][TPN];
    int sub = threadIdx.x / TPN;
    int j   = threadIdx.x % TPN;
    int n = blockIdx.x * NPB + sub;
    if (n >= N) return;
    int e_my = j / H, h_my = j % H;
    int c0 = j * CH;
    float edv = esed[n * H2 + H + h_my];

    float acc[H][CH];
#pragma unroll
    for (int h = 0; h < H; ++h)
#pragma unroll
        for (int t = 0; t < CH; ++t) acc[h][t] = 0.f;
    float zloc = 0.f;

    int beg = indptr[n], deg = indptr[n + 1] - beg;

    // prologue: p for chunk 0
    float p = 0.f;
    if (e_my < deg) {
        int srcm = col[beg + e_my];
        p = expf(lrelu02(esed[srcm * H2 + h_my] + edv));
    }
    int buf = 0;
    for (int base = 0; base < deg; base += EC) {
        zloc += p;
        lds_p[sub][buf][j] = p;
        __builtin_amdgcn_wave_barrier();
        // issue next chunk's attention loads (exp after phase B)
        int ce = base + EC + e_my;
        bool vnext = (ce < deg);
        float esv = 0.f;
        if (vnext) {
            int srcm = col[beg + ce];
            esv = esed[srcm * H2 + h_my];
        }
        // phase B: pipelined gather with LDS-broadcast alphas
#pragma unroll
        for (int e = 0; e < EC; ++e) {
            int idx = base + e;
            if (idx < deg) {                  // uniform within node group
                int src = col[beg + idx];
                float f[CH];
                if (CH == 2) {
                    __half2 hv = *(const __half2*)(hinf + (size_t)src * KP + c0);
                    float2 ff = __half22float2(hv);
                    f[0] = ff.x; f[1] = ff.y;
                } else {
                    half4v hv = *(const half4v*)(hinf + (size_t)src * KP + c0);
                    f[0] = (float)hv[0]; f[1] = (float)hv[1];
                    f[2] = (float)hv[2]; f[3] = (float)hv[3];
                }
                const float4* ap = (const float4*)&lds_p[sub][buf][e * H];
#pragma unroll
                for (int q4 = 0; q4 < H / 4; ++q4) {
                    float4 a4 = ap[q4];
#pragma unroll
                    for (int t = 0; t < CH; ++t) {
                        acc[4 * q4 + 0][t] += a4.x * f[t];
                        acc[4 * q4 + 1][t] += a4.y * f[t];
                        acc[4 * q4 + 2][t] += a4.z * f[t];
                        acc[4 * q4 + 3][t] += a4.w * f[t];
                    }
                }
            }
        }
        p = vnext ? expf(lrelu02(esv + edv)) : 0.f;
        buf ^= 1;
    }

    // z: reduce across the EC lanes of each head class
#pragma unroll
    for (int off = H; off < TPN; off <<= 1)
        zloc += __shfl_xor(zloc, off, TPN);
    float zinv_my = (1.f / H) / (zloc + 1e-16f);

    __half* gp = g + (size_t)n * (H * KP) + c0;
#pragma unroll
    for (int h = 0; h < H; ++h) {
        float zf = __shfl(zinv_my, h, TPN);   // lane class h holds z for head h
        if (CH == 2) {
            *(__half2*)(gp + h * KP) =
                __floats2half2_rn(acc[h][0] * zf, acc[h][1] * zf);
        } else {
            __half2 lo = __floats2half2_rn(acc[h][0] * zf, acc[h][1] * zf);
            __half2 hi = __floats2half2_rn(acc[h][2] * zf, acc[h][3] * zf);
            union { __half2 h2[2]; float2 f2; } u;
            u.h2[0] = lo; u.h2[1] = hi;
            *(float2*)(gp + h * KP) = u.f2;
        }
    }
}

// -------- layer 4: fused attention + projected gather + output --------------
template <int NPB>
__global__ __launch_bounds__(NPB * 32) void final_attn(
        const float* __restrict__ eyp, const int* __restrict__ indptr,
        const int* __restrict__ col, const float* __restrict__ b5,
        const unsigned* __restrict__ masks, const float* __restrict__ x,
        float* __restrict__ outp, int N) {
    int sub = threadIdx.x >> 5;
    int j   = threadIdx.x & 31;
    int n = blockIdx.x * NPB + sub;
    if (n >= N) return;
    int h = j >> 1;
    float edv = eyp[(size_t)n * 64 + 16 + h];
    int beg = indptr[n], end = indptr[n + 1];
    float z = 0.f, a = 0.f;
    int i = beg;
    for (; i + 1 < end; i += 2) {
        int s0 = col[i], s1 = col[i + 1];
        const float* r0 = eyp + (size_t)s0 * 64;
        const float* r1 = eyp + (size_t)s1 * 64;
        float es0 = r0[h], y0 = r0[32 + j];
        float es1 = r1[h], y1 = r1[32 + j];
        float p0 = expf(lrelu02(es0 + edv));
        float p1 = expf(lrelu02(es1 + edv));
        z += p0; a += p0 * y0;
        z += p1; a += p1 * y1;
    }
    for (; i < end; ++i) {
        const float* r = eyp + (size_t)col[i] * 64;
        float p = expf(lrelu02(r[h] + edv));
        z += p; a += p * r[32 + j];
    }
    float zf = (1.f / 16.f) / (z + 1e-16f);
    float val = a * zf;
#pragma unroll
    for (int off = 2; off <= 16; off <<= 1) val += __shfl_xor(val, off, 32);
    float other = __shfl_xor(val, 1, 32);        // opposite parity's sum
    if (j == 0) {
        unsigned mk = masks[n];
        float v0 = x[n * 10 + 0] + selu_f(val + b5[0]);
        float v1 = x[n * 10 + 1] + selu_f(other + b5[1]);
        if (mk & 2u) v0 = 0.f; else if (mk & 1u) v0 = 1.f;
        if (mk & 8u) v1 = 1.f; else if (mk & 4u) v1 = 0.f;
        outp[n * 2 + 0] = v0;
        outp[n * 2 + 1] = v1;
    }
}

// ---------------- LDS-staged f16 MFMA GEMMs ---------------------------------
#define LDP 72

// 64x64 tile (layer 0, C=64).
__global__ __launch_bounds__(256) void gemm_lds(const __half* __restrict__ A,
                                                const unsigned short* __restrict__ Bhi,
                                                const float* __restrict__ bias,
                                                const unsigned* __restrict__ masks,
                                                __half* __restrict__ O16,
                                                int N, int K, int M) {
    __shared__ __half lA[64 * LDP], lB[64 * LDP];
    int tid = threadIdx.x;
    int wave = tid >> 6, lane = tid & 63;
    int ln16 = lane & 15, q = lane >> 4;
    int row0 = blockIdx.x * 64;
    int col0 = blockIdx.y * 64;

    int r0 = tid >> 3, r1 = r0 + 32;
    int ac = (tid & 7) * 8;
    int ga0 = min(row0 + r0, N - 1);
    int ga1 = min(row0 + r1, N - 1);
    const __half* Bp = (const __half*)Bhi;
    const __half* a0p = A + (size_t)ga0 * K + ac;
    const __half* a1p = A + (size_t)ga1 * K + ac;
    const __half* b0p = Bp + (size_t)(col0 + r0) * K + ac;
    const __half* b1p = Bp + (size_t)(col0 + r1) * K + ac;

    half8 ra0 = *(const half8*)(a0p);
    half8 ra1 = *(const half8*)(a1p);
    half8 rb0 = *(const half8*)(b0p);
    half8 rb1 = *(const half8*)(b1p);

    f32x4 acc[4];
#pragma unroll
    for (int j = 0; j < 4; ++j) acc[j] = (f32x4){0.f, 0.f, 0.f, 0.f};

    for (int kc = 0; kc < K; kc += 64) {
        __syncthreads();
        *(half8*)(lA + r0 * LDP + ac) = ra0;
        *(half8*)(lA + r1 * LDP + ac) = ra1;
        *(half8*)(lB + r0 * LDP + ac) = rb0;
        *(half8*)(lB + r1 * LDP + ac) = rb1;
        __syncthreads();
        int kn = kc + 64;
        if (kn < K) {
            ra0 = *(const half8*)(a0p + kn);
            ra1 = *(const half8*)(a1p + kn);
            rb0 = *(const half8*)(b0p + kn);
            rb1 = *(const half8*)(b1p + kn);
        }
#pragma unroll
        for (int kk = 0; kk < 2; ++kk) {
            half8 af = *(const half8*)(lA + (wave * 16 + ln16) * LDP + kk * 32 + q * 8);
#pragma unroll
            for (int j = 0; j < 4; ++j) {
                half8 bf = *(const half8*)(lB + (j * 16 + ln16) * LDP + kk * 32 + q * 8);
                acc[j] = __builtin_amdgcn_mfma_f32_16x16x32_f16(af, bf, acc[j], 0, 0, 0);
            }
        }
    }

#pragma unroll
    for (int j = 0; j < 4; ++j) {
        int cc = col0 + j * 16 + ln16;
        float bv = bias[cc];
#pragma unroll
        for (int r = 0; r < 4; ++r) {
            int rr = row0 + wave * 16 + q * 4 + r;
            if (rr >= N) continue;
            float v = selu_f(acc[j][r] + bv);
            if (cc < 2) {
                unsigned mk = masks[rr];
                if (cc == 0) { if (mk & 2u) v = 0.f; else if (mk & 1u) v = 1.f; }
                else         { if (mk & 8u) v = 1.f; else if (mk & 4u) v = 0.f; }
            }
            O16[(size_t)rr * M + cc] = __float2half(v);
        }
    }
}

// 32x128 tile (layers 1-3): halves A-reads. 4 waves: wave w -> rows
// (w>>1)*16, cols (w&1)*64; per-wave shape identical to gemm_lds.
__global__ __launch_bounds__(256) void gemm_rc(const __half* __restrict__ A,
                                               const unsigned short* __restrict__ Bhi,
                                               const float* __restrict__ bias,
                                               const unsigned* __restrict__ masks,
                                               __half* __restrict__ O16,
                                               int N, int K, int M) {
    __shared__ __half lA[32 * LDP], lB[128 * LDP];
    int tid = threadIdx.x;
    int wave = tid >> 6, lane = tid & 63;
    int ln16 = lane & 15, q = lane >> 4;
    int row0 = blockIdx.x * 32;
    int col0 = blockIdx.y * 128;
    int wr = (wave >> 1) * 16;
    int wc = (wave & 1) * 64;

    int ar = tid >> 3;                       // 0..31
    int ac = (tid & 7) * 8;
    int ga = min(row0 + ar, N - 1);
    const __half* ap  = A + (size_t)ga * K + ac;
    const __half* Bp  = (const __half*)Bhi;
    const __half* b0p = Bp + (size_t)(col0 + ar) * K + ac;
    const __half* b1p = Bp + (size_t)(col0 + ar + 32) * K + ac;
    const __half* b2p = Bp + (size_t)(col0 + ar + 64) * K + ac;
    const __half* b3p = Bp + (size_t)(col0 + ar + 96) * K + ac;

    half8 ra  = *(const half8*)(ap);
    half8 rb0 = *(const half8*)(b0p);
    half8 rb1 = *(const half8*)(b1p);
    half8 rb2 = *(const half8*)(b2p);
    half8 rb3 = *(const half8*)(b3p);

    f32x4 acc[4];
#pragma unroll
    for (int j = 0; j < 4; ++j) acc[j] = (f32x4){0.f, 0.f, 0.f, 0.f};

    for (int kc = 0; kc < K; kc += 64) {
        __syncthreads();
        *(half8*)(lA + ar * LDP + ac)        = ra;
        *(half8*)(lB + ar * LDP + ac)        = rb0;
        *(half8*)(lB + (ar + 32) * LDP + ac) = rb1;
        *(half8*)(lB + (ar + 64) * LDP + ac) = rb2;
        *(half8*)(lB + (ar + 96) * LDP + ac) = rb3;
        __syncthreads();
        int kn = kc + 64;
        if (kn < K) {
            ra  = *(const half8*)(ap + kn);
            rb0 = *(const half8*)(b0p + kn);
            rb1 = *(const half8*)(b1p + kn);
            rb2 = *(const half8*)(b2p + kn);
            rb3 = *(const half8*)(b3p + kn);
        }
#pragma unroll
        for (int kk = 0; kk < 2; ++kk) {
            half8 af = *(const half8*)(lA + (wr + ln16) * LDP + kk * 32 + q * 8);
#pragma unroll
            for (int j = 0; j < 4; ++j) {
                half8 bf = *(const half8*)(lB + (wc + j * 16 + ln16) * LDP + kk * 32 + q * 8);
                acc[j] = __builtin_amdgcn_mfma_f32_16x16x32_f16(af, bf, acc[j], 0, 0, 0);
            }
        }
    }

#pragma unroll
    for (int j = 0; j < 4; ++j) {
        int cc = col0 + wc + j * 16 + ln16;
        float bv = bias[cc];
#pragma unroll
        for (int r = 0; r < 4; ++r) {
            int rr = row0 + wr + q * 4 + r;
            if (rr >= N) continue;
            float v = selu_f(acc[j][r] + bv);
            if (cc < 2) {
                unsigned mk = masks[rr];
                if (cc == 0) { if (mk & 2u) v = 0.f; else if (mk & 1u) v = 1.f; }
                else         { if (mk & 8u) v = 1.f; else if (mk & 4u) v = 0.f; }
            }
            O16[(size_t)rr * M + cc] = __float2half(v);
        }
    }
}

// ---------------------------------------------------------------------------
extern "C" void kernel_launch(void* const* d_in, const int* in_sizes, int n_in,
                              void* d_out, int out_size, void* d_ws, size_t ws_size,
                              hipStream_t stream) {
    const float* x   = (const float*)d_in[0];
    const int*   ei  = (const int*)d_in[1];
    const float* cf  = (const float*)d_in[2];
    const float* cw[4] = {(const float*)d_in[3], (const float*)d_in[5],
                          (const float*)d_in[7], (const float*)d_in[9]};
    const float* cb[4] = {(const float*)d_in[4], (const float*)d_in[6],
                          (const float*)d_in[8], (const float*)d_in[10]};
    const float* gw[5], *gas[5], *gad[5], *gb[5];
    for (int i = 0; i < 5; ++i) {
        gw[i]  = (const float*)d_in[11 + 4 * i];
        gas[i] = (const float*)d_in[12 + 4 * i];
        gad[i] = (const float*)d_in[13 + 4 * i];
        gb[i]  = (const float*)d_in[14 + 4 * i];
    }
    const int N = in_sizes[0] / 10;        // 10000
    const int E = in_sizes[1] / 2;         // 160000
    const int EN = E + N;

    // ---- workspace carve-up ----
    char* base = (char*)d_ws;
    size_t off = 0;
    auto alloc = [&](size_t bytes) -> char* {
        char* p = base + off;
        off = (off + bytes + 255) & ~(size_t)255;
        return p;
    };
    float* c1p   = (float*)alloc((size_t)16 * PSZ * 4);
    float* c2p   = (float*)alloc((size_t)32 * PSZ * 4);
    float* c3p   = (float*)alloc((size_t)64 * PSZ * 4);
    float* c4p   = (float*)alloc((size_t)24 * PSZ * 4);
    float* gfeat = (float*)alloc(24 * 4);
    __half* hA16 = (__half*)alloc((size_t)N * 256 * 2);
    __half* hB16 = (__half*)alloc((size_t)N * 256 * 2);
    __half* g    = (__half*)alloc((size_t)N * 2048 * 2);
    float* esed  = (float*)alloc((size_t)N * 32 * 4);
    float* eyp   = (float*)alloc((size_t)N * 64 * 4);        // L4 [es|ed|y]
    float* wesed = (float*)alloc((size_t)13312 * 4);         // layers 0-4
    float* wcomb = (float*)alloc((size_t)8192 * 4);          // L4 combined weights
    unsigned short* bt = (unsigned short*)alloc((size_t)688128 * 2);  // 4 GEMM layers
    unsigned* masks = (unsigned*)alloc((size_t)N * 4);
    int* cnt    = (int*)alloc((size_t)N * 4);
    int* indptr = (int*)alloc((size_t)(N + 1) * 4);
    int* cursor = (int*)alloc((size_t)N * 4);
    int* col    = (int*)alloc((size_t)EN * 4);
    (void)ws_size; // ~70 MB

    // ---- one-shot fused weight prep (all 5 layers) ----
    prep_all<<<252, 256, 0, stream>>>(gw[0], gw[1], gw[2], gw[3], gw[4],
                                      gas[0], gas[1], gas[2], gas[3], gas[4],
                                      gad[0], gad[1], gad[2], gad[3], gad[4],
                                      bt, wesed, wcomb);

    // ---- CNN (padded layout; memset zeroes intermediate borders) ----
    hipMemsetAsync(c1p, 0, (size_t)136 * PSZ * 4, stream);
    conv3x3_first<<<dim3(16, 16), 256, 0, stream>>>(cf, cw[0], cb[0], c1p);
    conv3x3_pad<16><<<dim3(16, 32), 256, 0, stream>>>(c1p, cw[1], cb[1], c2p);
    conv3x3_pad<32><<<dim3(16, 64), 256, 0, stream>>>(c2p, cw[2], cb[2], c3p);
    conv3x3_pad<64><<<dim3(16, 24), 256, 0, stream>>>(c3p, cw[3], cb[3], c4p);
    avgpool_c<<<24, 256, 0, stream>>>(c4p, gfeat);

    // ---- h0 (padded to 64, fp16) + masks ----
    build_h0<<<(N + 255) / 256, 256, 0, stream>>>(x, gfeat, hA16, masks, N);

    // ---- CSR by dst (incl self loops): count, one-block scan, scatter ----
    hipMemsetAsync(cnt, 0, (size_t)N * 4, stream);
    count_dst<<<(EN + 255) / 256, 256, 0, stream>>>(ei, cnt, E, N);
    scan_all<<<1, 1024, 0, stream>>>(cnt, indptr, cursor, N, EN);
    scatter_edges<<<(EN + 255) / 256, 256, 0, stream>>>(ei, cursor, col, E, N);

    // ---- GAT layers ----
    const int Hs[5] = {8, 16, 8, 8, 16};
    const int Cs[5] = {64, 128, 256, 128, 2};
    const int Kp[5] = {64, 64, 128, 256, 128};
    const int btOffA[5] = {0, 32768, 163840, 425984, 0};
    const int weOffA[5] = {0, 1024, 3072, 5120, 9216};

    const __half* hin16 = hA16;
    __half* hout16[4]  = {hB16, hA16, hB16, hA16};

    for (int lyr = 0; lyr < 5; ++lyr) {
        int KP = Kp[lyr], H = Hs[lyr], C = Cs[lyr];
        int KA = H * KP;
        if (lyr == 4) {
            // project-first fused final layer
            esed_kernel<<<(N * 64 + 255) / 256, 256, 0, stream>>>(hin16, wcomb, eyp,
                                                                  N, 128, 64);
            final_attn<8><<<(N + 7) / 8, 256, 0, stream>>>(eyp, indptr, col, gb[4],
                                                           masks, x, (float*)d_out, N);
            break;
        }
        esed_kernel<<<(N * 2 * H + 255) / 256, 256, 0, stream>>>(hin16, wesed + weOffA[lyr],
                                                                 esed, N, KP, 2 * H);
        if (lyr == 0) {
            gat_fused_lds<8, 64, 4, 16><<<(N + 15) / 16, 256, 0, stream>>>(
                hin16, esed, indptr, col, g, N);
        } else if (lyr == 1) {
            gat_fused_lds<16, 64, 2, 8><<<(N + 7) / 8, 256, 0, stream>>>(
                hin16, esed, indptr, col, g, N);
        } else if (lyr == 2) {
            gat_fused_lds<8, 128, 4, 8><<<(N + 7) / 8, 256, 0, stream>>>(
                hin16, esed, indptr, col, g, N);
        } else {
            gat_fused_lds<8, 256, 4, 4><<<(N + 3) / 4, 256, 0, stream>>>(
                hin16, esed, indptr, col, g, N);
        }

        const unsigned short* btL = bt + btOffA[lyr];
        if (lyr == 0) {
            gemm_lds<<<dim3((N + 63) / 64, 1), 256, 0, stream>>>(g, btL, gb[lyr], masks,
                                                                 hout16[lyr], N, KA, C);
        } else {
            gemm_rc<<<dim3((N + 31) / 32, C / 128), 256, 0, stream>>>(g, btL, gb[lyr], masks,
                                                                      hout16[lyr], N, KA, C);
        }
        hin16 = hout16[lyr];
    }
}

// Round 14
// 470.066 us; speedup vs baseline: 1.0913x; 1.0913x over previous
//
#include <hip/hip_runtime.h>
#include <hip/hip_fp16.h>
#include <math.h>

// ---------------------------------------------------------------------------
// NetGlobGATFix. R30: fuse next-layer esed/eyp into full-width GEMM epilogues.
//   - L0/L1/L3 GEMM blocks span the full output width (grid.y=1), so the next
//     layer's esed (or L4's eyp) is computed in-epilogue: selu'd tile ->
//     fp16 round-trip -> LDS vt -> per-thread ascending-k dot with wesed/wcomb.
//     Values bit-identical to esed_kernel's input (reads the same fp16).
//   - Removes 3 esed dispatches + ~12MB hout re-reads. L2 (C=256, grid.y=2)
//     keeps standalone esed. Everything else identical to R29 (513.0us;
//     best R28 506.8us; 4-round plateau ~510).
// ---------------------------------------------------------------------------

#define DEVFN static __device__ __forceinline__

typedef __attribute__((ext_vector_type(8))) _Float16 half8;
typedef __attribute__((ext_vector_type(4))) _Float16 half4v;
typedef __attribute__((ext_vector_type(4))) float f32x4;

DEVFN float selu_f(float v) {
    const float scale = 1.0507009873554805f;
    const float alpha = 1.6732632423543772f;
    return v > 0.f ? scale * v : scale * alpha * (expf(v) - 1.f);
}

DEVFN float lrelu02(float v) { return v > 0.f ? v : 0.2f * v; }

// ---------------- CNN (padded 66x66 layout) ----------------
#define PST 66
#define PSZ (66 * 66)

// first conv: reads raw 4x64x64 input with boundary guards, writes padded c1p
__global__ __launch_bounds__(256) void conv3x3_first(const float* __restrict__ cf,
                                                     const float* __restrict__ w,
                                                     const float* __restrict__ b,
                                                     float* __restrict__ out) {
    int x  = threadIdx.x & 63;
    int yg = threadIdx.x >> 6;
    int y  = blockIdx.x * 4 + yg;          // 0..63
    int co = blockIdx.y;
    float acc = b[co];
    const float* wp = w + (size_t)co * 4 * 9;
#pragma unroll
    for (int ci = 0; ci < 4; ++ci) {
        const float* ip = cf + ci * 4096;
        const float* wr = wp + ci * 9;
#pragma unroll
        for (int ky = 0; ky < 3; ++ky) {
            int yy = y + ky - 1;
            if (yy < 0 || yy >= 64) continue;
#pragma unroll
            for (int kx = 0; kx < 3; ++kx) {
                int xx = x + kx - 1;
                if (xx < 0 || xx >= 64) continue;
                acc += wr[ky * 3 + kx] * ip[yy * 64 + xx];
            }
        }
    }
    out[(size_t)co * PSZ + (y + 1) * PST + (x + 1)] = selu_f(acc);
}

template <int CIN>
__global__ __launch_bounds__(256) void conv3x3_pad(const float* __restrict__ in,
                                                   const float* __restrict__ w,
                                                   const float* __restrict__ b,
                                                   float* __restrict__ out) {
    int x  = threadIdx.x & 63;
    int yg = threadIdx.x >> 6;
    int y  = blockIdx.x * 4 + yg;          // 0..63
    int co = blockIdx.y;
    float acc = b[co];
    const float* wp = w + (size_t)co * CIN * 9;
#pragma unroll 4
    for (int ci = 0; ci < CIN; ++ci) {
        const float* ip = in + ci * PSZ + y * PST + x;
        const float* wr = wp + ci * 9;
        acc += wr[0] * ip[0]           + wr[1] * ip[1]           + wr[2] * ip[2]
             + wr[3] * ip[PST]         + wr[4] * ip[PST + 1]     + wr[5] * ip[PST + 2]
             + wr[6] * ip[2 * PST]     + wr[7] * ip[2 * PST + 1] + wr[8] * ip[2 * PST + 2];
    }
    out[(size_t)co * PSZ + (y + 1) * PST + (x + 1)] = selu_f(acc);
}

__global__ void avgpool_c(const float* __restrict__ in, float* __restrict__ gfeat) {
    int c = blockIdx.x;            // 24 blocks
    int t = threadIdx.x;           // 256 threads
    float s = 0.f;
    for (int i = t; i < 4096; i += 256) {
        int y = i >> 6, x = i & 63;
        s += in[c * PSZ + (y + 1) * PST + (x + 1)];
    }
#pragma unroll
    for (int off = 32; off >= 1; off >>= 1) s += __shfl_xor(s, off);
    __shared__ float red[4];
    int wave = t >> 6, lane = t & 63;
    if (lane == 0) red[wave] = s;
    __syncthreads();
    if (t == 0) gfeat[c] = (red[0] + red[1] + red[2] + red[3]) * (1.f / 4096.f);
}

// ---------------- node feature init (padded to 64 ch, fp16) + masks ---------
__global__ void build_h0(const float* __restrict__ x, const float* __restrict__ gfeat,
                         __half* __restrict__ h0f, unsigned* __restrict__ masks, int N) {
    int n = blockIdx.x * blockDim.x + threadIdx.x;
    if (n >= N) return;
    float x0 = x[n * 10 + 0], x1 = x[n * 10 + 1];
    unsigned mk = (x0 == 1.f ? 1u : 0u) | (x0 == 0.f ? 2u : 0u) |
                  (x1 == 0.f ? 4u : 0u) | (x1 == 1.f ? 8u : 0u);
    masks[n] = mk;
    __half* hq = h0f + (size_t)n * 64;
#pragma unroll
    for (int j = 0; j < 64; ++j) {
        float v = (j < 24) ? gfeat[j] : (j < 34 ? x[n * 10 + (j - 24)] : 0.f);
        hq[j] = __float2half(v);
    }
}

// ---------------- CSR build ----------------
__global__ void count_dst(const int* __restrict__ ei, int* __restrict__ cnt, int E, int N) {
    int t = blockIdx.x * blockDim.x + threadIdx.x;
    if (t >= E + N) return;
    int dst = (t < E) ? ei[E + t] : (t - E);
    atomicAdd(&cnt[dst], 1);
}

// single-block exclusive scan over n<=10240 counts (10 elems/thread, 1024 thr)
__global__ __launch_bounds__(1024) void scan_all(const int* __restrict__ cnt,
                                                 int* __restrict__ indptr,
                                                 int* __restrict__ cursor,
                                                 int n, int total) {
    __shared__ int sdata[1024];
    int t = threadIdx.x;
    int base = t * 10;
    int loc[10];
    int s = 0;
#pragma unroll
    for (int i = 0; i < 10; ++i) {
        int idx = base + i;
        int v = (idx < n) ? cnt[idx] : 0;
        loc[i] = s;                     // exclusive prefix within thread
        s += v;
    }
    sdata[t] = s;
    __syncthreads();
    for (int off = 1; off < 1024; off <<= 1) {
        int tmp = (t >= off) ? sdata[t - off] : 0;
        __syncthreads();
        sdata[t] += tmp;
        __syncthreads();
    }
    int excl = (t == 0) ? 0 : sdata[t - 1];
#pragma unroll
    for (int i = 0; i < 10; ++i) {
        int idx = base + i;
        if (idx < n) {
            int e = excl + loc[i];
            indptr[idx] = e;
            cursor[idx] = e;
        }
    }
    if (t == 0) indptr[n] = total;
}

__global__ void scatter_edges(const int* __restrict__ ei, int* __restrict__ cursor,
                              int* __restrict__ col, int E, int N) {
    int t = blockIdx.x * blockDim.x + threadIdx.x;
    if (t >= E + N) return;
    int src, dst;
    if (t < E) { src = ei[t]; dst = ei[E + t]; }
    else       { src = dst = t - E; }
    int pos = atomicAdd(&cursor[dst], 1);
    col[pos] = src;
}

// ---------------- fused one-shot weight prep --------------------------------
// bt layout per layer: bt[btOff + m*KA + h*Kp + k] = fp16(W[k*HC + h*C + m])
// wesed[weOff + k*2H + o] = sum_c W[k,h*C+c]*a[h,c]  (h=o%H, a=as/ad by o<H).
// wcomb (layer 4, 128x64): cols 0..31 = es/ed weights, cols 32..63 = W4 cols.
__global__ __launch_bounds__(256) void prep_all(
        const float* __restrict__ W0, const float* __restrict__ W1,
        const float* __restrict__ W2, const float* __restrict__ W3,
        const float* __restrict__ W4,
        const float* __restrict__ as0, const float* __restrict__ as1,
        const float* __restrict__ as2, const float* __restrict__ as3,
        const float* __restrict__ as4,
        const float* __restrict__ ad0, const float* __restrict__ ad1,
        const float* __restrict__ ad2, const float* __restrict__ ad3,
        const float* __restrict__ ad4,
        unsigned short* __restrict__ bt, float* __restrict__ wesed,
        float* __restrict__ wcomb) {
    const int Kc[5]  = {34, 64, 128, 256, 128};
    const int Kpc[5] = {64, 64, 128, 256, 128};        // L0 padded to 64
    const int Hc[5]  = {8, 16, 8, 8, 16};
    const int Cc[5]  = {64, 128, 256, 128, 2};
    const int HCc[5] = {512, 2048, 2048, 1024, 32};
    const int KAc[5] = {512, 1024, 1024, 2048, 2048};  // L0 KA = 8*64
    const int btOff[5] = {0, 32768, 163840, 425984, 0};
    const int weOff[5] = {0, 1024, 3072, 5120, 9216};

    int b = blockIdx.x, tid = threadIdx.x;

    if (b < 168) {
        // ---- LDS-tiled transpose, one (layer, head, 64x64 tile) per block --
        int lyr, tloc;
        if (b < 8)        { lyr = 0; tloc = b; }
        else if (b < 40)  { lyr = 1; tloc = b - 8; }
        else if (b < 104) { lyr = 2; tloc = b - 40; }
        else              { lyr = 3; tloc = b - 104; }
        const int ktl[4] = {1, 1, 2, 4};   // ceil(Kp/64)
        const int mtl[4] = {1, 2, 4, 2};   // ceil(C/64)
        int kt = ktl[lyr], mt = mtl[lyr];
        int per_h = kt * mt;
        int h = tloc / per_h, r = tloc - h * per_h;
        int ki = r % kt, mi = r / kt;
        int k0 = ki * 64, m0 = mi * 64;
        int K = Kc[lyr], Kp = Kpc[lyr], C = Cc[lyr], HC = HCc[lyr], KA = KAc[lyr];
        const float* W;
        if (lyr == 0) W = W0; else if (lyr == 1) W = W1;
        else if (lyr == 2) W = W2; else W = W3;

        __shared__ float tile[64][65];
        int c = tid & 63, rg = tid >> 6;
        for (int r2 = rg; r2 < 64; r2 += 4) {       // coalesced 256B reads
            int k = k0 + r2, m = m0 + c;
            float v = (k < K && m < C) ? W[(size_t)k * HC + h * C + m] : 0.f;
            tile[r2][c] = v;
        }
        __syncthreads();
        unsigned short* bp = bt + btOff[lyr];
        for (int mr = rg; mr < 64; mr += 4) {       // coalesced 128B fp16 writes
            int m = m0 + mr, k = k0 + c;
            if (m < C && k < Kp)
                bp[(size_t)m * KA + h * Kp + k] =
                    __half_as_ushort(__float2half(tile[c][mr]));
        }
    } else if (b < 200) {
        // ---- wcomb for layer 4: 8192 outputs (128 x 64) ----
        int u = (b - 168) * 256 + tid;
        int k = u >> 6, o = u & 63;
        float s;
        if (o < 32) {                       // es/ed weights
            int h = (o < 16) ? o : o - 16;
            const float* av = ((o < 16) ? as4 : ad4) + h * 2;
            s = W4[k * 32 + h * 2 + 0] * av[0] + W4[k * 32 + h * 2 + 1] * av[1];
        } else {                            // y projection: raw W4 column
            s = W4[k * 32 + (o - 32)];
        }
        wcomb[u] = s;
    } else {
        // ---- wesed dots: sizes {1024,2048,2048,4096,4096} -> 52 blocks ----
        int wb = b - 200;
        int lyr, u0;
        if (wb < 4)       { lyr = 0; u0 = wb * 256; }
        else if (wb < 12) { lyr = 1; u0 = (wb - 4) * 256; }
        else if (wb < 20) { lyr = 2; u0 = (wb - 12) * 256; }
        else if (wb < 36) { lyr = 3; u0 = (wb - 20) * 256; }
        else              { lyr = 4; u0 = (wb - 36) * 256; }
        int u = u0 + tid;
        int K = Kc[lyr], Kp = Kpc[lyr], H = Hc[lyr], C = Cc[lyr], HC = HCc[lyr];
        int H2 = 2 * H;
        if (u < Kp * H2) {
            int k = u / H2, o = u - k * H2;
            float s = 0.f;
            if (k < K) {
                int h = (o < H) ? o : o - H;
                const float *W, *as_, *ad_;
                if (lyr == 0)      { W = W0; as_ = as0; ad_ = ad0; }
                else if (lyr == 1) { W = W1; as_ = as1; ad_ = ad1; }
                else if (lyr == 2) { W = W2; as_ = as2; ad_ = ad2; }
                else if (lyr == 3) { W = W3; as_ = as3; ad_ = ad3; }
                else               { W = W4; as_ = as4; ad_ = ad4; }
                const float* av = ((o < H) ? as_ : ad_) + h * C;
                const float* wp = W + (size_t)k * HC + h * C;
#pragma unroll 4
                for (int c2 = 0; c2 < C; ++c2) s += wp[c2] * av[c2];
            }
            wesed[weOff[lyr] + u] = s;
        }
    }
}

// ---------------- es/ed: out[n,o] = hin16[n,:] @ w[:,o] ---------------------
__global__ void esed_kernel(const __half* __restrict__ hin, const float* __restrict__ wesed,
                            float* __restrict__ esed, int N, int Kp, int H2) {
    int t = blockIdx.x * blockDim.x + threadIdx.x;
    if (t >= N * H2) return;
    int n = t / H2, o = t - n * H2;
    const __half2* hp = (const __half2*)(hin + (size_t)n * Kp);
    float s = 0.f;
    for (int k2 = 0; k2 < Kp / 2; ++k2) {
        float2 f = __half22float2(hp[k2]);
        s += f.x * wesed[(2 * k2) * H2 + o] + f.y * wesed[(2 * k2 + 1) * H2 + o];
    }
    esed[t] = s;
}

// -------- fused attn+gather via LDS broadcast, pipelined (layers 0-3) -------
template <int H, int KP, int CH, int NPB>
__global__ __launch_bounds__(NPB * (KP / CH)) void gat_fused_lds(
        const __half* __restrict__ hinf, const float* __restrict__ esed,
        const int* __restrict__ indptr, const int* __restrict__ col,
        __half* __restrict__ g, int N) {
    const int TPN = KP / CH;
    const int EC  = TPN / H;
    const int H2  = 2 * H;
    __shared__ float lds_p[NPB][2][TPN];
    int sub = threadIdx.x / TPN;
    int j   = threadIdx.x % TPN;
    int n = blockIdx.x * NPB + sub;
    if (n >= N) return;
    int e_my = j / H, h_my = j % H;
    int c0 = j * CH;
    float edv = esed[n * H2 + H + h_my];

    float acc[H][CH];
#pragma unroll
    for (int h = 0; h < H; ++h)
#pragma unroll
        for (int t = 0; t < CH; ++t) acc[h][t] = 0.f;
    float zloc = 0.f;

    int beg = indptr[n], deg = indptr[n + 1] - beg;

    // prologue: p for chunk 0
    float p = 0.f;
    if (e_my < deg) {
        int srcm = col[beg + e_my];
        p = expf(lrelu02(esed[srcm * H2 + h_my] + edv));
    }
    int buf = 0;
    for (int base = 0; base < deg; base += EC) {
        zloc += p;
        lds_p[sub][buf][j] = p;
        __builtin_amdgcn_wave_barrier();
        // issue next chunk's attention loads (exp after phase B)
        int ce = base + EC + e_my;
        bool vnext = (ce < deg);
        float esv = 0.f;
        if (vnext) {
            int srcm = col[beg + ce];
            esv = esed[srcm * H2 + h_my];
        }
        // phase B: pipelined gather with LDS-broadcast alphas
#pragma unroll
        for (int e = 0; e < EC; ++e) {
            int idx = base + e;
            if (idx < deg) {                  // uniform within node group
                int src = col[beg + idx];
                float f[CH];
                if (CH == 2) {
                    __half2 hv = *(const __half2*)(hinf + (size_t)src * KP + c0);
                    float2 ff = __half22float2(hv);
                    f[0] = ff.x; f[1] = ff.y;
                } else {
                    half4v hv = *(const half4v*)(hinf + (size_t)src * KP + c0);
                    f[0] = (float)hv[0]; f[1] = (float)hv[1];
                    f[2] = (float)hv[2]; f[3] = (float)hv[3];
                }
                const float4* ap = (const float4*)&lds_p[sub][buf][e * H];
#pragma unroll
                for (int q4 = 0; q4 < H / 4; ++q4) {
                    float4 a4 = ap[q4];
#pragma unroll
                    for (int t = 0; t < CH; ++t) {
                        acc[4 * q4 + 0][t] += a4.x * f[t];
                        acc[4 * q4 + 1][t] += a4.y * f[t];
                        acc[4 * q4 + 2][t] += a4.z * f[t];
                        acc[4 * q4 + 3][t] += a4.w * f[t];
                    }
                }
            }
        }
        p = vnext ? expf(lrelu02(esv + edv)) : 0.f;
        buf ^= 1;
    }

    // z: reduce across the EC lanes of each head class
#pragma unroll
    for (int off = H; off < TPN; off <<= 1)
        zloc += __shfl_xor(zloc, off, TPN);
    float zinv_my = (1.f / H) / (zloc + 1e-16f);

    __half* gp = g + (size_t)n * (H * KP) + c0;
#pragma unroll
    for (int h = 0; h < H; ++h) {
        float zf = __shfl(zinv_my, h, TPN);   // lane class h holds z for head h
        if (CH == 2) {
            *(__half2*)(gp + h * KP) =
                __floats2half2_rn(acc[h][0] * zf, acc[h][1] * zf);
        } else {
            __half2 lo = __floats2half2_rn(acc[h][0] * zf, acc[h][1] * zf);
            __half2 hi = __floats2half2_rn(acc[h][2] * zf, acc[h][3] * zf);
            union { __half2 h2[2]; float2 f2; } u;
            u.h2[0] = lo; u.h2[1] = hi;
            *(float2*)(gp + h * KP) = u.f2;
        }
    }
}

// -------- layer 4: fused attention + projected gather + output --------------
template <int NPB>
__global__ __launch_bounds__(NPB * 32) void final_attn(
        const float* __restrict__ eyp, const int* __restrict__ indptr,
        const int* __restrict__ col, const float* __restrict__ b5,
        const unsigned* __restrict__ masks, const float* __restrict__ x,
        float* __restrict__ outp, int N) {
    int sub = threadIdx.x >> 5;
    int j   = threadIdx.x & 31;
    int n = blockIdx.x * NPB + sub;
    if (n >= N) return;
    int h = j >> 1;
    float edv = eyp[(size_t)n * 64 + 16 + h];
    int beg = indptr[n], end = indptr[n + 1];
    float z = 0.f, a = 0.f;
    int i = beg;
    for (; i + 1 < end; i += 2) {
        int s0 = col[i], s1 = col[i + 1];
        const float* r0 = eyp + (size_t)s0 * 64;
        const float* r1 = eyp + (size_t)s1 * 64;
        float es0 = r0[h], y0 = r0[32 + j];
        float es1 = r1[h], y1 = r1[32 + j];
        float p0 = expf(lrelu02(es0 + edv));
        float p1 = expf(lrelu02(es1 + edv));
        z += p0; a += p0 * y0;
        z += p1; a += p1 * y1;
    }
    for (; i < end; ++i) {
        const float* r = eyp + (size_t)col[i] * 64;
        float p = expf(lrelu02(r[h] + edv));
        z += p; a += p * r[32 + j];
    }
    float zf = (1.f / 16.f) / (z + 1e-16f);
    float val = a * zf;
#pragma unroll
    for (int off = 2; off <= 16; off <<= 1) val += __shfl_xor(val, off, 32);
    float other = __shfl_xor(val, 1, 32);        // opposite parity's sum
    if (j == 0) {
        unsigned mk = masks[n];
        float v0 = x[n * 10 + 0] + selu_f(val + b5[0]);
        float v1 = x[n * 10 + 1] + selu_f(other + b5[1]);
        if (mk & 2u) v0 = 0.f; else if (mk & 1u) v0 = 1.f;
        if (mk & 8u) v1 = 1.f; else if (mk & 4u) v1 = 0.f;
        outp[n * 2 + 0] = v0;
        outp[n * 2 + 1] = v1;
    }
}

// ---------------- LDS-staged f16 MFMA GEMMs ---------------------------------
#define LDP 72

// 64x64 tile (layer 0, C=64). EOUT>0: fused next-layer esed from LDS tile.
template <int EOUT>
__global__ __launch_bounds__(256) void gemm_lds(const __half* __restrict__ A,
                                                const unsigned short* __restrict__ Bhi,
                                                const float* __restrict__ bias,
                                                const unsigned* __restrict__ masks,
                                                __half* __restrict__ O16,
                                                const float* __restrict__ wnext,
                                                float* __restrict__ eout,
                                                int N, int K, int M) {
    __shared__ __half lA[64 * LDP], lB[64 * LDP];
    __shared__ float vt[EOUT ? 64 : 1][EOUT ? 68 : 1];
    int tid = threadIdx.x;
    int wave = tid >> 6, lane = tid & 63;
    int ln16 = lane & 15, q = lane >> 4;
    int row0 = blockIdx.x * 64;
    int col0 = blockIdx.y * 64;

    int r0 = tid >> 3, r1 = r0 + 32;
    int ac = (tid & 7) * 8;
    int ga0 = min(row0 + r0, N - 1);
    int ga1 = min(row0 + r1, N - 1);
    const __half* Bp = (const __half*)Bhi;
    const __half* a0p = A + (size_t)ga0 * K + ac;
    const __half* a1p = A + (size_t)ga1 * K + ac;
    const __half* b0p = Bp + (size_t)(col0 + r0) * K + ac;
    const __half* b1p = Bp + (size_t)(col0 + r1) * K + ac;

    half8 ra0 = *(const half8*)(a0p);
    half8 ra1 = *(const half8*)(a1p);
    half8 rb0 = *(const half8*)(b0p);
    half8 rb1 = *(const half8*)(b1p);

    f32x4 acc[4];
#pragma unroll
    for (int j = 0; j < 4; ++j) acc[j] = (f32x4){0.f, 0.f, 0.f, 0.f};

    for (int kc = 0; kc < K; kc += 64) {
        __syncthreads();
        *(half8*)(lA + r0 * LDP + ac) = ra0;
        *(half8*)(lA + r1 * LDP + ac) = ra1;
        *(half8*)(lB + r0 * LDP + ac) = rb0;
        *(half8*)(lB + r1 * LDP + ac) = rb1;
        __syncthreads();
        int kn = kc + 64;
        if (kn < K) {
            ra0 = *(const half8*)(a0p + kn);
            ra1 = *(const half8*)(a1p + kn);
            rb0 = *(const half8*)(b0p + kn);
            rb1 = *(const half8*)(b1p + kn);
        }
#pragma unroll
        for (int kk = 0; kk < 2; ++kk) {
            half8 af = *(const half8*)(lA + (wave * 16 + ln16) * LDP + kk * 32 + q * 8);
#pragma unroll
            for (int j = 0; j < 4; ++j) {
                half8 bf = *(const half8*)(lB + (j * 16 + ln16) * LDP + kk * 32 + q * 8);
                acc[j] = __builtin_amdgcn_mfma_f32_16x16x32_f16(af, bf, acc[j], 0, 0, 0);
            }
        }
    }

#pragma unroll
    for (int j = 0; j < 4; ++j) {
        int cc = col0 + j * 16 + ln16;
        float bv = bias[cc];
#pragma unroll
        for (int r = 0; r < 4; ++r) {
            int rr = row0 + wave * 16 + q * 4 + r;
            float v = selu_f(acc[j][r] + bv);
            if (cc < 2 && rr < N) {
                unsigned mk = masks[rr];
                if (cc == 0) { if (mk & 2u) v = 0.f; else if (mk & 1u) v = 1.f; }
                else         { if (mk & 8u) v = 1.f; else if (mk & 4u) v = 0.f; }
            }
            __half hv = __float2half(v);
            if (rr < N) O16[(size_t)rr * M + cc] = hv;
            if constexpr (EOUT > 0)
                vt[wave * 16 + q * 4 + r][j * 16 + ln16] = __half2float(hv);
        }
    }

    if constexpr (EOUT > 0) {
        __syncthreads();
        const int NG = 256 / EOUT;     // row-groups (8 for EOUT=32)
        const int NI = 64 / NG;        // rows per thread (8)
        int o = tid & (EOUT - 1);
        int ngrp = tid / EOUT;
        float s[NI];
#pragma unroll
        for (int i = 0; i < NI; ++i) s[i] = 0.f;
        for (int k = 0; k < 64; ++k) {
            float wk = wnext[k * EOUT + o];
#pragma unroll
            for (int i = 0; i < NI; ++i)
                s[i] += vt[ngrp + NG * i][k] * wk;
        }
#pragma unroll
        for (int i = 0; i < NI; ++i) {
            int n = row0 + ngrp + NG * i;
            if (n < N) eout[(size_t)n * EOUT + o] = s[i];
        }
    }
}

// 32x128 tile (layers 1-3). EOUT>0: fused next-layer esed/eyp (needs grid.y=1).
template <int EOUT>
__global__ __launch_bounds__(256) void gemm_rc(const __half* __restrict__ A,
                                               const unsigned short* __restrict__ Bhi,
                                               const float* __restrict__ bias,
                                               const unsigned* __restrict__ masks,
                                               __half* __restrict__ O16,
                                               const float* __restrict__ wnext,
                                               float* __restrict__ eout,
                                               int N, int K, int M) {
    __shared__ __half lA[32 * LDP], lB[128 * LDP];
    __shared__ float vt[EOUT ? 32 : 1][EOUT ? 132 : 1];
    int tid = threadIdx.x;
    int wave = tid >> 6, lane = tid & 63;
    int ln16 = lane & 15, q = lane >> 4;
    int row0 = blockIdx.x * 32;
    int col0 = blockIdx.y * 128;
    int wr = (wave >> 1) * 16;
    int wc = (wave & 1) * 64;

    int ar = tid >> 3;                       // 0..31
    int ac = (tid & 7) * 8;
    int ga = min(row0 + ar, N - 1);
    const __half* ap  = A + (size_t)ga * K + ac;
    const __half* Bp  = (const __half*)Bhi;
    const __half* b0p = Bp + (size_t)(col0 + ar) * K + ac;
    const __half* b1p = Bp + (size_t)(col0 + ar + 32) * K + ac;
    const __half* b2p = Bp + (size_t)(col0 + ar + 64) * K + ac;
    const __half* b3p = Bp + (size_t)(col0 + ar + 96) * K + ac;

    half8 ra  = *(const half8*)(ap);
    half8 rb0 = *(const half8*)(b0p);
    half8 rb1 = *(const half8*)(b1p);
    half8 rb2 = *(const half8*)(b2p);
    half8 rb3 = *(const half8*)(b3p);

    f32x4 acc[4];
#pragma unroll
    for (int j = 0; j < 4; ++j) acc[j] = (f32x4){0.f, 0.f, 0.f, 0.f};

    for (int kc = 0; kc < K; kc += 64) {
        __syncthreads();
        *(half8*)(lA + ar * LDP + ac)        = ra;
        *(half8*)(lB + ar * LDP + ac)        = rb0;
        *(half8*)(lB + (ar + 32) * LDP + ac) = rb1;
        *(half8*)(lB + (ar + 64) * LDP + ac) = rb2;
        *(half8*)(lB + (ar + 96) * LDP + ac) = rb3;
        __syncthreads();
        int kn = kc + 64;
        if (kn < K) {
            ra  = *(const half8*)(ap + kn);
            rb0 = *(const half8*)(b0p + kn);
            rb1 = *(const half8*)(b1p + kn);
            rb2 = *(const half8*)(b2p + kn);
            rb3 = *(const half8*)(b3p + kn);
        }
#pragma unroll
        for (int kk = 0; kk < 2; ++kk) {
            half8 af = *(const half8*)(lA + (wr + ln16) * LDP + kk * 32 + q * 8);
#pragma unroll
            for (int j = 0; j < 4; ++j) {
                half8 bf = *(const half8*)(lB + (wc + j * 16 + ln16) * LDP + kk * 32 + q * 8);
                acc[j] = __builtin_amdgcn_mfma_f32_16x16x32_f16(af, bf, acc[j], 0, 0, 0);
            }
        }
    }

#pragma unroll
    for (int j = 0; j < 4; ++j) {
        int cc = col0 + wc + j * 16 + ln16;
        float bv = bias[cc];
#pragma unroll
        for (int r = 0; r < 4; ++r) {
            int rr = row0 + wr + q * 4 + r;
            float v = selu_f(acc[j][r] + bv);
            if (cc < 2 && rr < N) {
                unsigned mk = masks[rr];
                if (cc == 0) { if (mk & 2u) v = 0.f; else if (mk & 1u) v = 1.f; }
                else         { if (mk & 8u) v = 1.f; else if (mk & 4u) v = 0.f; }
            }
            __half hv = __float2half(v);
            if (rr < N) O16[(size_t)rr * M + cc] = hv;
            if constexpr (EOUT > 0)
                vt[wr + q * 4 + r][wc + j * 16 + ln16] = __half2float(hv);
        }
    }

    if constexpr (EOUT > 0) {
        __syncthreads();
        const int NG = 256 / EOUT;     // row-groups (16 for EOUT=16, 4 for 64)
        const int NI = 32 / NG;        // rows per thread (2 / 8)
        int o = tid & (EOUT - 1);
        int ngrp = tid / EOUT;
        float s[NI];
#pragma unroll
        for (int i = 0; i < NI; ++i) s[i] = 0.f;
        for (int k = 0; k < 128; ++k) {
            float wk = wnext[k * EOUT + o];
#pragma unroll
            for (int i = 0; i < NI; ++i)
                s[i] += vt[ngrp + NG * i][k] * wk;
        }
#pragma unroll
        for (int i = 0; i < NI; ++i) {
            int n = row0 + ngrp + NG * i;
            if (n < N) eout[(size_t)n * EOUT + o] = s[i];
        }
    }
}

// ---------------------------------------------------------------------------
extern "C" void kernel_launch(void* const* d_in, const int* in_sizes, int n_in,
                              void* d_out, int out_size, void* d_ws, size_t ws_size,
                              hipStream_t stream) {
    const float* x   = (const float*)d_in[0];
    const int*   ei  = (const int*)d_in[1];
    const float* cf  = (const float*)d_in[2];
    const float* cw[4] = {(const float*)d_in[3], (const float*)d_in[5],
                          (const float*)d_in[7], (const float*)d_in[9]};
    const float* cb[4] = {(const float*)d_in[4], (const float*)d_in[6],
                          (const float*)d_in[8], (const float*)d_in[10]};
    const float* gw[5], *gas[5], *gad[5], *gb[5];
    for (int i = 0; i < 5; ++i) {
        gw[i]  = (const float*)d_in[11 + 4 * i];
        gas[i] = (const float*)d_in[12 + 4 * i];
        gad[i] = (const float*)d_in[13 + 4 * i];
        gb[i]  = (const float*)d_in[14 + 4 * i];
    }
    const int N = in_sizes[0] / 10;        // 10000
    const int E = in_sizes[1] / 2;         // 160000
    const int EN = E + N;

    // ---- workspace carve-up ----
    char* base = (char*)d_ws;
    size_t off = 0;
    auto alloc = [&](size_t bytes) -> char* {
        char* p = base + off;
        off = (off + bytes + 255) & ~(size_t)255;
        return p;
    };
    float* c1p   = (float*)alloc((size_t)16 * PSZ * 4);
    float* c2p   = (float*)alloc((size_t)32 * PSZ * 4);
    float* c3p   = (float*)alloc((size_t)64 * PSZ * 4);
    float* c4p   = (float*)alloc((size_t)24 * PSZ * 4);
    float* gfeat = (float*)alloc(24 * 4);
    __half* hA16 = (__half*)alloc((size_t)N * 256 * 2);
    __half* hB16 = (__half*)alloc((size_t)N * 256 * 2);
    __half* g    = (__half*)alloc((size_t)N * 2048 * 2);
    float* esed  = (float*)alloc((size_t)N * 32 * 4);
    float* eyp   = (float*)alloc((size_t)N * 64 * 4);        // L4 [es|ed|y]
    float* wesed = (float*)alloc((size_t)13312 * 4);         // layers 0-4
    float* wcomb = (float*)alloc((size_t)8192 * 4);          // L4 combined weights
    unsigned short* bt = (unsigned short*)alloc((size_t)688128 * 2);  // 4 GEMM layers
    unsigned* masks = (unsigned*)alloc((size_t)N * 4);
    int* cnt    = (int*)alloc((size_t)N * 4);
    int* indptr = (int*)alloc((size_t)(N + 1) * 4);
    int* cursor = (int*)alloc((size_t)N * 4);
    int* col    = (int*)alloc((size_t)EN * 4);
    (void)ws_size; // ~70 MB

    // ---- one-shot fused weight prep (all 5 layers) ----
    prep_all<<<252, 256, 0, stream>>>(gw[0], gw[1], gw[2], gw[3], gw[4],
                                      gas[0], gas[1], gas[2], gas[3], gas[4],
                                      gad[0], gad[1], gad[2], gad[3], gad[4],
                                      bt, wesed, wcomb);

    // ---- CNN (padded layout; memset zeroes intermediate borders) ----
    hipMemsetAsync(c1p, 0, (size_t)136 * PSZ * 4, stream);
    conv3x3_first<<<dim3(16, 16), 256, 0, stream>>>(cf, cw[0], cb[0], c1p);
    conv3x3_pad<16><<<dim3(16, 32), 256, 0, stream>>>(c1p, cw[1], cb[1], c2p);
    conv3x3_pad<32><<<dim3(16, 64), 256, 0, stream>>>(c2p, cw[2], cb[2], c3p);
    conv3x3_pad<64><<<dim3(16, 24), 256, 0, stream>>>(c3p, cw[3], cb[3], c4p);
    avgpool_c<<<24, 256, 0, stream>>>(c4p, gfeat);

    // ---- h0 (padded to 64, fp16) + masks ----
    build_h0<<<(N + 255) / 256, 256, 0, stream>>>(x, gfeat, hA16, masks, N);

    // ---- CSR by dst (incl self loops): count, one-block scan, scatter ----
    hipMemsetAsync(cnt, 0, (size_t)N * 4, stream);
    count_dst<<<(EN + 255) / 256, 256, 0, stream>>>(ei, cnt, E, N);
    scan_all<<<1, 1024, 0, stream>>>(cnt, indptr, cursor, N, EN);
    scatter_edges<<<(EN + 255) / 256, 256, 0, stream>>>(ei, cursor, col, E, N);

    // ---- GAT layers (esed for L1/L2/L4 fused into preceding GEMMs) ----
    int gx32 = (N + 31) / 32;   // 313
    int gx64 = (N + 63) / 64;   // 157

    // L0: Kp=64 H=8 C=64 KA=512 ; standalone esed (H2=16) from h0
    esed_kernel<<<(N * 16 + 255) / 256, 256, 0, stream>>>(hA16, wesed + 0, esed, N, 64, 16);
    gat_fused_lds<8, 64, 4, 16><<<(N + 15) / 16, 256, 0, stream>>>(
        hA16, esed, indptr, col, g, N);
    gemm_lds<32><<<dim3(gx64, 1), 256, 0, stream>>>(g, bt + 0, gb[0], masks, hB16,
                                                    wesed + 1024, esed, N, 512, 64);

    // L1: Kp=64 H=16 C=128 KA=1024 ; esed (H2=32) from L0 gemm
    gat_fused_lds<16, 64, 2, 8><<<(N + 7) / 8, 256, 0, stream>>>(
        hB16, esed, indptr, col, g, N);
    gemm_rc<16><<<dim3(gx32, 1), 256, 0, stream>>>(g, bt + 32768, gb[1], masks, hA16,
                                                   wesed + 3072, esed, N, 1024, 128);

    // L2: Kp=128 H=8 C=256 KA=1024 ; esed (H2=16) from L1 gemm
    gat_fused_lds<8, 128, 4, 8><<<(N + 7) / 8, 256, 0, stream>>>(
        hA16, esed, indptr, col, g, N);
    gemm_rc<0><<<dim3(gx32, 2), 256, 0, stream>>>(g, bt + 163840, gb[2], masks, hB16,
                                                  nullptr, nullptr, N, 1024, 256);
    esed_kernel<<<(N * 16 + 255) / 256, 256, 0, stream>>>(hB16, wesed + 5120, esed, N, 256, 16);

    // L3: Kp=256 H=8 C=128 KA=2048 ; eyp (64) from L3 gemm
    gat_fused_lds<8, 256, 4, 4><<<(N + 3) / 4, 256, 0, stream>>>(
        hB16, esed, indptr, col, g, N);
    gemm_rc<64><<<dim3(gx32, 1), 256, 0, stream>>>(g, bt + 425984, gb[3], masks, hA16,
                                                   wcomb, eyp, N, 2048, 128);

    // L4: project-first fused final layer
    final_attn<8><<<(N + 7) / 8, 256, 0, stream>>>(eyp, indptr, col, gb[4],
                                                   masks, x, (float*)d_out, N);
}

// Round 15
// 433.132 us; speedup vs baseline: 1.1844x; 1.0853x over previous
//
#include <hip/hip_runtime.h>
#include <hip/hip_fp16.h>
#include <math.h>

// ---------------------------------------------------------------------------
// NetGlobGATFix. R31: last two esed dispatches fused (build_h0 + L2 partials).
//   - L0 esed fused into build_h0 (fp16-rounded regs -> 16 dots inline;
//     bit-identical inputs to the deleted esed_kernel).
//   - L2 esed fused into L2's gemm_rc<16> grid.y=2 as TWO K-half partials
//     (eout + blockIdx.y*N*EOUT, wnext + col0*EOUT); L3's gather sums the
//     two partials at load (order-independent 2-float add).
//   - esed_kernel deleted; -2 dispatches, -6MB re-reads.
//   - Everything else identical to R30 (470.1us best).
// ---------------------------------------------------------------------------

#define DEVFN static __device__ __forceinline__

typedef __attribute__((ext_vector_type(8))) _Float16 half8;
typedef __attribute__((ext_vector_type(4))) _Float16 half4v;
typedef __attribute__((ext_vector_type(4))) float f32x4;

DEVFN float selu_f(float v) {
    const float scale = 1.0507009873554805f;
    const float alpha = 1.6732632423543772f;
    return v > 0.f ? scale * v : scale * alpha * (expf(v) - 1.f);
}

DEVFN float lrelu02(float v) { return v > 0.f ? v : 0.2f * v; }

// ---------------- CNN (padded 66x66 layout) ----------------
#define PST 66
#define PSZ (66 * 66)

// first conv: reads raw 4x64x64 input with boundary guards, writes padded c1p
__global__ __launch_bounds__(256) void conv3x3_first(const float* __restrict__ cf,
                                                     const float* __restrict__ w,
                                                     const float* __restrict__ b,
                                                     float* __restrict__ out) {
    int x  = threadIdx.x & 63;
    int yg = threadIdx.x >> 6;
    int y  = blockIdx.x * 4 + yg;          // 0..63
    int co = blockIdx.y;
    float acc = b[co];
    const float* wp = w + (size_t)co * 4 * 9;
#pragma unroll
    for (int ci = 0; ci < 4; ++ci) {
        const float* ip = cf + ci * 4096;
        const float* wr = wp + ci * 9;
#pragma unroll
        for (int ky = 0; ky < 3; ++ky) {
            int yy = y + ky - 1;
            if (yy < 0 || yy >= 64) continue;
#pragma unroll
            for (int kx = 0; kx < 3; ++kx) {
                int xx = x + kx - 1;
                if (xx < 0 || xx >= 64) continue;
                acc += wr[ky * 3 + kx] * ip[yy * 64 + xx];
            }
        }
    }
    out[(size_t)co * PSZ + (y + 1) * PST + (x + 1)] = selu_f(acc);
}

template <int CIN>
__global__ __launch_bounds__(256) void conv3x3_pad(const float* __restrict__ in,
                                                   const float* __restrict__ w,
                                                   const float* __restrict__ b,
                                                   float* __restrict__ out) {
    int x  = threadIdx.x & 63;
    int yg = threadIdx.x >> 6;
    int y  = blockIdx.x * 4 + yg;          // 0..63
    int co = blockIdx.y;
    float acc = b[co];
    const float* wp = w + (size_t)co * CIN * 9;
#pragma unroll 4
    for (int ci = 0; ci < CIN; ++ci) {
        const float* ip = in + ci * PSZ + y * PST + x;
        const float* wr = wp + ci * 9;
        acc += wr[0] * ip[0]           + wr[1] * ip[1]           + wr[2] * ip[2]
             + wr[3] * ip[PST]         + wr[4] * ip[PST + 1]     + wr[5] * ip[PST + 2]
             + wr[6] * ip[2 * PST]     + wr[7] * ip[2 * PST + 1] + wr[8] * ip[2 * PST + 2];
    }
    out[(size_t)co * PSZ + (y + 1) * PST + (x + 1)] = selu_f(acc);
}

__global__ void avgpool_c(const float* __restrict__ in, float* __restrict__ gfeat) {
    int c = blockIdx.x;            // 24 blocks
    int t = threadIdx.x;           // 256 threads
    float s = 0.f;
    for (int i = t; i < 4096; i += 256) {
        int y = i >> 6, x = i & 63;
        s += in[c * PSZ + (y + 1) * PST + (x + 1)];
    }
#pragma unroll
    for (int off = 32; off >= 1; off >>= 1) s += __shfl_xor(s, off);
    __shared__ float red[4];
    int wave = t >> 6, lane = t & 63;
    if (lane == 0) red[wave] = s;
    __syncthreads();
    if (t == 0) gfeat[c] = (red[0] + red[1] + red[2] + red[3]) * (1.f / 4096.f);
}

// ---------------- node feature init (padded to 64 ch, fp16) + masks ---------
// Fused L0 esed: per node, 16 dots over the fp16-rounded features
// (bit-identical inputs to the old esed_kernel read of h0f).
__global__ void build_h0(const float* __restrict__ x, const float* __restrict__ gfeat,
                         const float* __restrict__ we0,
                         __half* __restrict__ h0f, unsigned* __restrict__ masks,
                         float* __restrict__ esed, int N) {
    int n = blockIdx.x * blockDim.x + threadIdx.x;
    if (n >= N) return;
    float x0 = x[n * 10 + 0], x1 = x[n * 10 + 1];
    unsigned mk = (x0 == 1.f ? 1u : 0u) | (x0 == 0.f ? 2u : 0u) |
                  (x1 == 0.f ? 4u : 0u) | (x1 == 1.f ? 8u : 0u);
    masks[n] = mk;
    __half* hq = h0f + (size_t)n * 64;
    float hf[64];
#pragma unroll
    for (int j = 0; j < 64; ++j) {
        float v = (j < 24) ? gfeat[j] : (j < 34 ? x[n * 10 + (j - 24)] : 0.f);
        __half hv = __float2half(v);
        hq[j] = hv;
        hf[j] = __half2float(hv);
    }
    float s[16];
#pragma unroll
    for (int o = 0; o < 16; ++o) s[o] = 0.f;
    for (int k = 0; k < 64; ++k) {
        float f = hf[k];
        const float* wk = we0 + k * 16;
#pragma unroll
        for (int o = 0; o < 16; ++o) s[o] += f * wk[o];
    }
#pragma unroll
    for (int o = 0; o < 16; ++o) esed[(size_t)n * 16 + o] = s[o];
}

// ---------------- CSR build ----------------
__global__ void count_dst(const int* __restrict__ ei, int* __restrict__ cnt, int E, int N) {
    int t = blockIdx.x * blockDim.x + threadIdx.x;
    if (t >= E + N) return;
    int dst = (t < E) ? ei[E + t] : (t - E);
    atomicAdd(&cnt[dst], 1);
}

// single-block exclusive scan over n<=10240 counts (10 elems/thread, 1024 thr)
__global__ __launch_bounds__(1024) void scan_all(const int* __restrict__ cnt,
                                                 int* __restrict__ indptr,
                                                 int* __restrict__ cursor,
                                                 int n, int total) {
    __shared__ int sdata[1024];
    int t = threadIdx.x;
    int base = t * 10;
    int loc[10];
    int s = 0;
#pragma unroll
    for (int i = 0; i < 10; ++i) {
        int idx = base + i;
        int v = (idx < n) ? cnt[idx] : 0;
        loc[i] = s;                     // exclusive prefix within thread
        s += v;
    }
    sdata[t] = s;
    __syncthreads();
    for (int off = 1; off < 1024; off <<= 1) {
        int tmp = (t >= off) ? sdata[t - off] : 0;
        __syncthreads();
        sdata[t] += tmp;
        __syncthreads();
    }
    int excl = (t == 0) ? 0 : sdata[t - 1];
#pragma unroll
    for (int i = 0; i < 10; ++i) {
        int idx = base + i;
        if (idx < n) {
            int e = excl + loc[i];
            indptr[idx] = e;
            cursor[idx] = e;
        }
    }
    if (t == 0) indptr[n] = total;
}

__global__ void scatter_edges(const int* __restrict__ ei, int* __restrict__ cursor,
                              int* __restrict__ col, int E, int N) {
    int t = blockIdx.x * blockDim.x + threadIdx.x;
    if (t >= E + N) return;
    int src, dst;
    if (t < E) { src = ei[t]; dst = ei[E + t]; }
    else       { src = dst = t - E; }
    int pos = atomicAdd(&cursor[dst], 1);
    col[pos] = src;
}

// ---------------- fused one-shot weight prep --------------------------------
// bt layout per layer: bt[btOff + m*KA + h*Kp + k] = fp16(W[k*HC + h*C + m])
// wesed[weOff + k*2H + o] = sum_c W[k,h*C+c]*a[h,c]  (h=o%H, a=as/ad by o<H).
// wcomb (layer 4, 128x64): cols 0..31 = es/ed weights, cols 32..63 = W4 cols.
__global__ __launch_bounds__(256) void prep_all(
        const float* __restrict__ W0, const float* __restrict__ W1,
        const float* __restrict__ W2, const float* __restrict__ W3,
        const float* __restrict__ W4,
        const float* __restrict__ as0, const float* __restrict__ as1,
        const float* __restrict__ as2, const float* __restrict__ as3,
        const float* __restrict__ as4,
        const float* __restrict__ ad0, const float* __restrict__ ad1,
        const float* __restrict__ ad2, const float* __restrict__ ad3,
        const float* __restrict__ ad4,
        unsigned short* __restrict__ bt, float* __restrict__ wesed,
        float* __restrict__ wcomb) {
    const int Kc[5]  = {34, 64, 128, 256, 128};
    const int Kpc[5] = {64, 64, 128, 256, 128};        // L0 padded to 64
    const int Hc[5]  = {8, 16, 8, 8, 16};
    const int Cc[5]  = {64, 128, 256, 128, 2};
    const int HCc[5] = {512, 2048, 2048, 1024, 32};
    const int KAc[5] = {512, 1024, 1024, 2048, 2048};  // L0 KA = 8*64
    const int btOff[5] = {0, 32768, 163840, 425984, 0};
    const int weOff[5] = {0, 1024, 3072, 5120, 9216};

    int b = blockIdx.x, tid = threadIdx.x;

    if (b < 168) {
        // ---- LDS-tiled transpose, one (layer, head, 64x64 tile) per block --
        int lyr, tloc;
        if (b < 8)        { lyr = 0; tloc = b; }
        else if (b < 40)  { lyr = 1; tloc = b - 8; }
        else if (b < 104) { lyr = 2; tloc = b - 40; }
        else              { lyr = 3; tloc = b - 104; }
        const int ktl[4] = {1, 1, 2, 4};   // ceil(Kp/64)
        const int mtl[4] = {1, 2, 4, 2};   // ceil(C/64)
        int kt = ktl[lyr], mt = mtl[lyr];
        int per_h = kt * mt;
        int h = tloc / per_h, r = tloc - h * per_h;
        int ki = r % kt, mi = r / kt;
        int k0 = ki * 64, m0 = mi * 64;
        int K = Kc[lyr], Kp = Kpc[lyr], C = Cc[lyr], HC = HCc[lyr], KA = KAc[lyr];
        const float* W;
        if (lyr == 0) W = W0; else if (lyr == 1) W = W1;
        else if (lyr == 2) W = W2; else W = W3;

        __shared__ float tile[64][65];
        int c = tid & 63, rg = tid >> 6;
        for (int r2 = rg; r2 < 64; r2 += 4) {       // coalesced 256B reads
            int k = k0 + r2, m = m0 + c;
            float v = (k < K && m < C) ? W[(size_t)k * HC + h * C + m] : 0.f;
            tile[r2][c] = v;
        }
        __syncthreads();
        unsigned short* bp = bt + btOff[lyr];
        for (int mr = rg; mr < 64; mr += 4) {       // coalesced 128B fp16 writes
            int m = m0 + mr, k = k0 + c;
            if (m < C && k < Kp)
                bp[(size_t)m * KA + h * Kp + k] =
                    __half_as_ushort(__float2half(tile[c][mr]));
        }
    } else if (b < 200) {
        // ---- wcomb for layer 4: 8192 outputs (128 x 64) ----
        int u = (b - 168) * 256 + tid;
        int k = u >> 6, o = u & 63;
        float s;
        if (o < 32) {                       // es/ed weights
            int h = (o < 16) ? o : o - 16;
            const float* av = ((o < 16) ? as4 : ad4) + h * 2;
            s = W4[k * 32 + h * 2 + 0] * av[0] + W4[k * 32 + h * 2 + 1] * av[1];
        } else {                            // y projection: raw W4 column
            s = W4[k * 32 + (o - 32)];
        }
        wcomb[u] = s;
    } else {
        // ---- wesed dots: sizes {1024,2048,2048,4096,4096} -> 52 blocks ----
        int wb = b - 200;
        int lyr, u0;
        if (wb < 4)       { lyr = 0; u0 = wb * 256; }
        else if (wb < 12) { lyr = 1; u0 = (wb - 4) * 256; }
        else if (wb < 20) { lyr = 2; u0 = (wb - 12) * 256; }
        else if (wb < 36) { lyr = 3; u0 = (wb - 20) * 256; }
        else              { lyr = 4; u0 = (wb - 36) * 256; }
        int u = u0 + tid;
        int K = Kc[lyr], Kp = Kpc[lyr], H = Hc[lyr], C = Cc[lyr], HC = HCc[lyr];
        int H2 = 2 * H;
        if (u < Kp * H2) {
            int k = u / H2, o = u - k * H2;
            float s = 0.f;
            if (k < K) {
                int h = (o < H) ? o : o - H;
                const float *W, *as_, *ad_;
                if (lyr == 0)      { W = W0; as_ = as0; ad_ = ad0; }
                else if (lyr == 1) { W = W1; as_ = as1; ad_ = ad1; }
                else if (lyr == 2) { W = W2; as_ = as2; ad_ = ad2; }
                else if (lyr == 3) { W = W3; as_ = as3; ad_ = ad3; }
                else               { W = W4; as_ = as4; ad_ = ad4; }
                const float* av = ((o < H) ? as_ : ad_) + h * C;
                const float* wp = W + (size_t)k * HC + h * C;
#pragma unroll 4
                for (int c2 = 0; c2 < C; ++c2) s += wp[c2] * av[c2];
            }
            wesed[weOff[lyr] + u] = s;
        }
    }
}

// -------- fused attn+gather via LDS broadcast, pipelined (layers 0-3) -------
// TWO: esed is split into two K-half partials (esed, esed2) -> sum at load.
template <int H, int KP, int CH, int NPB, int TWO>
__global__ __launch_bounds__(NPB * (KP / CH)) void gat_fused_lds(
        const __half* __restrict__ hinf, const float* __restrict__ esed,
        const float* __restrict__ esed2,
        const int* __restrict__ indptr, const int* __restrict__ col,
        __half* __restrict__ g, int N) {
    const int TPN = KP / CH;
    const int EC  = TPN / H;
    const int H2  = 2 * H;
    __shared__ float lds_p[NPB][2][TPN];
    int sub = threadIdx.x / TPN;
    int j   = threadIdx.x % TPN;
    int n = blockIdx.x * NPB + sub;
    if (n >= N) return;
    int e_my = j / H, h_my = j % H;
    int c0 = j * CH;
    float edv = esed[n * H2 + H + h_my];
    if constexpr (TWO) edv += esed2[n * H2 + H + h_my];

    float acc[H][CH];
#pragma unroll
    for (int h = 0; h < H; ++h)
#pragma unroll
        for (int t = 0; t < CH; ++t) acc[h][t] = 0.f;
    float zloc = 0.f;

    int beg = indptr[n], deg = indptr[n + 1] - beg;

    // prologue: p for chunk 0
    float p = 0.f;
    if (e_my < deg) {
        int srcm = col[beg + e_my];
        float es0 = esed[srcm * H2 + h_my];
        if constexpr (TWO) es0 += esed2[srcm * H2 + h_my];
        p = expf(lrelu02(es0 + edv));
    }
    int buf = 0;
    for (int base = 0; base < deg; base += EC) {
        zloc += p;
        lds_p[sub][buf][j] = p;
        __builtin_amdgcn_wave_barrier();
        // issue next chunk's attention loads (exp after phase B)
        int ce = base + EC + e_my;
        bool vnext = (ce < deg);
        float esv = 0.f;
        if (vnext) {
            int srcm = col[beg + ce];
            esv = esed[srcm * H2 + h_my];
            if constexpr (TWO) esv += esed2[srcm * H2 + h_my];
        }
        // phase B: pipelined gather with LDS-broadcast alphas
#pragma unroll
        for (int e = 0; e < EC; ++e) {
            int idx = base + e;
            if (idx < deg) {                  // uniform within node group
                int src = col[beg + idx];
                float f[CH];
                if (CH == 2) {
                    __half2 hv = *(const __half2*)(hinf + (size_t)src * KP + c0);
                    float2 ff = __half22float2(hv);
                    f[0] = ff.x; f[1] = ff.y;
                } else {
                    half4v hv = *(const half4v*)(hinf + (size_t)src * KP + c0);
                    f[0] = (float)hv[0]; f[1] = (float)hv[1];
                    f[2] = (float)hv[2]; f[3] = (float)hv[3];
                }
                const float4* ap = (const float4*)&lds_p[sub][buf][e * H];
#pragma unroll
                for (int q4 = 0; q4 < H / 4; ++q4) {
                    float4 a4 = ap[q4];
#pragma unroll
                    for (int t = 0; t < CH; ++t) {
                        acc[4 * q4 + 0][t] += a4.x * f[t];
                        acc[4 * q4 + 1][t] += a4.y * f[t];
                        acc[4 * q4 + 2][t] += a4.z * f[t];
                        acc[4 * q4 + 3][t] += a4.w * f[t];
                    }
                }
            }
        }
        p = vnext ? expf(lrelu02(esv + edv)) : 0.f;
        buf ^= 1;
    }

    // z: reduce across the EC lanes of each head class
#pragma unroll
    for (int off = H; off < TPN; off <<= 1)
        zloc += __shfl_xor(zloc, off, TPN);
    float zinv_my = (1.f / H) / (zloc + 1e-16f);

    __half* gp = g + (size_t)n * (H * KP) + c0;
#pragma unroll
    for (int h = 0; h < H; ++h) {
        float zf = __shfl(zinv_my, h, TPN);   // lane class h holds z for head h
        if (CH == 2) {
            *(__half2*)(gp + h * KP) =
                __floats2half2_rn(acc[h][0] * zf, acc[h][1] * zf);
        } else {
            __half2 lo = __floats2half2_rn(acc[h][0] * zf, acc[h][1] * zf);
            __half2 hi = __floats2half2_rn(acc[h][2] * zf, acc[h][3] * zf);
            union { __half2 h2[2]; float2 f2; } u;
            u.h2[0] = lo; u.h2[1] = hi;
            *(float2*)(gp + h * KP) = u.f2;
        }
    }
}

// -------- layer 4: fused attention + projected gather + output --------------
template <int NPB>
__global__ __launch_bounds__(NPB * 32) void final_attn(
        const float* __restrict__ eyp, const int* __restrict__ indptr,
        const int* __restrict__ col, const float* __restrict__ b5,
        const unsigned* __restrict__ masks, const float* __restrict__ x,
        float* __restrict__ outp, int N) {
    int sub = threadIdx.x >> 5;
    int j   = threadIdx.x & 31;
    int n = blockIdx.x * NPB + sub;
    if (n >= N) return;
    int h = j >> 1;
    float edv = eyp[(size_t)n * 64 + 16 + h];
    int beg = indptr[n], end = indptr[n + 1];
    float z = 0.f, a = 0.f;
    int i = beg;
    for (; i + 1 < end; i += 2) {
        int s0 = col[i], s1 = col[i + 1];
        const float* r0 = eyp + (size_t)s0 * 64;
        const float* r1 = eyp + (size_t)s1 * 64;
        float es0 = r0[h], y0 = r0[32 + j];
        float es1 = r1[h], y1 = r1[32 + j];
        float p0 = expf(lrelu02(es0 + edv));
        float p1 = expf(lrelu02(es1 + edv));
        z += p0; a += p0 * y0;
        z += p1; a += p1 * y1;
    }
    for (; i < end; ++i) {
        const float* r = eyp + (size_t)col[i] * 64;
        float p = expf(lrelu02(r[h] + edv));
        z += p; a += p * r[32 + j];
    }
    float zf = (1.f / 16.f) / (z + 1e-16f);
    float val = a * zf;
#pragma unroll
    for (int off = 2; off <= 16; off <<= 1) val += __shfl_xor(val, off, 32);
    float other = __shfl_xor(val, 1, 32);        // opposite parity's sum
    if (j == 0) {
        unsigned mk = masks[n];
        float v0 = x[n * 10 + 0] + selu_f(val + b5[0]);
        float v1 = x[n * 10 + 1] + selu_f(other + b5[1]);
        if (mk & 2u) v0 = 0.f; else if (mk & 1u) v0 = 1.f;
        if (mk & 8u) v1 = 1.f; else if (mk & 4u) v1 = 0.f;
        outp[n * 2 + 0] = v0;
        outp[n * 2 + 1] = v1;
    }
}

// ---------------- LDS-staged f16 MFMA GEMMs ---------------------------------
#define LDP 72

// 64x64 tile (layer 0, C=64). EOUT>0: fused next-layer esed from LDS tile.
template <int EOUT>
__global__ __launch_bounds__(256) void gemm_lds(const __half* __restrict__ A,
                                                const unsigned short* __restrict__ Bhi,
                                                const float* __restrict__ bias,
                                                const unsigned* __restrict__ masks,
                                                __half* __restrict__ O16,
                                                const float* __restrict__ wnext,
                                                float* __restrict__ eout,
                                                int N, int K, int M) {
    __shared__ __half lA[64 * LDP], lB[64 * LDP];
    __shared__ float vt[EOUT ? 64 : 1][EOUT ? 68 : 1];
    int tid = threadIdx.x;
    int wave = tid >> 6, lane = tid & 63;
    int ln16 = lane & 15, q = lane >> 4;
    int row0 = blockIdx.x * 64;
    int col0 = blockIdx.y * 64;

    int r0 = tid >> 3, r1 = r0 + 32;
    int ac = (tid & 7) * 8;
    int ga0 = min(row0 + r0, N - 1);
    int ga1 = min(row0 + r1, N - 1);
    const __half* Bp = (const __half*)Bhi;
    const __half* a0p = A + (size_t)ga0 * K + ac;
    const __half* a1p = A + (size_t)ga1 * K + ac;
    const __half* b0p = Bp + (size_t)(col0 + r0) * K + ac;
    const __half* b1p = Bp + (size_t)(col0 + r1) * K + ac;

    half8 ra0 = *(const half8*)(a0p);
    half8 ra1 = *(const half8*)(a1p);
    half8 rb0 = *(const half8*)(b0p);
    half8 rb1 = *(const half8*)(b1p);

    f32x4 acc[4];
#pragma unroll
    for (int j = 0; j < 4; ++j) acc[j] = (f32x4){0.f, 0.f, 0.f, 0.f};

    for (int kc = 0; kc < K; kc += 64) {
        __syncthreads();
        *(half8*)(lA + r0 * LDP + ac) = ra0;
        *(half8*)(lA + r1 * LDP + ac) = ra1;
        *(half8*)(lB + r0 * LDP + ac) = rb0;
        *(half8*)(lB + r1 * LDP + ac) = rb1;
        __syncthreads();
        int kn = kc + 64;
        if (kn < K) {
            ra0 = *(const half8*)(a0p + kn);
            ra1 = *(const half8*)(a1p + kn);
            rb0 = *(const half8*)(b0p + kn);
            rb1 = *(const half8*)(b1p + kn);
        }
#pragma unroll
        for (int kk = 0; kk < 2; ++kk) {
            half8 af = *(const half8*)(lA + (wave * 16 + ln16) * LDP + kk * 32 + q * 8);
#pragma unroll
            for (int j = 0; j < 4; ++j) {
                half8 bf = *(const half8*)(lB + (j * 16 + ln16) * LDP + kk * 32 + q * 8);
                acc[j] = __builtin_amdgcn_mfma_f32_16x16x32_f16(af, bf, acc[j], 0, 0, 0);
            }
        }
    }

#pragma unroll
    for (int j = 0; j < 4; ++j) {
        int cc = col0 + j * 16 + ln16;
        float bv = bias[cc];
#pragma unroll
        for (int r = 0; r < 4; ++r) {
            int rr = row0 + wave * 16 + q * 4 + r;
            float v = selu_f(acc[j][r] + bv);
            if (cc < 2 && rr < N) {
                unsigned mk = masks[rr];
                if (cc == 0) { if (mk & 2u) v = 0.f; else if (mk & 1u) v = 1.f; }
                else         { if (mk & 8u) v = 1.f; else if (mk & 4u) v = 0.f; }
            }
            __half hv = __float2half(v);
            if (rr < N) O16[(size_t)rr * M + cc] = hv;
            if constexpr (EOUT > 0)
                vt[wave * 16 + q * 4 + r][j * 16 + ln16] = __half2float(hv);
        }
    }

    if constexpr (EOUT > 0) {
        __syncthreads();
        const int NG = 256 / EOUT;     // row-groups (8 for EOUT=32)
        const int NI = 64 / NG;        // rows per thread (8)
        int o = tid & (EOUT - 1);
        int ngrp = tid / EOUT;
        const float* wp = wnext + (size_t)col0 * EOUT;
        float* ep = eout + (size_t)blockIdx.y * N * EOUT;
        float s[NI];
#pragma unroll
        for (int i = 0; i < NI; ++i) s[i] = 0.f;
        for (int k = 0; k < 64; ++k) {
            float wk = wp[k * EOUT + o];
#pragma unroll
            for (int i = 0; i < NI; ++i)
                s[i] += vt[ngrp + NG * i][k] * wk;
        }
#pragma unroll
        for (int i = 0; i < NI; ++i) {
            int n = row0 + ngrp + NG * i;
            if (n < N) ep[(size_t)n * EOUT + o] = s[i];
        }
    }
}

// 32x128 tile (layers 1-3). EOUT>0: fused next-layer esed/eyp. For grid.y>1,
// each col-block writes its K-half partial to eout + blockIdx.y*N*EOUT using
// weight rows [col0, col0+128).
template <int EOUT>
__global__ __launch_bounds__(256) void gemm_rc(const __half* __restrict__ A,
                                               const unsigned short* __restrict__ Bhi,
                                               const float* __restrict__ bias,
                                               const unsigned* __restrict__ masks,
                                               __half* __restrict__ O16,
                                               const float* __restrict__ wnext,
                                               float* __restrict__ eout,
                                               int N, int K, int M) {
    __shared__ __half lA[32 * LDP], lB[128 * LDP];
    __shared__ float vt[EOUT ? 32 : 1][EOUT ? 132 : 1];
    int tid = threadIdx.x;
    int wave = tid >> 6, lane = tid & 63;
    int ln16 = lane & 15, q = lane >> 4;
    int row0 = blockIdx.x * 32;
    int col0 = blockIdx.y * 128;
    int wr = (wave >> 1) * 16;
    int wc = (wave & 1) * 64;

    int ar = tid >> 3;                       // 0..31
    int ac = (tid & 7) * 8;
    int ga = min(row0 + ar, N - 1);
    const __half* ap  = A + (size_t)ga * K + ac;
    const __half* Bp  = (const __half*)Bhi;
    const __half* b0p = Bp + (size_t)(col0 + ar) * K + ac;
    const __half* b1p = Bp + (size_t)(col0 + ar + 32) * K + ac;
    const __half* b2p = Bp + (size_t)(col0 + ar + 64) * K + ac;
    const __half* b3p = Bp + (size_t)(col0 + ar + 96) * K + ac;

    half8 ra  = *(const half8*)(ap);
    half8 rb0 = *(const half8*)(b0p);
    half8 rb1 = *(const half8*)(b1p);
    half8 rb2 = *(const half8*)(b2p);
    half8 rb3 = *(const half8*)(b3p);

    f32x4 acc[4];
#pragma unroll
    for (int j = 0; j < 4; ++j) acc[j] = (f32x4){0.f, 0.f, 0.f, 0.f};

    for (int kc = 0; kc < K; kc += 64) {
        __syncthreads();
        *(half8*)(lA + ar * LDP + ac)        = ra;
        *(half8*)(lB + ar * LDP + ac)        = rb0;
        *(half8*)(lB + (ar + 32) * LDP + ac) = rb1;
        *(half8*)(lB + (ar + 64) * LDP + ac) = rb2;
        *(half8*)(lB + (ar + 96) * LDP + ac) = rb3;
        __syncthreads();
        int kn = kc + 64;
        if (kn < K) {
            ra  = *(const half8*)(ap + kn);
            rb0 = *(const half8*)(b0p + kn);
            rb1 = *(const half8*)(b1p + kn);
            rb2 = *(const half8*)(b2p + kn);
            rb3 = *(const half8*)(b3p + kn);
        }
#pragma unroll
        for (int kk = 0; kk < 2; ++kk) {
            half8 af = *(const half8*)(lA + (wr + ln16) * LDP + kk * 32 + q * 8);
#pragma unroll
            for (int j = 0; j < 4; ++j) {
                half8 bf = *(const half8*)(lB + (wc + j * 16 + ln16) * LDP + kk * 32 + q * 8);
                acc[j] = __builtin_amdgcn_mfma_f32_16x16x32_f16(af, bf, acc[j], 0, 0, 0);
            }
        }
    }

#pragma unroll
    for (int j = 0; j < 4; ++j) {
        int cc = col0 + wc + j * 16 + ln16;
        float bv = bias[cc];
#pragma unroll
        for (int r = 0; r < 4; ++r) {
            int rr = row0 + wr + q * 4 + r;
            float v = selu_f(acc[j][r] + bv);
            if (cc < 2 && rr < N) {
                unsigned mk = masks[rr];
                if (cc == 0) { if (mk & 2u) v = 0.f; else if (mk & 1u) v = 1.f; }
                else         { if (mk & 8u) v = 1.f; else if (mk & 4u) v = 0.f; }
            }
            __half hv = __float2half(v);
            if (rr < N) O16[(size_t)rr * M + cc] = hv;
            if constexpr (EOUT > 0)
                vt[wr + q * 4 + r][wc + j * 16 + ln16] = __half2float(hv);
        }
    }

    if constexpr (EOUT > 0) {
        __syncthreads();
        const int NG = 256 / EOUT;     // row-groups (16 for EOUT=16, 4 for 64)
        const int NI = 32 / NG;        // rows per thread (2 / 8)
        int o = tid & (EOUT - 1);
        int ngrp = tid / EOUT;
        const float* wp = wnext + (size_t)col0 * EOUT;
        float* ep = eout + (size_t)blockIdx.y * N * EOUT;
        float s[NI];
#pragma unroll
        for (int i = 0; i < NI; ++i) s[i] = 0.f;
        for (int k = 0; k < 128; ++k) {
            float wk = wp[k * EOUT + o];
#pragma unroll
            for (int i = 0; i < NI; ++i)
                s[i] += vt[ngrp + NG * i][k] * wk;
        }
#pragma unroll
        for (int i = 0; i < NI; ++i) {
            int n = row0 + ngrp + NG * i;
            if (n < N) ep[(size_t)n * EOUT + o] = s[i];
        }
    }
}

// ---------------------------------------------------------------------------
extern "C" void kernel_launch(void* const* d_in, const int* in_sizes, int n_in,
                              void* d_out, int out_size, void* d_ws, size_t ws_size,
                              hipStream_t stream) {
    const float* x   = (const float*)d_in[0];
    const int*   ei  = (const int*)d_in[1];
    const float* cf  = (const float*)d_in[2];
    const float* cw[4] = {(const float*)d_in[3], (const float*)d_in[5],
                          (const float*)d_in[7], (const float*)d_in[9]};
    const float* cb[4] = {(const float*)d_in[4], (const float*)d_in[6],
                          (const float*)d_in[8], (const float*)d_in[10]};
    const float* gw[5], *gas[5], *gad[5], *gb[5];
    for (int i = 0; i < 5; ++i) {
        gw[i]  = (const float*)d_in[11 + 4 * i];
        gas[i] = (const float*)d_in[12 + 4 * i];
        gad[i] = (const float*)d_in[13 + 4 * i];
        gb[i]  = (const float*)d_in[14 + 4 * i];
    }
    const int N = in_sizes[0] / 10;        // 10000
    const int E = in_sizes[1] / 2;         // 160000
    const int EN = E + N;

    // ---- workspace carve-up ----
    char* base = (char*)d_ws;
    size_t off = 0;
    auto alloc = [&](size_t bytes) -> char* {
        char* p = base + off;
        off = (off + bytes + 255) & ~(size_t)255;
        return p;
    };
    float* c1p   = (float*)alloc((size_t)16 * PSZ * 4);
    float* c2p   = (float*)alloc((size_t)32 * PSZ * 4);
    float* c3p   = (float*)alloc((size_t)64 * PSZ * 4);
    float* c4p   = (float*)alloc((size_t)24 * PSZ * 4);
    float* gfeat = (float*)alloc(24 * 4);
    __half* hA16 = (__half*)alloc((size_t)N * 256 * 2);
    __half* hB16 = (__half*)alloc((size_t)N * 256 * 2);
    __half* g    = (__half*)alloc((size_t)N * 2048 * 2);
    float* esed  = (float*)alloc((size_t)N * 32 * 4);        // also 2x N*16 partials
    float* eyp   = (float*)alloc((size_t)N * 64 * 4);        // L4 [es|ed|y]
    float* wesed = (float*)alloc((size_t)13312 * 4);         // layers 0-4
    float* wcomb = (float*)alloc((size_t)8192 * 4);          // L4 combined weights
    unsigned short* bt = (unsigned short*)alloc((size_t)688128 * 2);  // 4 GEMM layers
    unsigned* masks = (unsigned*)alloc((size_t)N * 4);
    int* cnt    = (int*)alloc((size_t)N * 4);
    int* indptr = (int*)alloc((size_t)(N + 1) * 4);
    int* cursor = (int*)alloc((size_t)N * 4);
    int* col    = (int*)alloc((size_t)EN * 4);
    (void)ws_size; // ~70 MB

    // ---- one-shot fused weight prep (all 5 layers) ----
    prep_all<<<252, 256, 0, stream>>>(gw[0], gw[1], gw[2], gw[3], gw[4],
                                      gas[0], gas[1], gas[2], gas[3], gas[4],
                                      gad[0], gad[1], gad[2], gad[3], gad[4],
                                      bt, wesed, wcomb);

    // ---- CNN (padded layout; memset zeroes intermediate borders) ----
    hipMemsetAsync(c1p, 0, (size_t)136 * PSZ * 4, stream);
    conv3x3_first<<<dim3(16, 16), 256, 0, stream>>>(cf, cw[0], cb[0], c1p);
    conv3x3_pad<16><<<dim3(16, 32), 256, 0, stream>>>(c1p, cw[1], cb[1], c2p);
    conv3x3_pad<32><<<dim3(16, 64), 256, 0, stream>>>(c2p, cw[2], cb[2], c3p);
    conv3x3_pad<64><<<dim3(16, 24), 256, 0, stream>>>(c3p, cw[3], cb[3], c4p);
    avgpool_c<<<24, 256, 0, stream>>>(c4p, gfeat);

    // ---- h0 (padded to 64, fp16) + masks + fused L0 esed ----
    build_h0<<<(N + 255) / 256, 256, 0, stream>>>(x, gfeat, wesed + 0, hA16, masks,
                                                  esed, N);

    // ---- CSR by dst (incl self loops): count, one-block scan, scatter ----
    hipMemsetAsync(cnt, 0, (size_t)N * 4, stream);
    count_dst<<<(EN + 255) / 256, 256, 0, stream>>>(ei, cnt, E, N);
    scan_all<<<1, 1024, 0, stream>>>(cnt, indptr, cursor, N, EN);
    scatter_edges<<<(EN + 255) / 256, 256, 0, stream>>>(ei, cursor, col, E, N);

    // ---- GAT layers (all esed/eyp hand-offs fused into producers) ----
    int gx32 = (N + 31) / 32;   // 313
    int gx64 = (N + 63) / 64;   // 157

    // L0: Kp=64 H=8 C=64 KA=512 ; esed came from build_h0
    gat_fused_lds<8, 64, 4, 16, 0><<<(N + 15) / 16, 256, 0, stream>>>(
        hA16, esed, nullptr, indptr, col, g, N);
    gemm_lds<32><<<dim3(gx64, 1), 256, 0, stream>>>(g, bt + 0, gb[0], masks, hB16,
                                                    wesed + 1024, esed, N, 512, 64);

    // L1: Kp=64 H=16 C=128 KA=1024 ; esed (H2=32) from L0 gemm
    gat_fused_lds<16, 64, 2, 8, 0><<<(N + 7) / 8, 256, 0, stream>>>(
        hB16, esed, nullptr, indptr, col, g, N);
    gemm_rc<16><<<dim3(gx32, 1), 256, 0, stream>>>(g, bt + 32768, gb[1], masks, hA16,
                                                   wesed + 3072, esed, N, 1024, 128);

    // L2: Kp=128 H=8 C=256 KA=1024 ; esed (H2=16) from L1 gemm; L3's esed
    // produced as two K-half partials by the two col-blocks (grid.y=2)
    gat_fused_lds<8, 128, 4, 8, 0><<<(N + 7) / 8, 256, 0, stream>>>(
        hA16, esed, nullptr, indptr, col, g, N);
    gemm_rc<16><<<dim3(gx32, 2), 256, 0, stream>>>(g, bt + 163840, gb[2], masks, hB16,
                                                   wesed + 5120, esed, N, 1024, 256);

    // L3: Kp=256 H=8 C=128 KA=2048 ; esed = partial A + partial B
    gat_fused_lds<8, 256, 4, 4, 1><<<(N + 3) / 4, 256, 0, stream>>>(
        hB16, esed, esed + (size_t)N * 16, indptr, col, g, N);
    gemm_rc<64><<<dim3(gx32, 1), 256, 0, stream>>>(g, bt + 425984, gb[3], masks, hA16,
                                                   wcomb, eyp, N, 2048, 128);

    // L4: project-first fused final layer
    final_attn<8><<<(N + 7) / 8, 256, 0, stream>>>(eyp, indptr, col, gb[4],
                                                   masks, x, (float*)d_out, N);
}

// Round 16
// 428.986 us; speedup vs baseline: 1.1958x; 1.0097x over previous
//
#include <hip/hip_runtime.h>
#include <hip/hip_fp16.h>
#include <math.h>

// ---------------------------------------------------------------------------
// NetGlobGATFix. R32: GEMM grid-starvation fix (16-row tiles, unified gemm16).
//   - R31 counters: L2 gemm_rc 44.4us @ 630 GB/s, Occupancy 11% -- grid 626
//     blocks = 2.4/CU, serial barrier'd K-loop, nothing to hide latency.
//     L0's gemm was worse (grid 157 = 0.6 blocks/CU).
//   - gemm16<CW,EOUT>: 16 rows x CW cols, 4 waves each own CW/4 cols.
//     Grid 625 (L0/L1/L3) / 1250 (L2). Per-output MFMA sequence and EOUT
//     epilogue sums identical to R31 (bit-identical numerics).
//   - Everything else identical to R31 (433.1us best).
// ---------------------------------------------------------------------------

#define DEVFN static __device__ __forceinline__

typedef __attribute__((ext_vector_type(8))) _Float16 half8;
typedef __attribute__((ext_vector_type(4))) _Float16 half4v;
typedef __attribute__((ext_vector_type(4))) float f32x4;

DEVFN float selu_f(float v) {
    const float scale = 1.0507009873554805f;
    const float alpha = 1.6732632423543772f;
    return v > 0.f ? scale * v : scale * alpha * (expf(v) - 1.f);
}

DEVFN float lrelu02(float v) { return v > 0.f ? v : 0.2f * v; }

// ---------------- CNN (padded 66x66 layout) ----------------
#define PST 66
#define PSZ (66 * 66)

// first conv: reads raw 4x64x64 input with boundary guards, writes padded c1p
__global__ __launch_bounds__(256) void conv3x3_first(const float* __restrict__ cf,
                                                     const float* __restrict__ w,
                                                     const float* __restrict__ b,
                                                     float* __restrict__ out) {
    int x  = threadIdx.x & 63;
    int yg = threadIdx.x >> 6;
    int y  = blockIdx.x * 4 + yg;          // 0..63
    int co = blockIdx.y;
    float acc = b[co];
    const float* wp = w + (size_t)co * 4 * 9;
#pragma unroll
    for (int ci = 0; ci < 4; ++ci) {
        const float* ip = cf + ci * 4096;
        const float* wr = wp + ci * 9;
#pragma unroll
        for (int ky = 0; ky < 3; ++ky) {
            int yy = y + ky - 1;
            if (yy < 0 || yy >= 64) continue;
#pragma unroll
            for (int kx = 0; kx < 3; ++kx) {
                int xx = x + kx - 1;
                if (xx < 0 || xx >= 64) continue;
                acc += wr[ky * 3 + kx] * ip[yy * 64 + xx];
            }
        }
    }
    out[(size_t)co * PSZ + (y + 1) * PST + (x + 1)] = selu_f(acc);
}

template <int CIN>
__global__ __launch_bounds__(256) void conv3x3_pad(const float* __restrict__ in,
                                                   const float* __restrict__ w,
                                                   const float* __restrict__ b,
                                                   float* __restrict__ out) {
    int x  = threadIdx.x & 63;
    int yg = threadIdx.x >> 6;
    int y  = blockIdx.x * 4 + yg;          // 0..63
    int co = blockIdx.y;
    float acc = b[co];
    const float* wp = w + (size_t)co * CIN * 9;
#pragma unroll 4
    for (int ci = 0; ci < CIN; ++ci) {
        const float* ip = in + ci * PSZ + y * PST + x;
        const float* wr = wp + ci * 9;
        acc += wr[0] * ip[0]           + wr[1] * ip[1]           + wr[2] * ip[2]
             + wr[3] * ip[PST]         + wr[4] * ip[PST + 1]     + wr[5] * ip[PST + 2]
             + wr[6] * ip[2 * PST]     + wr[7] * ip[2 * PST + 1] + wr[8] * ip[2 * PST + 2];
    }
    out[(size_t)co * PSZ + (y + 1) * PST + (x + 1)] = selu_f(acc);
}

__global__ void avgpool_c(const float* __restrict__ in, float* __restrict__ gfeat) {
    int c = blockIdx.x;            // 24 blocks
    int t = threadIdx.x;           // 256 threads
    float s = 0.f;
    for (int i = t; i < 4096; i += 256) {
        int y = i >> 6, x = i & 63;
        s += in[c * PSZ + (y + 1) * PST + (x + 1)];
    }
#pragma unroll
    for (int off = 32; off >= 1; off >>= 1) s += __shfl_xor(s, off);
    __shared__ float red[4];
    int wave = t >> 6, lane = t & 63;
    if (lane == 0) red[wave] = s;
    __syncthreads();
    if (t == 0) gfeat[c] = (red[0] + red[1] + red[2] + red[3]) * (1.f / 4096.f);
}

// ---------------- node feature init (padded to 64 ch, fp16) + masks ---------
// Fused L0 esed: per node, 16 dots over the fp16-rounded features.
__global__ void build_h0(const float* __restrict__ x, const float* __restrict__ gfeat,
                         const float* __restrict__ we0,
                         __half* __restrict__ h0f, unsigned* __restrict__ masks,
                         float* __restrict__ esed, int N) {
    int n = blockIdx.x * blockDim.x + threadIdx.x;
    if (n >= N) return;
    float x0 = x[n * 10 + 0], x1 = x[n * 10 + 1];
    unsigned mk = (x0 == 1.f ? 1u : 0u) | (x0 == 0.f ? 2u : 0u) |
                  (x1 == 0.f ? 4u : 0u) | (x1 == 1.f ? 8u : 0u);
    masks[n] = mk;
    __half* hq = h0f + (size_t)n * 64;
    float hf[64];
#pragma unroll
    for (int j = 0; j < 64; ++j) {
        float v = (j < 24) ? gfeat[j] : (j < 34 ? x[n * 10 + (j - 24)] : 0.f);
        __half hv = __float2half(v);
        hq[j] = hv;
        hf[j] = __half2float(hv);
    }
    float s[16];
#pragma unroll
    for (int o = 0; o < 16; ++o) s[o] = 0.f;
    for (int k = 0; k < 64; ++k) {
        float f = hf[k];
        const float* wk = we0 + k * 16;
#pragma unroll
        for (int o = 0; o < 16; ++o) s[o] += f * wk[o];
    }
#pragma unroll
    for (int o = 0; o < 16; ++o) esed[(size_t)n * 16 + o] = s[o];
}

// ---------------- CSR build ----------------
__global__ void count_dst(const int* __restrict__ ei, int* __restrict__ cnt, int E, int N) {
    int t = blockIdx.x * blockDim.x + threadIdx.x;
    if (t >= E + N) return;
    int dst = (t < E) ? ei[E + t] : (t - E);
    atomicAdd(&cnt[dst], 1);
}

// single-block exclusive scan over n<=10240 counts (10 elems/thread, 1024 thr)
__global__ __launch_bounds__(1024) void scan_all(const int* __restrict__ cnt,
                                                 int* __restrict__ indptr,
                                                 int* __restrict__ cursor,
                                                 int n, int total) {
    __shared__ int sdata[1024];
    int t = threadIdx.x;
    int base = t * 10;
    int loc[10];
    int s = 0;
#pragma unroll
    for (int i = 0; i < 10; ++i) {
        int idx = base + i;
        int v = (idx < n) ? cnt[idx] : 0;
        loc[i] = s;                     // exclusive prefix within thread
        s += v;
    }
    sdata[t] = s;
    __syncthreads();
    for (int off = 1; off < 1024; off <<= 1) {
        int tmp = (t >= off) ? sdata[t - off] : 0;
        __syncthreads();
        sdata[t] += tmp;
        __syncthreads();
    }
    int excl = (t == 0) ? 0 : sdata[t - 1];
#pragma unroll
    for (int i = 0; i < 10; ++i) {
        int idx = base + i;
        if (idx < n) {
            int e = excl + loc[i];
            indptr[idx] = e;
            cursor[idx] = e;
        }
    }
    if (t == 0) indptr[n] = total;
}

__global__ void scatter_edges(const int* __restrict__ ei, int* __restrict__ cursor,
                              int* __restrict__ col, int E, int N) {
    int t = blockIdx.x * blockDim.x + threadIdx.x;
    if (t >= E + N) return;
    int src, dst;
    if (t < E) { src = ei[t]; dst = ei[E + t]; }
    else       { src = dst = t - E; }
    int pos = atomicAdd(&cursor[dst], 1);
    col[pos] = src;
}

// ---------------- fused one-shot weight prep --------------------------------
__global__ __launch_bounds__(256) void prep_all(
        const float* __restrict__ W0, const float* __restrict__ W1,
        const float* __restrict__ W2, const float* __restrict__ W3,
        const float* __restrict__ W4,
        const float* __restrict__ as0, const float* __restrict__ as1,
        const float* __restrict__ as2, const float* __restrict__ as3,
        const float* __restrict__ as4,
        const float* __restrict__ ad0, const float* __restrict__ ad1,
        const float* __restrict__ ad2, const float* __restrict__ ad3,
        const float* __restrict__ ad4,
        unsigned short* __restrict__ bt, float* __restrict__ wesed,
        float* __restrict__ wcomb) {
    const int Kc[5]  = {34, 64, 128, 256, 128};
    const int Kpc[5] = {64, 64, 128, 256, 128};        // L0 padded to 64
    const int Hc[5]  = {8, 16, 8, 8, 16};
    const int Cc[5]  = {64, 128, 256, 128, 2};
    const int HCc[5] = {512, 2048, 2048, 1024, 32};
    const int KAc[5] = {512, 1024, 1024, 2048, 2048};  // L0 KA = 8*64
    const int btOff[5] = {0, 32768, 163840, 425984, 0};
    const int weOff[5] = {0, 1024, 3072, 5120, 9216};

    int b = blockIdx.x, tid = threadIdx.x;

    if (b < 168) {
        // ---- LDS-tiled transpose, one (layer, head, 64x64 tile) per block --
        int lyr, tloc;
        if (b < 8)        { lyr = 0; tloc = b; }
        else if (b < 40)  { lyr = 1; tloc = b - 8; }
        else if (b < 104) { lyr = 2; tloc = b - 40; }
        else              { lyr = 3; tloc = b - 104; }
        const int ktl[4] = {1, 1, 2, 4};   // ceil(Kp/64)
        const int mtl[4] = {1, 2, 4, 2};   // ceil(C/64)
        int kt = ktl[lyr], mt = mtl[lyr];
        int per_h = kt * mt;
        int h = tloc / per_h, r = tloc - h * per_h;
        int ki = r % kt, mi = r / kt;
        int k0 = ki * 64, m0 = mi * 64;
        int K = Kc[lyr], Kp = Kpc[lyr], C = Cc[lyr], HC = HCc[lyr], KA = KAc[lyr];
        const float* W;
        if (lyr == 0) W = W0; else if (lyr == 1) W = W1;
        else if (lyr == 2) W = W2; else W = W3;

        __shared__ float tile[64][65];
        int c = tid & 63, rg = tid >> 6;
        for (int r2 = rg; r2 < 64; r2 += 4) {       // coalesced 256B reads
            int k = k0 + r2, m = m0 + c;
            float v = (k < K && m < C) ? W[(size_t)k * HC + h * C + m] : 0.f;
            tile[r2][c] = v;
        }
        __syncthreads();
        unsigned short* bp = bt + btOff[lyr];
        for (int mr = rg; mr < 64; mr += 4) {       // coalesced 128B fp16 writes
            int m = m0 + mr, k = k0 + c;
            if (m < C && k < Kp)
                bp[(size_t)m * KA + h * Kp + k] =
                    __half_as_ushort(__float2half(tile[c][mr]));
        }
    } else if (b < 200) {
        // ---- wcomb for layer 4: 8192 outputs (128 x 64) ----
        int u = (b - 168) * 256 + tid;
        int k = u >> 6, o = u & 63;
        float s;
        if (o < 32) {                       // es/ed weights
            int h = (o < 16) ? o : o - 16;
            const float* av = ((o < 16) ? as4 : ad4) + h * 2;
            s = W4[k * 32 + h * 2 + 0] * av[0] + W4[k * 32 + h * 2 + 1] * av[1];
        } else {                            // y projection: raw W4 column
            s = W4[k * 32 + (o - 32)];
        }
        wcomb[u] = s;
    } else {
        // ---- wesed dots: sizes {1024,2048,2048,4096,4096} -> 52 blocks ----
        int wb = b - 200;
        int lyr, u0;
        if (wb < 4)       { lyr = 0; u0 = wb * 256; }
        else if (wb < 12) { lyr = 1; u0 = (wb - 4) * 256; }
        else if (wb < 20) { lyr = 2; u0 = (wb - 12) * 256; }
        else if (wb < 36) { lyr = 3; u0 = (wb - 20) * 256; }
        else              { lyr = 4; u0 = (wb - 36) * 256; }
        int u = u0 + tid;
        int K = Kc[lyr], Kp = Kpc[lyr], H = Hc[lyr], C = Cc[lyr], HC = HCc[lyr];
        int H2 = 2 * H;
        if (u < Kp * H2) {
            int k = u / H2, o = u - k * H2;
            float s = 0.f;
            if (k < K) {
                int h = (o < H) ? o : o - H;
                const float *W, *as_, *ad_;
                if (lyr == 0)      { W = W0; as_ = as0; ad_ = ad0; }
                else if (lyr == 1) { W = W1; as_ = as1; ad_ = ad1; }
                else if (lyr == 2) { W = W2; as_ = as2; ad_ = ad2; }
                else if (lyr == 3) { W = W3; as_ = as3; ad_ = ad3; }
                else               { W = W4; as_ = as4; ad_ = ad4; }
                const float* av = ((o < H) ? as_ : ad_) + h * C;
                const float* wp = W + (size_t)k * HC + h * C;
#pragma unroll 4
                for (int c2 = 0; c2 < C; ++c2) s += wp[c2] * av[c2];
            }
            wesed[weOff[lyr] + u] = s;
        }
    }
}

// -------- fused attn+gather via LDS broadcast, pipelined (layers 0-3) -------
// TWO: esed is split into two K-half partials (esed, esed2) -> sum at load.
template <int H, int KP, int CH, int NPB, int TWO>
__global__ __launch_bounds__(NPB * (KP / CH)) void gat_fused_lds(
        const __half* __restrict__ hinf, const float* __restrict__ esed,
        const float* __restrict__ esed2,
        const int* __restrict__ indptr, const int* __restrict__ col,
        __half* __restrict__ g, int N) {
    const int TPN = KP / CH;
    const int EC  = TPN / H;
    const int H2  = 2 * H;
    __shared__ float lds_p[NPB][2][TPN];
    int sub = threadIdx.x / TPN;
    int j   = threadIdx.x % TPN;
    int n = blockIdx.x * NPB + sub;
    if (n >= N) return;
    int e_my = j / H, h_my = j % H;
    int c0 = j * CH;
    float edv = esed[n * H2 + H + h_my];
    if constexpr (TWO) edv += esed2[n * H2 + H + h_my];

    float acc[H][CH];
#pragma unroll
    for (int h = 0; h < H; ++h)
#pragma unroll
        for (int t = 0; t < CH; ++t) acc[h][t] = 0.f;
    float zloc = 0.f;

    int beg = indptr[n], deg = indptr[n + 1] - beg;

    // prologue: p for chunk 0
    float p = 0.f;
    if (e_my < deg) {
        int srcm = col[beg + e_my];
        float es0 = esed[srcm * H2 + h_my];
        if constexpr (TWO) es0 += esed2[srcm * H2 + h_my];
        p = expf(lrelu02(es0 + edv));
    }
    int buf = 0;
    for (int base = 0; base < deg; base += EC) {
        zloc += p;
        lds_p[sub][buf][j] = p;
        __builtin_amdgcn_wave_barrier();
        // issue next chunk's attention loads (exp after phase B)
        int ce = base + EC + e_my;
        bool vnext = (ce < deg);
        float esv = 0.f;
        if (vnext) {
            int srcm = col[beg + ce];
            esv = esed[srcm * H2 + h_my];
            if constexpr (TWO) esv += esed2[srcm * H2 + h_my];
        }
        // phase B: pipelined gather with LDS-broadcast alphas
#pragma unroll
        for (int e = 0; e < EC; ++e) {
            int idx = base + e;
            if (idx < deg) {                  // uniform within node group
                int src = col[beg + idx];
                float f[CH];
                if (CH == 2) {
                    __half2 hv = *(const __half2*)(hinf + (size_t)src * KP + c0);
                    float2 ff = __half22float2(hv);
                    f[0] = ff.x; f[1] = ff.y;
                } else {
                    half4v hv = *(const half4v*)(hinf + (size_t)src * KP + c0);
                    f[0] = (float)hv[0]; f[1] = (float)hv[1];
                    f[2] = (float)hv[2]; f[3] = (float)hv[3];
                }
                const float4* ap = (const float4*)&lds_p[sub][buf][e * H];
#pragma unroll
                for (int q4 = 0; q4 < H / 4; ++q4) {
                    float4 a4 = ap[q4];
#pragma unroll
                    for (int t = 0; t < CH; ++t) {
                        acc[4 * q4 + 0][t] += a4.x * f[t];
                        acc[4 * q4 + 1][t] += a4.y * f[t];
                        acc[4 * q4 + 2][t] += a4.z * f[t];
                        acc[4 * q4 + 3][t] += a4.w * f[t];
                    }
                }
            }
        }
        p = vnext ? expf(lrelu02(esv + edv)) : 0.f;
        buf ^= 1;
    }

    // z: reduce across the EC lanes of each head class
#pragma unroll
    for (int off = H; off < TPN; off <<= 1)
        zloc += __shfl_xor(zloc, off, TPN);
    float zinv_my = (1.f / H) / (zloc + 1e-16f);

    __half* gp = g + (size_t)n * (H * KP) + c0;
#pragma unroll
    for (int h = 0; h < H; ++h) {
        float zf = __shfl(zinv_my, h, TPN);   // lane class h holds z for head h
        if (CH == 2) {
            *(__half2*)(gp + h * KP) =
                __floats2half2_rn(acc[h][0] * zf, acc[h][1] * zf);
        } else {
            __half2 lo = __floats2half2_rn(acc[h][0] * zf, acc[h][1] * zf);
            __half2 hi = __floats2half2_rn(acc[h][2] * zf, acc[h][3] * zf);
            union { __half2 h2[2]; float2 f2; } u;
            u.h2[0] = lo; u.h2[1] = hi;
            *(float2*)(gp + h * KP) = u.f2;
        }
    }
}

// -------- layer 4: fused attention + projected gather + output --------------
template <int NPB>
__global__ __launch_bounds__(NPB * 32) void final_attn(
        const float* __restrict__ eyp, const int* __restrict__ indptr,
        const int* __restrict__ col, const float* __restrict__ b5,
        const unsigned* __restrict__ masks, const float* __restrict__ x,
        float* __restrict__ outp, int N) {
    int sub = threadIdx.x >> 5;
    int j   = threadIdx.x & 31;
    int n = blockIdx.x * NPB + sub;
    if (n >= N) return;
    int h = j >> 1;
    float edv = eyp[(size_t)n * 64 + 16 + h];
    int beg = indptr[n], end = indptr[n + 1];
    float z = 0.f, a = 0.f;
    int i = beg;
    for (; i + 1 < end; i += 2) {
        int s0 = col[i], s1 = col[i + 1];
        const float* r0 = eyp + (size_t)s0 * 64;
        const float* r1 = eyp + (size_t)s1 * 64;
        float es0 = r0[h], y0 = r0[32 + j];
        float es1 = r1[h], y1 = r1[32 + j];
        float p0 = expf(lrelu02(es0 + edv));
        float p1 = expf(lrelu02(es1 + edv));
        z += p0; a += p0 * y0;
        z += p1; a += p1 * y1;
    }
    for (; i < end; ++i) {
        const float* r = eyp + (size_t)col[i] * 64;
        float p = expf(lrelu02(r[h] + edv));
        z += p; a += p * r[32 + j];
    }
    float zf = (1.f / 16.f) / (z + 1e-16f);
    float val = a * zf;
#pragma unroll
    for (int off = 2; off <= 16; off <<= 1) val += __shfl_xor(val, off, 32);
    float other = __shfl_xor(val, 1, 32);        // opposite parity's sum
    if (j == 0) {
        unsigned mk = masks[n];
        float v0 = x[n * 10 + 0] + selu_f(val + b5[0]);
        float v1 = x[n * 10 + 1] + selu_f(other + b5[1]);
        if (mk & 2u) v0 = 0.f; else if (mk & 1u) v0 = 1.f;
        if (mk & 8u) v1 = 1.f; else if (mk & 4u) v1 = 0.f;
        outp[n * 2 + 0] = v0;
        outp[n * 2 + 1] = v1;
    }
}

// ---------------- unified 16-row LDS-staged f16 MFMA GEMM -------------------
// 16 rows x CW cols per block; 4 waves each own CW/4 cols (JT = CW/64 j-tiles
// of 16). Per-output MFMA K-sequence identical to the old 32/64-row kernels.
// EOUT>0: fused next-layer esed/eyp epilogue; for grid.y>1 each col-block
// writes its K-half partial to eout + blockIdx.y*N*EOUT.
#define LDP 72
template <int CW, int EOUT>
__global__ __launch_bounds__(256) void gemm16(const __half* __restrict__ A,
                                              const unsigned short* __restrict__ Bhi,
                                              const float* __restrict__ bias,
                                              const unsigned* __restrict__ masks,
                                              __half* __restrict__ O16,
                                              const float* __restrict__ wnext,
                                              float* __restrict__ eout,
                                              int N, int K, int M) {
    const int JT = CW / 64;                 // 1 or 2 col-tiles of 16 per wave
    const int BR = CW / 32;                 // B rows per staging thread (2/4)
    __shared__ __half lA[16 * LDP], lB[CW * LDP];
    __shared__ float vt[EOUT ? 16 : 1][EOUT ? (CW + 4) : 1];
    int tid = threadIdx.x;
    int wave = tid >> 6, lane = tid & 63;
    int ln16 = lane & 15, q = lane >> 4;
    int row0 = blockIdx.x * 16;
    int col0 = blockIdx.y * CW;
    int wc = wave * (CW / 4);

    int arow = tid >> 3;                    // 0..31
    int ac   = (tid & 7) * 8;               // col offset in halves
    const __half* Bp = (const __half*)Bhi;
    const __half* ap = A + (size_t)min(row0 + arow, N - 1) * K + ac;  // tid<128
    const __half* bp[BR];
#pragma unroll
    for (int i = 0; i < BR; ++i)
        bp[i] = Bp + (size_t)(col0 + arow + 32 * i) * K + ac;

    half8 ra;
    if (tid < 128) ra = *(const half8*)(ap);
    half8 rb[BR];
#pragma unroll
    for (int i = 0; i < BR; ++i) rb[i] = *(const half8*)(bp[i]);

    f32x4 acc[JT];
#pragma unroll
    for (int j = 0; j < JT; ++j) acc[j] = (f32x4){0.f, 0.f, 0.f, 0.f};

    for (int kc = 0; kc < K; kc += 64) {
        __syncthreads();
        if (tid < 128) *(half8*)(lA + arow * LDP + ac) = ra;
#pragma unroll
        for (int i = 0; i < BR; ++i)
            *(half8*)(lB + (arow + 32 * i) * LDP + ac) = rb[i];
        __syncthreads();
        int kn = kc + 64;
        if (kn < K) {
            if (tid < 128) ra = *(const half8*)(ap + kn);
#pragma unroll
            for (int i = 0; i < BR; ++i) rb[i] = *(const half8*)(bp[i] + kn);
        }
#pragma unroll
        for (int kk = 0; kk < 2; ++kk) {
            half8 af = *(const half8*)(lA + ln16 * LDP + kk * 32 + q * 8);
#pragma unroll
            for (int j = 0; j < JT; ++j) {
                half8 bf = *(const half8*)(lB + (wc + j * 16 + ln16) * LDP + kk * 32 + q * 8);
                acc[j] = __builtin_amdgcn_mfma_f32_16x16x32_f16(af, bf, acc[j], 0, 0, 0);
            }
        }
    }

#pragma unroll
    for (int j = 0; j < JT; ++j) {
        int cc = col0 + wc + j * 16 + ln16;
        float bv = bias[cc];
#pragma unroll
        for (int r = 0; r < 4; ++r) {
            int rr = row0 + q * 4 + r;
            float v = selu_f(acc[j][r] + bv);
            if (cc < 2 && rr < N) {
                unsigned mk = masks[rr];
                if (cc == 0) { if (mk & 2u) v = 0.f; else if (mk & 1u) v = 1.f; }
                else         { if (mk & 8u) v = 1.f; else if (mk & 4u) v = 0.f; }
            }
            __half hv = __float2half(v);
            if (rr < N) O16[(size_t)rr * M + cc] = hv;
            if constexpr (EOUT > 0)
                vt[q * 4 + r][wc + j * 16 + ln16] = __half2float(hv);
        }
    }

    if constexpr (EOUT > 0) {
        __syncthreads();
        const int NG = 256 / EOUT;          // rows in parallel (16/8/4)
        const int NI = 16 / NG;             // rows per thread (1/2/4)
        int o = tid & (EOUT - 1);
        int ngrp = tid / EOUT;
        const float* wp = wnext + (size_t)col0 * EOUT;
        float* ep = eout + (size_t)blockIdx.y * N * EOUT;
        float s[NI];
#pragma unroll
        for (int i = 0; i < NI; ++i) s[i] = 0.f;
        for (int k = 0; k < CW; ++k) {
            float wk = wp[k * EOUT + o];
#pragma unroll
            for (int i = 0; i < NI; ++i)
                s[i] += vt[ngrp + NG * i][k] * wk;
        }
#pragma unroll
        for (int i = 0; i < NI; ++i) {
            int n = row0 + ngrp + NG * i;
            if (n < N) ep[(size_t)n * EOUT + o] = s[i];
        }
    }
}

// ---------------------------------------------------------------------------
extern "C" void kernel_launch(void* const* d_in, const int* in_sizes, int n_in,
                              void* d_out, int out_size, void* d_ws, size_t ws_size,
                              hipStream_t stream) {
    const float* x   = (const float*)d_in[0];
    const int*   ei  = (const int*)d_in[1];
    const float* cf  = (const float*)d_in[2];
    const float* cw[4] = {(const float*)d_in[3], (const float*)d_in[5],
                          (const float*)d_in[7], (const float*)d_in[9]};
    const float* cb[4] = {(const float*)d_in[4], (const float*)d_in[6],
                          (const float*)d_in[8], (const float*)d_in[10]};
    const float* gw[5], *gas[5], *gad[5], *gb[5];
    for (int i = 0; i < 5; ++i) {
        gw[i]  = (const float*)d_in[11 + 4 * i];
        gas[i] = (const float*)d_in[12 + 4 * i];
        gad[i] = (const float*)d_in[13 + 4 * i];
        gb[i]  = (const float*)d_in[14 + 4 * i];
    }
    const int N = in_sizes[0] / 10;        // 10000
    const int E = in_sizes[1] / 2;         // 160000
    const int EN = E + N;

    // ---- workspace carve-up ----
    char* base = (char*)d_ws;
    size_t off = 0;
    auto alloc = [&](size_t bytes) -> char* {
        char* p = base + off;
        off = (off + bytes + 255) & ~(size_t)255;
        return p;
    };
    float* c1p   = (float*)alloc((size_t)16 * PSZ * 4);
    float* c2p   = (float*)alloc((size_t)32 * PSZ * 4);
    float* c3p   = (float*)alloc((size_t)64 * PSZ * 4);
    float* c4p   = (float*)alloc((size_t)24 * PSZ * 4);
    float* gfeat = (float*)alloc(24 * 4);
    __half* hA16 = (__half*)alloc((size_t)N * 256 * 2);
    __half* hB16 = (__half*)alloc((size_t)N * 256 * 2);
    __half* g    = (__half*)alloc((size_t)N * 2048 * 2);
    float* esed  = (float*)alloc((size_t)N * 32 * 4);        // also 2x N*16 partials
    float* eyp   = (float*)alloc((size_t)N * 64 * 4);        // L4 [es|ed|y]
    float* wesed = (float*)alloc((size_t)13312 * 4);         // layers 0-4
    float* wcomb = (float*)alloc((size_t)8192 * 4);          // L4 combined weights
    unsigned short* bt = (unsigned short*)alloc((size_t)688128 * 2);  // 4 GEMM layers
    unsigned* masks = (unsigned*)alloc((size_t)N * 4);
    int* cnt    = (int*)alloc((size_t)N * 4);
    int* indptr = (int*)alloc((size_t)(N + 1) * 4);
    int* cursor = (int*)alloc((size_t)N * 4);
    int* col    = (int*)alloc((size_t)EN * 4);
    (void)ws_size; // ~70 MB

    // ---- one-shot fused weight prep (all 5 layers) ----
    prep_all<<<252, 256, 0, stream>>>(gw[0], gw[1], gw[2], gw[3], gw[4],
                                      gas[0], gas[1], gas[2], gas[3], gas[4],
                                      gad[0], gad[1], gad[2], gad[3], gad[4],
                                      bt, wesed, wcomb);

    // ---- CNN (padded layout; memset zeroes intermediate borders) ----
    hipMemsetAsync(c1p, 0, (size_t)136 * PSZ * 4, stream);
    conv3x3_first<<<dim3(16, 16), 256, 0, stream>>>(cf, cw[0], cb[0], c1p);
    conv3x3_pad<16><<<dim3(16, 32), 256, 0, stream>>>(c1p, cw[1], cb[1], c2p);
    conv3x3_pad<32><<<dim3(16, 64), 256, 0, stream>>>(c2p, cw[2], cb[2], c3p);
    conv3x3_pad<64><<<dim3(16, 24), 256, 0, stream>>>(c3p, cw[3], cb[3], c4p);
    avgpool_c<<<24, 256, 0, stream>>>(c4p, gfeat);

    // ---- h0 (padded to 64, fp16) + masks + fused L0 esed ----
    build_h0<<<(N + 255) / 256, 256, 0, stream>>>(x, gfeat, wesed + 0, hA16, masks,
                                                  esed, N);

    // ---- CSR by dst (incl self loops): count, one-block scan, scatter ----
    hipMemsetAsync(cnt, 0, (size_t)N * 4, stream);
    count_dst<<<(EN + 255) / 256, 256, 0, stream>>>(ei, cnt, E, N);
    scan_all<<<1, 1024, 0, stream>>>(cnt, indptr, cursor, N, EN);
    scatter_edges<<<(EN + 255) / 256, 256, 0, stream>>>(ei, cursor, col, E, N);

    // ---- GAT layers (all esed/eyp hand-offs fused into producers) ----
    int gx16 = (N + 15) / 16;   // 625

    // L0: Kp=64 H=8 C=64 KA=512 ; esed came from build_h0
    gat_fused_lds<8, 64, 4, 16, 0><<<(N + 15) / 16, 256, 0, stream>>>(
        hA16, esed, nullptr, indptr, col, g, N);
    gemm16<64, 32><<<dim3(gx16, 1), 256, 0, stream>>>(g, bt + 0, gb[0], masks, hB16,
                                                      wesed + 1024, esed, N, 512, 64);

    // L1: Kp=64 H=16 C=128 KA=1024 ; esed (H2=32) from L0 gemm
    gat_fused_lds<16, 64, 2, 8, 0><<<(N + 7) / 8, 256, 0, stream>>>(
        hB16, esed, nullptr, indptr, col, g, N);
    gemm16<128, 16><<<dim3(gx16, 1), 256, 0, stream>>>(g, bt + 32768, gb[1], masks, hA16,
                                                       wesed + 3072, esed, N, 1024, 128);

    // L2: Kp=128 H=8 C=256 KA=1024 ; esed (H2=16) from L1 gemm; L3's esed
    // produced as two K-half partials by the two col-blocks (grid.y=2)
    gat_fused_lds<8, 128, 4, 8, 0><<<(N + 7) / 8, 256, 0, stream>>>(
        hA16, esed, nullptr, indptr, col, g, N);
    gemm16<128, 16><<<dim3(gx16, 2), 256, 0, stream>>>(g, bt + 163840, gb[2], masks, hB16,
                                                       wesed + 5120, esed, N, 1024, 256);

    // L3: Kp=256 H=8 C=128 KA=2048 ; esed = partial A + partial B
    gat_fused_lds<8, 256, 4, 4, 1><<<(N + 3) / 4, 256, 0, stream>>>(
        hB16, esed, esed + (size_t)N * 16, indptr, col, g, N);
    gemm16<128, 64><<<dim3(gx16, 1), 256, 0, stream>>>(g, bt + 425984, gb[3], masks, hA16,
                                                       wcomb, eyp, N, 2048, 128);

    // L4: project-first fused final layer
    final_attn<8><<<(N + 7) / 8, 256, 0, stream>>>(eyp, indptr, col, gb[4],
                                                   masks, x, (float*)d_out, N);
}

// Round 17
// 422.298 us; speedup vs baseline: 1.2147x; 1.0158x over previous
//
#include <hip/hip_runtime.h>
#include <hip/hip_fp16.h>
#include <math.h>

// ---------------------------------------------------------------------------
// NetGlobGATFix. R33: prologue overlap (CNN chain || CSR chain).
//   - comboA = conv1 U count_dst; comboB = scan(block0) U conv2;
//     comboC = scatter U conv3. Kernel boundaries preserve both chains'
//     dependencies; independent sub-grids overlap on different CUs.
//   - cnt allocated right after c4p -> single memset zeroes conv borders
//     AND cnt. Prologue 10 dispatches -> 6.
//   - All compute code paths identical to R32 (429.0us best); scan re-blocked
//     to 256thr x 40 elems (same sums, static-indexed).
// ---------------------------------------------------------------------------

#define DEVFN static __device__ __forceinline__

typedef __attribute__((ext_vector_type(8))) _Float16 half8;
typedef __attribute__((ext_vector_type(4))) _Float16 half4v;
typedef __attribute__((ext_vector_type(4))) float f32x4;

DEVFN float selu_f(float v) {
    const float scale = 1.0507009873554805f;
    const float alpha = 1.6732632423543772f;
    return v > 0.f ? scale * v : scale * alpha * (expf(v) - 1.f);
}

DEVFN float lrelu02(float v) { return v > 0.f ? v : 0.2f * v; }

// ---------------- CNN (padded 66x66 layout) ----------------
#define PST 66
#define PSZ (66 * 66)

// first conv body: raw 4x64x64 input with boundary guards -> padded out
DEVFN void conv_first_body(const float* __restrict__ cf, const float* __restrict__ w,
                           const float* __restrict__ b, float* __restrict__ out,
                           int bx, int co) {
    int x  = threadIdx.x & 63;
    int yg = threadIdx.x >> 6;
    int y  = bx * 4 + yg;                  // 0..63
    float acc = b[co];
    const float* wp = w + (size_t)co * 4 * 9;
#pragma unroll
    for (int ci = 0; ci < 4; ++ci) {
        const float* ip = cf + ci * 4096;
        const float* wr = wp + ci * 9;
#pragma unroll
        for (int ky = 0; ky < 3; ++ky) {
            int yy = y + ky - 1;
            if (yy < 0 || yy >= 64) continue;
#pragma unroll
            for (int kx = 0; kx < 3; ++kx) {
                int xx = x + kx - 1;
                if (xx < 0 || xx >= 64) continue;
                acc += wr[ky * 3 + kx] * ip[yy * 64 + xx];
            }
        }
    }
    out[(size_t)co * PSZ + (y + 1) * PST + (x + 1)] = selu_f(acc);
}

template <int CIN>
DEVFN void conv_pad_body(const float* __restrict__ in, const float* __restrict__ w,
                         const float* __restrict__ b, float* __restrict__ out,
                         int bx, int co) {
    int x  = threadIdx.x & 63;
    int yg = threadIdx.x >> 6;
    int y  = bx * 4 + yg;                  // 0..63
    float acc = b[co];
    const float* wp = w + (size_t)co * CIN * 9;
#pragma unroll 4
    for (int ci = 0; ci < CIN; ++ci) {
        const float* ip = in + ci * PSZ + y * PST + x;
        const float* wr = wp + ci * 9;
        acc += wr[0] * ip[0]           + wr[1] * ip[1]           + wr[2] * ip[2]
             + wr[3] * ip[PST]         + wr[4] * ip[PST + 1]     + wr[5] * ip[PST + 2]
             + wr[6] * ip[2 * PST]     + wr[7] * ip[2 * PST + 1] + wr[8] * ip[2 * PST + 2];
    }
    out[(size_t)co * PSZ + (y + 1) * PST + (x + 1)] = selu_f(acc);
}

template <int CIN>
__global__ __launch_bounds__(256) void conv3x3_pad(const float* __restrict__ in,
                                                   const float* __restrict__ w,
                                                   const float* __restrict__ b,
                                                   float* __restrict__ out) {
    conv_pad_body<CIN>(in, w, b, out, blockIdx.x, blockIdx.y);
}

__global__ void avgpool_c(const float* __restrict__ in, float* __restrict__ gfeat) {
    int c = blockIdx.x;            // 24 blocks
    int t = threadIdx.x;           // 256 threads
    float s = 0.f;
    for (int i = t; i < 4096; i += 256) {
        int y = i >> 6, x = i & 63;
        s += in[c * PSZ + (y + 1) * PST + (x + 1)];
    }
#pragma unroll
    for (int off = 32; off >= 1; off >>= 1) s += __shfl_xor(s, off);
    __shared__ float red[4];
    int wave = t >> 6, lane = t & 63;
    if (lane == 0) red[wave] = s;
    __syncthreads();
    if (t == 0) gfeat[c] = (red[0] + red[1] + red[2] + red[3]) * (1.f / 4096.f);
}

// ---------------- node feature init (padded to 64 ch, fp16) + masks ---------
// Fused L0 esed: per node, 16 dots over the fp16-rounded features.
__global__ void build_h0(const float* __restrict__ x, const float* __restrict__ gfeat,
                         const float* __restrict__ we0,
                         __half* __restrict__ h0f, unsigned* __restrict__ masks,
                         float* __restrict__ esed, int N) {
    int n = blockIdx.x * blockDim.x + threadIdx.x;
    if (n >= N) return;
    float x0 = x[n * 10 + 0], x1 = x[n * 10 + 1];
    unsigned mk = (x0 == 1.f ? 1u : 0u) | (x0 == 0.f ? 2u : 0u) |
                  (x1 == 0.f ? 4u : 0u) | (x1 == 1.f ? 8u : 0u);
    masks[n] = mk;
    __half* hq = h0f + (size_t)n * 64;
    float hf[64];
#pragma unroll
    for (int j = 0; j < 64; ++j) {
        float v = (j < 24) ? gfeat[j] : (j < 34 ? x[n * 10 + (j - 24)] : 0.f);
        __half hv = __float2half(v);
        hq[j] = hv;
        hf[j] = __half2float(hv);
    }
    float s[16];
#pragma unroll
    for (int o = 0; o < 16; ++o) s[o] = 0.f;
    for (int k = 0; k < 64; ++k) {
        float f = hf[k];
        const float* wk = we0 + k * 16;
#pragma unroll
        for (int o = 0; o < 16; ++o) s[o] += f * wk[o];
    }
#pragma unroll
    for (int o = 0; o < 16; ++o) esed[(size_t)n * 16 + o] = s[o];
}

// ---------------- CSR bodies ----------------
DEVFN void count_body(const int* __restrict__ ei, int* __restrict__ cnt,
                      int blk, int E, int N) {
    int t = blk * 256 + threadIdx.x;
    if (t >= E + N) return;
    int dst = (t < E) ? ei[E + t] : (t - E);
    atomicAdd(&cnt[dst], 1);
}

// 256-thread exclusive scan over n<=10240 counts (40 elems/thread)
DEVFN void scan_body(const int* __restrict__ cnt, int* __restrict__ indptr,
                     int* __restrict__ cursor, int n, int total) {
    __shared__ int sdata[256];
    int t = threadIdx.x;
    int base = t * 40;
    int loc[40];
    int s = 0;
#pragma unroll
    for (int i = 0; i < 40; ++i) {
        int idx = base + i;
        int v = (idx < n) ? cnt[idx] : 0;
        loc[i] = s;                     // exclusive prefix within thread
        s += v;
    }
    sdata[t] = s;
    __syncthreads();
    for (int off = 1; off < 256; off <<= 1) {
        int tmp = (t >= off) ? sdata[t - off] : 0;
        __syncthreads();
        sdata[t] += tmp;
        __syncthreads();
    }
    int excl = (t == 0) ? 0 : sdata[t - 1];
#pragma unroll
    for (int i = 0; i < 40; ++i) {
        int idx = base + i;
        if (idx < n) {
            int e = excl + loc[i];
            indptr[idx] = e;
            cursor[idx] = e;
        }
    }
    if (t == 0) indptr[n] = total;
}

DEVFN void scatter_body(const int* __restrict__ ei, int* __restrict__ cursor,
                        int* __restrict__ col, int blk, int E, int N) {
    int t = blk * 256 + threadIdx.x;
    if (t >= E + N) return;
    int src, dst;
    if (t < E) { src = ei[t]; dst = ei[E + t]; }
    else       { src = dst = t - E; }
    int pos = atomicAdd(&cursor[dst], 1);
    col[pos] = src;
}

// ---------------- prologue combo kernels (CNN || CSR overlap) ---------------
// comboA: blocks [0,256) conv1 ; [256, 256+CB) count_dst
__global__ __launch_bounds__(256) void comboA(const float* __restrict__ cf,
                                              const float* __restrict__ w0,
                                              const float* __restrict__ b0,
                                              float* __restrict__ c1p,
                                              const int* __restrict__ ei,
                                              int* __restrict__ cnt, int E, int N) {
    int b = blockIdx.x;
    if (b < 256) conv_first_body(cf, w0, b0, c1p, b % 16, b / 16);
    else         count_body(ei, cnt, b - 256, E, N);
}

// comboB: block 0 scan ; blocks [1, 513) conv2 (CIN=16, 16x32)
__global__ __launch_bounds__(256) void comboB(const int* __restrict__ cnt,
                                              int* __restrict__ indptr,
                                              int* __restrict__ cursor, int n, int total,
                                              const float* __restrict__ c1p,
                                              const float* __restrict__ w1,
                                              const float* __restrict__ b1,
                                              float* __restrict__ c2p) {
    int b = blockIdx.x;
    if (b == 0) scan_body(cnt, indptr, cursor, n, total);
    else {
        int blk = b - 1;
        conv_pad_body<16>(c1p, w1, b1, c2p, blk % 16, blk / 16);
    }
}

// comboC: blocks [0,CB) scatter ; blocks [CB, CB+1024) conv3 (CIN=32, 16x64)
__global__ __launch_bounds__(256) void comboC(const int* __restrict__ ei,
                                              int* __restrict__ cursor,
                                              int* __restrict__ col, int E, int N, int CB,
                                              const float* __restrict__ c2p,
                                              const float* __restrict__ w2,
                                              const float* __restrict__ b2,
                                              float* __restrict__ c3p) {
    int b = blockIdx.x;
    if (b < CB) scatter_body(ei, cursor, col, b, E, N);
    else {
        int blk = b - CB;
        conv_pad_body<32>(c2p, w2, b2, c3p, blk % 16, blk / 16);
    }
}

// ---------------- fused one-shot weight prep --------------------------------
__global__ __launch_bounds__(256) void prep_all(
        const float* __restrict__ W0, const float* __restrict__ W1,
        const float* __restrict__ W2, const float* __restrict__ W3,
        const float* __restrict__ W4,
        const float* __restrict__ as0, const float* __restrict__ as1,
        const float* __restrict__ as2, const float* __restrict__ as3,
        const float* __restrict__ as4,
        const float* __restrict__ ad0, const float* __restrict__ ad1,
        const float* __restrict__ ad2, const float* __restrict__ ad3,
        const float* __restrict__ ad4,
        unsigned short* __restrict__ bt, float* __restrict__ wesed,
        float* __restrict__ wcomb) {
    const int Kc[5]  = {34, 64, 128, 256, 128};
    const int Kpc[5] = {64, 64, 128, 256, 128};        // L0 padded to 64
    const int Hc[5]  = {8, 16, 8, 8, 16};
    const int Cc[5]  = {64, 128, 256, 128, 2};
    const int HCc[5] = {512, 2048, 2048, 1024, 32};
    const int KAc[5] = {512, 1024, 1024, 2048, 2048};  // L0 KA = 8*64
    const int btOff[5] = {0, 32768, 163840, 425984, 0};
    const int weOff[5] = {0, 1024, 3072, 5120, 9216};

    int b = blockIdx.x, tid = threadIdx.x;

    if (b < 168) {
        // ---- LDS-tiled transpose, one (layer, head, 64x64 tile) per block --
        int lyr, tloc;
        if (b < 8)        { lyr = 0; tloc = b; }
        else if (b < 40)  { lyr = 1; tloc = b - 8; }
        else if (b < 104) { lyr = 2; tloc = b - 40; }
        else              { lyr = 3; tloc = b - 104; }
        const int ktl[4] = {1, 1, 2, 4};   // ceil(Kp/64)
        const int mtl[4] = {1, 2, 4, 2};   // ceil(C/64)
        int kt = ktl[lyr], mt = mtl[lyr];
        int per_h = kt * mt;
        int h = tloc / per_h, r = tloc - h * per_h;
        int ki = r % kt, mi = r / kt;
        int k0 = ki * 64, m0 = mi * 64;
        int K = Kc[lyr], Kp = Kpc[lyr], C = Cc[lyr], HC = HCc[lyr], KA = KAc[lyr];
        const float* W;
        if (lyr == 0) W = W0; else if (lyr == 1) W = W1;
        else if (lyr == 2) W = W2; else W = W3;

        __shared__ float tile[64][65];
        int c = tid & 63, rg = tid >> 6;
        for (int r2 = rg; r2 < 64; r2 += 4) {       // coalesced 256B reads
            int k = k0 + r2, m = m0 + c;
            float v = (k < K && m < C) ? W[(size_t)k * HC + h * C + m] : 0.f;
            tile[r2][c] = v;
        }
        __syncthreads();
        unsigned short* bp = bt + btOff[lyr];
        for (int mr = rg; mr < 64; mr += 4) {       // coalesced 128B fp16 writes
            int m = m0 + mr, k = k0 + c;
            if (m < C && k < Kp)
                bp[(size_t)m * KA + h * Kp + k] =
                    __half_as_ushort(__float2half(tile[c][mr]));
        }
    } else if (b < 200) {
        // ---- wcomb for layer 4: 8192 outputs (128 x 64) ----
        int u = (b - 168) * 256 + tid;
        int k = u >> 6, o = u & 63;
        float s;
        if (o < 32) {                       // es/ed weights
            int h = (o < 16) ? o : o - 16;
            const float* av = ((o < 16) ? as4 : ad4) + h * 2;
            s = W4[k * 32 + h * 2 + 0] * av[0] + W4[k * 32 + h * 2 + 1] * av[1];
        } else {                            // y projection: raw W4 column
            s = W4[k * 32 + (o - 32)];
        }
        wcomb[u] = s;
    } else {
        // ---- wesed dots: sizes {1024,2048,2048,4096,4096} -> 52 blocks ----
        int wb = b - 200;
        int lyr, u0;
        if (wb < 4)       { lyr = 0; u0 = wb * 256; }
        else if (wb < 12) { lyr = 1; u0 = (wb - 4) * 256; }
        else if (wb < 20) { lyr = 2; u0 = (wb - 12) * 256; }
        else if (wb < 36) { lyr = 3; u0 = (wb - 20) * 256; }
        else              { lyr = 4; u0 = (wb - 36) * 256; }
        int u = u0 + tid;
        int K = Kc[lyr], Kp = Kpc[lyr], H = Hc[lyr], C = Cc[lyr], HC = HCc[lyr];
        int H2 = 2 * H;
        if (u < Kp * H2) {
            int k = u / H2, o = u - k * H2;
            float s = 0.f;
            if (k < K) {
                int h = (o < H) ? o : o - H;
                const float *W, *as_, *ad_;
                if (lyr == 0)      { W = W0; as_ = as0; ad_ = ad0; }
                else if (lyr == 1) { W = W1; as_ = as1; ad_ = ad1; }
                else if (lyr == 2) { W = W2; as_ = as2; ad_ = ad2; }
                else if (lyr == 3) { W = W3; as_ = as3; ad_ = ad3; }
                else               { W = W4; as_ = as4; ad_ = ad4; }
                const float* av = ((o < H) ? as_ : ad_) + h * C;
                const float* wp = W + (size_t)k * HC + h * C;
#pragma unroll 4
                for (int c2 = 0; c2 < C; ++c2) s += wp[c2] * av[c2];
            }
            wesed[weOff[lyr] + u] = s;
        }
    }
}

// -------- fused attn+gather via LDS broadcast, pipelined (layers 0-3) -------
// TWO: esed is split into two K-half partials (esed, esed2) -> sum at load.
template <int H, int KP, int CH, int NPB, int TWO>
__global__ __launch_bounds__(NPB * (KP / CH)) void gat_fused_lds(
        const __half* __restrict__ hinf, const float* __restrict__ esed,
        const float* __restrict__ esed2,
        const int* __restrict__ indptr, const int* __restrict__ col,
        __half* __restrict__ g, int N) {
    const int TPN = KP / CH;
    const int EC  = TPN / H;
    const int H2  = 2 * H;
    __shared__ float lds_p[NPB][2][TPN];
    int sub = threadIdx.x / TPN;
    int j   = threadIdx.x % TPN;
    int n = blockIdx.x * NPB + sub;
    if (n >= N) return;
    int e_my = j / H, h_my = j % H;
    int c0 = j * CH;
    float edv = esed[n * H2 + H + h_my];
    if constexpr (TWO) edv += esed2[n * H2 + H + h_my];

    float acc[H][CH];
#pragma unroll
    for (int h = 0; h < H; ++h)
#pragma unroll
        for (int t = 0; t < CH; ++t) acc[h][t] = 0.f;
    float zloc = 0.f;

    int beg = indptr[n], deg = indptr[n + 1] - beg;

    // prologue: p for chunk 0
    float p = 0.f;
    if (e_my < deg) {
        int srcm = col[beg + e_my];
        float es0 = esed[srcm * H2 + h_my];
        if constexpr (TWO) es0 += esed2[srcm * H2 + h_my];
        p = expf(lrelu02(es0 + edv));
    }
    int buf = 0;
    for (int base = 0; base < deg; base += EC) {
        zloc += p;
        lds_p[sub][buf][j] = p;
        __builtin_amdgcn_wave_barrier();
        // issue next chunk's attention loads (exp after phase B)
        int ce = base + EC + e_my;
        bool vnext = (ce < deg);
        float esv = 0.f;
        if (vnext) {
            int srcm = col[beg + ce];
            esv = esed[srcm * H2 + h_my];
            if constexpr (TWO) esv += esed2[srcm * H2 + h_my];
        }
        // phase B: pipelined gather with LDS-broadcast alphas
#pragma unroll
        for (int e = 0; e < EC; ++e) {
            int idx = base + e;
            if (idx < deg) {                  // uniform within node group
                int src = col[beg + idx];
                float f[CH];
                if (CH == 2) {
                    __half2 hv = *(const __half2*)(hinf + (size_t)src * KP + c0);
                    float2 ff = __half22float2(hv);
                    f[0] = ff.x; f[1] = ff.y;
                } else {
                    half4v hv = *(const half4v*)(hinf + (size_t)src * KP + c0);
                    f[0] = (float)hv[0]; f[1] = (float)hv[1];
                    f[2] = (float)hv[2]; f[3] = (float)hv[3];
                }
                const float4* ap = (const float4*)&lds_p[sub][buf][e * H];
#pragma unroll
                for (int q4 = 0; q4 < H / 4; ++q4) {
                    float4 a4 = ap[q4];
#pragma unroll
                    for (int t = 0; t < CH; ++t) {
                        acc[4 * q4 + 0][t] += a4.x * f[t];
                        acc[4 * q4 + 1][t] += a4.y * f[t];
                        acc[4 * q4 + 2][t] += a4.z * f[t];
                        acc[4 * q4 + 3][t] += a4.w * f[t];
                    }
                }
            }
        }
        p = vnext ? expf(lrelu02(esv + edv)) : 0.f;
        buf ^= 1;
    }

    // z: reduce across the EC lanes of each head class
#pragma unroll
    for (int off = H; off < TPN; off <<= 1)
        zloc += __shfl_xor(zloc, off, TPN);
    float zinv_my = (1.f / H) / (zloc + 1e-16f);

    __half* gp = g + (size_t)n * (H * KP) + c0;
#pragma unroll
    for (int h = 0; h < H; ++h) {
        float zf = __shfl(zinv_my, h, TPN);   // lane class h holds z for head h
        if (CH == 2) {
            *(__half2*)(gp + h * KP) =
                __floats2half2_rn(acc[h][0] * zf, acc[h][1] * zf);
        } else {
            __half2 lo = __floats2half2_rn(acc[h][0] * zf, acc[h][1] * zf);
            __half2 hi = __floats2half2_rn(acc[h][2] * zf, acc[h][3] * zf);
            union { __half2 h2[2]; float2 f2; } u;
            u.h2[0] = lo; u.h2[1] = hi;
            *(float2*)(gp + h * KP) = u.f2;
        }
    }
}

// -------- layer 4: fused attention + projected gather + output --------------
template <int NPB>
__global__ __launch_bounds__(NPB * 32) void final_attn(
        const float* __restrict__ eyp, const int* __restrict__ indptr,
        const int* __restrict__ col, const float* __restrict__ b5,
        const unsigned* __restrict__ masks, const float* __restrict__ x,
        float* __restrict__ outp, int N) {
    int sub = threadIdx.x >> 5;
    int j   = threadIdx.x & 31;
    int n = blockIdx.x * NPB + sub;
    if (n >= N) return;
    int h = j >> 1;
    float edv = eyp[(size_t)n * 64 + 16 + h];
    int beg = indptr[n], end = indptr[n + 1];
    float z = 0.f, a = 0.f;
    int i = beg;
    for (; i + 1 < end; i += 2) {
        int s0 = col[i], s1 = col[i + 1];
        const float* r0 = eyp + (size_t)s0 * 64;
        const float* r1 = eyp + (size_t)s1 * 64;
        float es0 = r0[h], y0 = r0[32 + j];
        float es1 = r1[h], y1 = r1[32 + j];
        float p0 = expf(lrelu02(es0 + edv));
        float p1 = expf(lrelu02(es1 + edv));
        z += p0; a += p0 * y0;
        z += p1; a += p1 * y1;
    }
    for (; i < end; ++i) {
        const float* r = eyp + (size_t)col[i] * 64;
        float p = expf(lrelu02(r[h] + edv));
        z += p; a += p * r[32 + j];
    }
    float zf = (1.f / 16.f) / (z + 1e-16f);
    float val = a * zf;
#pragma unroll
    for (int off = 2; off <= 16; off <<= 1) val += __shfl_xor(val, off, 32);
    float other = __shfl_xor(val, 1, 32);        // opposite parity's sum
    if (j == 0) {
        unsigned mk = masks[n];
        float v0 = x[n * 10 + 0] + selu_f(val + b5[0]);
        float v1 = x[n * 10 + 1] + selu_f(other + b5[1]);
        if (mk & 2u) v0 = 0.f; else if (mk & 1u) v0 = 1.f;
        if (mk & 8u) v1 = 1.f; else if (mk & 4u) v1 = 0.f;
        outp[n * 2 + 0] = v0;
        outp[n * 2 + 1] = v1;
    }
}

// ---------------- unified 16-row LDS-staged f16 MFMA GEMM -------------------
#define LDP 72
template <int CW, int EOUT>
__global__ __launch_bounds__(256) void gemm16(const __half* __restrict__ A,
                                              const unsigned short* __restrict__ Bhi,
                                              const float* __restrict__ bias,
                                              const unsigned* __restrict__ masks,
                                              __half* __restrict__ O16,
                                              const float* __restrict__ wnext,
                                              float* __restrict__ eout,
                                              int N, int K, int M) {
    const int JT = CW / 64;                 // 1 or 2 col-tiles of 16 per wave
    const int BR = CW / 32;                 // B rows per staging thread (2/4)
    __shared__ __half lA[16 * LDP], lB[CW * LDP];
    __shared__ float vt[EOUT ? 16 : 1][EOUT ? (CW + 4) : 1];
    int tid = threadIdx.x;
    int wave = tid >> 6, lane = tid & 63;
    int ln16 = lane & 15, q = lane >> 4;
    int row0 = blockIdx.x * 16;
    int col0 = blockIdx.y * CW;
    int wc = wave * (CW / 4);

    int arow = tid >> 3;                    // 0..31
    int ac   = (tid & 7) * 8;               // col offset in halves
    const __half* Bp = (const __half*)Bhi;
    const __half* ap = A + (size_t)min(row0 + arow, N - 1) * K + ac;  // tid<128
    const __half* bp[BR];
#pragma unroll
    for (int i = 0; i < BR; ++i)
        bp[i] = Bp + (size_t)(col0 + arow + 32 * i) * K + ac;

    half8 ra;
    if (tid < 128) ra = *(const half8*)(ap);
    half8 rb[BR];
#pragma unroll
    for (int i = 0; i < BR; ++i) rb[i] = *(const half8*)(bp[i]);

    f32x4 acc[JT];
#pragma unroll
    for (int j = 0; j < JT; ++j) acc[j] = (f32x4){0.f, 0.f, 0.f, 0.f};

    for (int kc = 0; kc < K; kc += 64) {
        __syncthreads();
        if (tid < 128) *(half8*)(lA + arow * LDP + ac) = ra;
#pragma unroll
        for (int i = 0; i < BR; ++i)
            *(half8*)(lB + (arow + 32 * i) * LDP + ac) = rb[i];
        __syncthreads();
        int kn = kc + 64;
        if (kn < K) {
            if (tid < 128) ra = *(const half8*)(ap + kn);
#pragma unroll
            for (int i = 0; i < BR; ++i) rb[i] = *(const half8*)(bp[i] + kn);
        }
#pragma unroll
        for (int kk = 0; kk < 2; ++kk) {
            half8 af = *(const half8*)(lA + ln16 * LDP + kk * 32 + q * 8);
#pragma unroll
            for (int j = 0; j < JT; ++j) {
                half8 bf = *(const half8*)(lB + (wc + j * 16 + ln16) * LDP + kk * 32 + q * 8);
                acc[j] = __builtin_amdgcn_mfma_f32_16x16x32_f16(af, bf, acc[j], 0, 0, 0);
            }
        }
    }

#pragma unroll
    for (int j = 0; j < JT; ++j) {
        int cc = col0 + wc + j * 16 + ln16;
        float bv = bias[cc];
#pragma unroll
        for (int r = 0; r < 4; ++r) {
            int rr = row0 + q * 4 + r;
            float v = selu_f(acc[j][r] + bv);
            if (cc < 2 && rr < N) {
                unsigned mk = masks[rr];
                if (cc == 0) { if (mk & 2u) v = 0.f; else if (mk & 1u) v = 1.f; }
                else         { if (mk & 8u) v = 1.f; else if (mk & 4u) v = 0.f; }
            }
            __half hv = __float2half(v);
            if (rr < N) O16[(size_t)rr * M + cc] = hv;
            if constexpr (EOUT > 0)
                vt[q * 4 + r][wc + j * 16 + ln16] = __half2float(hv);
        }
    }

    if constexpr (EOUT > 0) {
        __syncthreads();
        const int NG = 256 / EOUT;          // rows in parallel (16/8/4)
        const int NI = 16 / NG;             // rows per thread (1/2/4)
        int o = tid & (EOUT - 1);
        int ngrp = tid / EOUT;
        const float* wp = wnext + (size_t)col0 * EOUT;
        float* ep = eout + (size_t)blockIdx.y * N * EOUT;
        float s[NI];
#pragma unroll
        for (int i = 0; i < NI; ++i) s[i] = 0.f;
        for (int k = 0; k < CW; ++k) {
            float wk = wp[k * EOUT + o];
#pragma unroll
            for (int i = 0; i < NI; ++i)
                s[i] += vt[ngrp + NG * i][k] * wk;
        }
#pragma unroll
        for (int i = 0; i < NI; ++i) {
            int n = row0 + ngrp + NG * i;
            if (n < N) ep[(size_t)n * EOUT + o] = s[i];
        }
    }
}

// ---------------------------------------------------------------------------
extern "C" void kernel_launch(void* const* d_in, const int* in_sizes, int n_in,
                              void* d_out, int out_size, void* d_ws, size_t ws_size,
                              hipStream_t stream) {
    const float* x   = (const float*)d_in[0];
    const int*   ei  = (const int*)d_in[1];
    const float* cf  = (const float*)d_in[2];
    const float* cw[4] = {(const float*)d_in[3], (const float*)d_in[5],
                          (const float*)d_in[7], (const float*)d_in[9]};
    const float* cb[4] = {(const float*)d_in[4], (const float*)d_in[6],
                          (const float*)d_in[8], (const float*)d_in[10]};
    const float* gw[5], *gas[5], *gad[5], *gb[5];
    for (int i = 0; i < 5; ++i) {
        gw[i]  = (const float*)d_in[11 + 4 * i];
        gas[i] = (const float*)d_in[12 + 4 * i];
        gad[i] = (const float*)d_in[13 + 4 * i];
        gb[i]  = (const float*)d_in[14 + 4 * i];
    }
    const int N = in_sizes[0] / 10;        // 10000
    const int E = in_sizes[1] / 2;         // 160000
    const int EN = E + N;
    const int CB = (EN + 255) / 256;       // 665 CSR blocks

    // ---- workspace carve-up (cnt adjacent to conv buffers: one memset) ----
    char* base = (char*)d_ws;
    size_t off = 0;
    auto alloc = [&](size_t bytes) -> char* {
        char* p = base + off;
        off = (off + bytes + 255) & ~(size_t)255;
        return p;
    };
    float* c1p   = (float*)alloc((size_t)16 * PSZ * 4);
    float* c2p   = (float*)alloc((size_t)32 * PSZ * 4);
    float* c3p   = (float*)alloc((size_t)64 * PSZ * 4);
    float* c4p   = (float*)alloc((size_t)24 * PSZ * 4);
    int*   cnt   = (int*)alloc((size_t)N * 4);
    float* gfeat = (float*)alloc(24 * 4);
    __half* hA16 = (__half*)alloc((size_t)N * 256 * 2);
    __half* hB16 = (__half*)alloc((size_t)N * 256 * 2);
    __half* g    = (__half*)alloc((size_t)N * 2048 * 2);
    float* esed  = (float*)alloc((size_t)N * 32 * 4);        // also 2x N*16 partials
    float* eyp   = (float*)alloc((size_t)N * 64 * 4);        // L4 [es|ed|y]
    float* wesed = (float*)alloc((size_t)13312 * 4);         // layers 0-4
    float* wcomb = (float*)alloc((size_t)8192 * 4);          // L4 combined weights
    unsigned short* bt = (unsigned short*)alloc((size_t)688128 * 2);  // 4 GEMM layers
    unsigned* masks = (unsigned*)alloc((size_t)N * 4);
    int* indptr = (int*)alloc((size_t)(N + 1) * 4);
    int* cursor = (int*)alloc((size_t)N * 4);
    int* col    = (int*)alloc((size_t)EN * 4);
    (void)ws_size; // ~70 MB

    // ---- one-shot fused weight prep (all 5 layers) ----
    prep_all<<<252, 256, 0, stream>>>(gw[0], gw[1], gw[2], gw[3], gw[4],
                                      gas[0], gas[1], gas[2], gas[3], gas[4],
                                      gad[0], gad[1], gad[2], gad[3], gad[4],
                                      bt, wesed, wcomb);

    // ---- single memset: conv borders (c1p..c4p) + cnt ----
    size_t zlen = (size_t)((char*)cnt - (char*)c1p) + (size_t)N * 4;
    hipMemsetAsync(c1p, 0, zlen, stream);

    // ---- prologue combos: CNN chain || CSR chain ----
    comboA<<<256 + CB, 256, 0, stream>>>(cf, cw[0], cb[0], c1p, ei, cnt, E, N);
    comboB<<<1 + 512, 256, 0, stream>>>(cnt, indptr, cursor, N, EN,
                                        c1p, cw[1], cb[1], c2p);
    comboC<<<CB + 1024, 256, 0, stream>>>(ei, cursor, col, E, N, CB,
                                          c2p, cw[2], cb[2], c3p);
    conv3x3_pad<64><<<dim3(16, 24), 256, 0, stream>>>(c3p, cw[3], cb[3], c4p);
    avgpool_c<<<24, 256, 0, stream>>>(c4p, gfeat);

    // ---- h0 (padded to 64, fp16) + masks + fused L0 esed ----
    build_h0<<<(N + 255) / 256, 256, 0, stream>>>(x, gfeat, wesed + 0, hA16, masks,
                                                  esed, N);

    // ---- GAT layers (all esed/eyp hand-offs fused into producers) ----
    int gx16 = (N + 15) / 16;   // 625

    // L0: Kp=64 H=8 C=64 KA=512 ; esed came from build_h0
    gat_fused_lds<8, 64, 4, 16, 0><<<(N + 15) / 16, 256, 0, stream>>>(
        hA16, esed, nullptr, indptr, col, g, N);
    gemm16<64, 32><<<dim3(gx16, 1), 256, 0, stream>>>(g, bt + 0, gb[0], masks, hB16,
                                                      wesed + 1024, esed, N, 512, 64);

    // L1: Kp=64 H=16 C=128 KA=1024 ; esed (H2=32) from L0 gemm
    gat_fused_lds<16, 64, 2, 8, 0><<<(N + 7) / 8, 256, 0, stream>>>(
        hB16, esed, nullptr, indptr, col, g, N);
    gemm16<128, 16><<<dim3(gx16, 1), 256, 0, stream>>>(g, bt + 32768, gb[1], masks, hA16,
                                                       wesed + 3072, esed, N, 1024, 128);

    // L2: Kp=128 H=8 C=256 KA=1024 ; esed (H2=16) from L1 gemm; L3's esed
    // produced as two K-half partials by the two col-blocks (grid.y=2)
    gat_fused_lds<8, 128, 4, 8, 0><<<(N + 7) / 8, 256, 0, stream>>>(
        hA16, esed, nullptr, indptr, col, g, N);
    gemm16<128, 16><<<dim3(gx16, 2), 256, 0, stream>>>(g, bt + 163840, gb[2], masks, hB16,
                                                       wesed + 5120, esed, N, 1024, 256);

    // L3: Kp=256 H=8 C=128 KA=2048 ; esed = partial A + partial B
    gat_fused_lds<8, 256, 4, 4, 1><<<(N + 3) / 4, 256, 0, stream>>>(
        hB16, esed, esed + (size_t)N * 16, indptr, col, g, N);
    gemm16<128, 64><<<dim3(gx16, 1), 256, 0, stream>>>(g, bt + 425984, gb[3], masks, hA16,
                                                       wcomb, eyp, N, 2048, 128);

    // L4: project-first fused final layer
    final_attn<8><<<(N + 7) / 8, 256, 0, stream>>>(eyp, indptr, col, gb[4],
                                                   masks, x, (float*)d_out, N);
}

// Round 18
// 416.809 us; speedup vs baseline: 1.2307x; 1.0132x over previous
//
#include <hip/hip_runtime.h>
#include <hip/hip_fp16.h>
#include <math.h>

// ---------------------------------------------------------------------------
// NetGlobGATFix. R34: prep_all folded into comboA + conv4/avgpool fused.
//   - comboA = prep_all(252) U conv1(256) U count_dst(CB): prep's blocks fill
//     CUs alongside the other chains instead of a serial dispatch slot.
//   - conv4_pool: conv4 pixel in regs -> block reduce -> atomicAdd partial
//     into gfeat (zeroed by memset); build_h0 applies x(1/4096). c4p deleted.
//     Mean reassociates over 16 partials (~1e-7, same class as accepted).
//   - Dispatches 17 -> 15. Everything else identical to R33 (422.3us best).
// ---------------------------------------------------------------------------

#define DEVFN static __device__ __forceinline__

typedef __attribute__((ext_vector_type(8))) _Float16 half8;
typedef __attribute__((ext_vector_type(4))) _Float16 half4v;
typedef __attribute__((ext_vector_type(4))) float f32x4;

DEVFN float selu_f(float v) {
    const float scale = 1.0507009873554805f;
    const float alpha = 1.6732632423543772f;
    return v > 0.f ? scale * v : scale * alpha * (expf(v) - 1.f);
}

DEVFN float lrelu02(float v) { return v > 0.f ? v : 0.2f * v; }

// ---------------- CNN (padded 66x66 layout) ----------------
#define PST 66
#define PSZ (66 * 66)

// first conv body: raw 4x64x64 input with boundary guards -> padded out
DEVFN void conv_first_body(const float* __restrict__ cf, const float* __restrict__ w,
                           const float* __restrict__ b, float* __restrict__ out,
                           int bx, int co) {
    int x  = threadIdx.x & 63;
    int yg = threadIdx.x >> 6;
    int y  = bx * 4 + yg;                  // 0..63
    float acc = b[co];
    const float* wp = w + (size_t)co * 4 * 9;
#pragma unroll
    for (int ci = 0; ci < 4; ++ci) {
        const float* ip = cf + ci * 4096;
        const float* wr = wp + ci * 9;
#pragma unroll
        for (int ky = 0; ky < 3; ++ky) {
            int yy = y + ky - 1;
            if (yy < 0 || yy >= 64) continue;
#pragma unroll
            for (int kx = 0; kx < 3; ++kx) {
                int xx = x + kx - 1;
                if (xx < 0 || xx >= 64) continue;
                acc += wr[ky * 3 + kx] * ip[yy * 64 + xx];
            }
        }
    }
    out[(size_t)co * PSZ + (y + 1) * PST + (x + 1)] = selu_f(acc);
}

template <int CIN>
DEVFN float conv_pad_val(const float* __restrict__ in, const float* __restrict__ w,
                         const float* __restrict__ b, int bx, int co,
                         int* px, int* py) {
    int x  = threadIdx.x & 63;
    int yg = threadIdx.x >> 6;
    int y  = bx * 4 + yg;                  // 0..63
    float acc = b[co];
    const float* wp = w + (size_t)co * CIN * 9;
#pragma unroll 4
    for (int ci = 0; ci < CIN; ++ci) {
        const float* ip = in + ci * PSZ + y * PST + x;
        const float* wr = wp + ci * 9;
        acc += wr[0] * ip[0]           + wr[1] * ip[1]           + wr[2] * ip[2]
             + wr[3] * ip[PST]         + wr[4] * ip[PST + 1]     + wr[5] * ip[PST + 2]
             + wr[6] * ip[2 * PST]     + wr[7] * ip[2 * PST + 1] + wr[8] * ip[2 * PST + 2];
    }
    *px = x; *py = y;
    return selu_f(acc);
}

template <int CIN>
DEVFN void conv_pad_body(const float* __restrict__ in, const float* __restrict__ w,
                         const float* __restrict__ b, float* __restrict__ out,
                         int bx, int co) {
    int x, y;
    float v = conv_pad_val<CIN>(in, w, b, bx, co, &x, &y);
    out[(size_t)co * PSZ + (y + 1) * PST + (x + 1)] = v;
}

// conv4 + global-avg-pool partial: value in regs, block reduce, atomicAdd.
__global__ __launch_bounds__(256) void conv4_pool(const float* __restrict__ in,
                                                  const float* __restrict__ w,
                                                  const float* __restrict__ b,
                                                  float* __restrict__ gfeat) {
    int x, y;
    float v = conv_pad_val<64>(in, w, b, blockIdx.x, blockIdx.y, &x, &y);
#pragma unroll
    for (int off = 32; off >= 1; off >>= 1) v += __shfl_xor(v, off);
    __shared__ float red[4];
    int wave = threadIdx.x >> 6, lane = threadIdx.x & 63;
    if (lane == 0) red[wave] = v;
    __syncthreads();
    if (threadIdx.x == 0)
        atomicAdd(&gfeat[blockIdx.y], red[0] + red[1] + red[2] + red[3]);
}

// ---------------- node feature init (padded to 64 ch, fp16) + masks ---------
// gfeat holds channel SUMS; mean applied here (x 1/4096).
__global__ void build_h0(const float* __restrict__ x, const float* __restrict__ gfeat,
                         const float* __restrict__ we0,
                         __half* __restrict__ h0f, unsigned* __restrict__ masks,
                         float* __restrict__ esed, int N) {
    int n = blockIdx.x * blockDim.x + threadIdx.x;
    if (n >= N) return;
    float x0 = x[n * 10 + 0], x1 = x[n * 10 + 1];
    unsigned mk = (x0 == 1.f ? 1u : 0u) | (x0 == 0.f ? 2u : 0u) |
                  (x1 == 0.f ? 4u : 0u) | (x1 == 1.f ? 8u : 0u);
    masks[n] = mk;
    __half* hq = h0f + (size_t)n * 64;
    float hf[64];
#pragma unroll
    for (int j = 0; j < 64; ++j) {
        float v = (j < 24) ? gfeat[j] * (1.f / 4096.f)
                           : (j < 34 ? x[n * 10 + (j - 24)] : 0.f);
        __half hv = __float2half(v);
        hq[j] = hv;
        hf[j] = __half2float(hv);
    }
    float s[16];
#pragma unroll
    for (int o = 0; o < 16; ++o) s[o] = 0.f;
    for (int k = 0; k < 64; ++k) {
        float f = hf[k];
        const float* wk = we0 + k * 16;
#pragma unroll
        for (int o = 0; o < 16; ++o) s[o] += f * wk[o];
    }
#pragma unroll
    for (int o = 0; o < 16; ++o) esed[(size_t)n * 16 + o] = s[o];
}

// ---------------- CSR bodies ----------------
DEVFN void count_body(const int* __restrict__ ei, int* __restrict__ cnt,
                      int blk, int E, int N) {
    int t = blk * 256 + threadIdx.x;
    if (t >= E + N) return;
    int dst = (t < E) ? ei[E + t] : (t - E);
    atomicAdd(&cnt[dst], 1);
}

// 256-thread exclusive scan over n<=10240 counts (40 elems/thread)
DEVFN void scan_body(const int* __restrict__ cnt, int* __restrict__ indptr,
                     int* __restrict__ cursor, int n, int total) {
    __shared__ int sdata[256];
    int t = threadIdx.x;
    int base = t * 40;
    int loc[40];
    int s = 0;
#pragma unroll
    for (int i = 0; i < 40; ++i) {
        int idx = base + i;
        int v = (idx < n) ? cnt[idx] : 0;
        loc[i] = s;                     // exclusive prefix within thread
        s += v;
    }
    sdata[t] = s;
    __syncthreads();
    for (int off = 1; off < 256; off <<= 1) {
        int tmp = (t >= off) ? sdata[t - off] : 0;
        __syncthreads();
        sdata[t] += tmp;
        __syncthreads();
    }
    int excl = (t == 0) ? 0 : sdata[t - 1];
#pragma unroll
    for (int i = 0; i < 40; ++i) {
        int idx = base + i;
        if (idx < n) {
            int e = excl + loc[i];
            indptr[idx] = e;
            cursor[idx] = e;
        }
    }
    if (t == 0) indptr[n] = total;
}

DEVFN void scatter_body(const int* __restrict__ ei, int* __restrict__ cursor,
                        int* __restrict__ col, int blk, int E, int N) {
    int t = blk * 256 + threadIdx.x;
    if (t >= E + N) return;
    int src, dst;
    if (t < E) { src = ei[t]; dst = ei[E + t]; }
    else       { src = dst = t - E; }
    int pos = atomicAdd(&cursor[dst], 1);
    col[pos] = src;
}

// ---------------- weight-prep body (252 blocks) -----------------------------
DEVFN void prep_body(int b,
        const float* __restrict__ W0, const float* __restrict__ W1,
        const float* __restrict__ W2, const float* __restrict__ W3,
        const float* __restrict__ W4,
        const float* __restrict__ as0, const float* __restrict__ as1,
        const float* __restrict__ as2, const float* __restrict__ as3,
        const float* __restrict__ as4,
        const float* __restrict__ ad0, const float* __restrict__ ad1,
        const float* __restrict__ ad2, const float* __restrict__ ad3,
        const float* __restrict__ ad4,
        unsigned short* __restrict__ bt, float* __restrict__ wesed,
        float* __restrict__ wcomb) {
    const int Kc[5]  = {34, 64, 128, 256, 128};
    const int Kpc[5] = {64, 64, 128, 256, 128};        // L0 padded to 64
    const int Hc[5]  = {8, 16, 8, 8, 16};
    const int Cc[5]  = {64, 128, 256, 128, 2};
    const int HCc[5] = {512, 2048, 2048, 1024, 32};
    const int KAc[5] = {512, 1024, 1024, 2048, 2048};  // L0 KA = 8*64
    const int btOff[5] = {0, 32768, 163840, 425984, 0};
    const int weOff[5] = {0, 1024, 3072, 5120, 9216};

    int tid = threadIdx.x;

    if (b < 168) {
        // ---- LDS-tiled transpose, one (layer, head, 64x64 tile) per block --
        int lyr, tloc;
        if (b < 8)        { lyr = 0; tloc = b; }
        else if (b < 40)  { lyr = 1; tloc = b - 8; }
        else if (b < 104) { lyr = 2; tloc = b - 40; }
        else              { lyr = 3; tloc = b - 104; }
        const int ktl[4] = {1, 1, 2, 4};   // ceil(Kp/64)
        const int mtl[4] = {1, 2, 4, 2};   // ceil(C/64)
        int kt = ktl[lyr], mt = mtl[lyr];
        int per_h = kt * mt;
        int h = tloc / per_h, r = tloc - h * per_h;
        int ki = r % kt, mi = r / kt;
        int k0 = ki * 64, m0 = mi * 64;
        int K = Kc[lyr], Kp = Kpc[lyr], C = Cc[lyr], HC = HCc[lyr], KA = KAc[lyr];
        const float* W;
        if (lyr == 0) W = W0; else if (lyr == 1) W = W1;
        else if (lyr == 2) W = W2; else W = W3;

        __shared__ float tile[64][65];
        int c = tid & 63, rg = tid >> 6;
        for (int r2 = rg; r2 < 64; r2 += 4) {       // coalesced 256B reads
            int k = k0 + r2, m = m0 + c;
            float v = (k < K && m < C) ? W[(size_t)k * HC + h * C + m] : 0.f;
            tile[r2][c] = v;
        }
        __syncthreads();
        unsigned short* bp = bt + btOff[lyr];
        for (int mr = rg; mr < 64; mr += 4) {       // coalesced 128B fp16 writes
            int m = m0 + mr, k = k0 + c;
            if (m < C && k < Kp)
                bp[(size_t)m * KA + h * Kp + k] =
                    __half_as_ushort(__float2half(tile[c][mr]));
        }
    } else if (b < 200) {
        // ---- wcomb for layer 4: 8192 outputs (128 x 64) ----
        int u = (b - 168) * 256 + tid;
        int k = u >> 6, o = u & 63;
        float s;
        if (o < 32) {                       // es/ed weights
            int h = (o < 16) ? o : o - 16;
            const float* av = ((o < 16) ? as4 : ad4) + h * 2;
            s = W4[k * 32 + h * 2 + 0] * av[0] + W4[k * 32 + h * 2 + 1] * av[1];
        } else {                            // y projection: raw W4 column
            s = W4[k * 32 + (o - 32)];
        }
        wcomb[u] = s;
    } else {
        // ---- wesed dots: sizes {1024,2048,2048,4096,4096} -> 52 blocks ----
        int wb = b - 200;
        int lyr, u0;
        if (wb < 4)       { lyr = 0; u0 = wb * 256; }
        else if (wb < 12) { lyr = 1; u0 = (wb - 4) * 256; }
        else if (wb < 20) { lyr = 2; u0 = (wb - 12) * 256; }
        else if (wb < 36) { lyr = 3; u0 = (wb - 20) * 256; }
        else              { lyr = 4; u0 = (wb - 36) * 256; }
        int u = u0 + tid;
        int K = Kc[lyr], Kp = Kpc[lyr], H = Hc[lyr], C = Cc[lyr], HC = HCc[lyr];
        int H2 = 2 * H;
        if (u < Kp * H2) {
            int k = u / H2, o = u - k * H2;
            float s = 0.f;
            if (k < K) {
                int h = (o < H) ? o : o - H;
                const float *W, *as_, *ad_;
                if (lyr == 0)      { W = W0; as_ = as0; ad_ = ad0; }
                else if (lyr == 1) { W = W1; as_ = as1; ad_ = ad1; }
                else if (lyr == 2) { W = W2; as_ = as2; ad_ = ad2; }
                else if (lyr == 3) { W = W3; as_ = as3; ad_ = ad3; }
                else               { W = W4; as_ = as4; ad_ = ad4; }
                const float* av = ((o < H) ? as_ : ad_) + h * C;
                const float* wp = W + (size_t)k * HC + h * C;
#pragma unroll 4
                for (int c2 = 0; c2 < C; ++c2) s += wp[c2] * av[c2];
            }
            wesed[weOff[lyr] + u] = s;
        }
    }
}

// ---------------- prologue combo kernels ------------------------------------
// comboA: [0,252) prep_all ; [252,508) conv1 ; [508, 508+CB) count_dst
__global__ __launch_bounds__(256) void comboA(
        const float* __restrict__ cf, const float* __restrict__ w0,
        const float* __restrict__ b0, float* __restrict__ c1p,
        const int* __restrict__ ei, int* __restrict__ cnt, int E, int N,
        const float* W0, const float* W1, const float* W2, const float* W3,
        const float* W4,
        const float* as0, const float* as1, const float* as2, const float* as3,
        const float* as4,
        const float* ad0, const float* ad1, const float* ad2, const float* ad3,
        const float* ad4,
        unsigned short* bt, float* wesed, float* wcomb) {
    int b = blockIdx.x;
    if (b < 252)
        prep_body(b, W0, W1, W2, W3, W4, as0, as1, as2, as3, as4,
                  ad0, ad1, ad2, ad3, ad4, bt, wesed, wcomb);
    else if (b < 508) {
        int blk = b - 252;
        conv_first_body(cf, w0, b0, c1p, blk % 16, blk / 16);
    } else
        count_body(ei, cnt, b - 508, E, N);
}

// comboB: block 0 scan ; blocks [1, 513) conv2 (CIN=16, 16x32)
__global__ __launch_bounds__(256) void comboB(const int* __restrict__ cnt,
                                              int* __restrict__ indptr,
                                              int* __restrict__ cursor, int n, int total,
                                              const float* __restrict__ c1p,
                                              const float* __restrict__ w1,
                                              const float* __restrict__ b1,
                                              float* __restrict__ c2p) {
    int b = blockIdx.x;
    if (b == 0) scan_body(cnt, indptr, cursor, n, total);
    else {
        int blk = b - 1;
        conv_pad_body<16>(c1p, w1, b1, c2p, blk % 16, blk / 16);
    }
}

// comboC: blocks [0,CB) scatter ; blocks [CB, CB+1024) conv3 (CIN=32, 16x64)
__global__ __launch_bounds__(256) void comboC(const int* __restrict__ ei,
                                              int* __restrict__ cursor,
                                              int* __restrict__ col, int E, int N, int CB,
                                              const float* __restrict__ c2p,
                                              const float* __restrict__ w2,
                                              const float* __restrict__ b2,
                                              float* __restrict__ c3p) {
    int b = blockIdx.x;
    if (b < CB) scatter_body(ei, cursor, col, b, E, N);
    else {
        int blk = b - CB;
        conv_pad_body<32>(c2p, w2, b2, c3p, blk % 16, blk / 16);
    }
}

// -------- fused attn+gather via LDS broadcast, pipelined (layers 0-3) -------
// TWO: esed is split into two K-half partials (esed, esed2) -> sum at load.
template <int H, int KP, int CH, int NPB, int TWO>
__global__ __launch_bounds__(NPB * (KP / CH)) void gat_fused_lds(
        const __half* __restrict__ hinf, const float* __restrict__ esed,
        const float* __restrict__ esed2,
        const int* __restrict__ indptr, const int* __restrict__ col,
        __half* __restrict__ g, int N) {
    const int TPN = KP / CH;
    const int EC  = TPN / H;
    const int H2  = 2 * H;
    __shared__ float lds_p[NPB][2][TPN];
    int sub = threadIdx.x / TPN;
    int j   = threadIdx.x % TPN;
    int n = blockIdx.x * NPB + sub;
    if (n >= N) return;
    int e_my = j / H, h_my = j % H;
    int c0 = j * CH;
    float edv = esed[n * H2 + H + h_my];
    if constexpr (TWO) edv += esed2[n * H2 + H + h_my];

    float acc[H][CH];
#pragma unroll
    for (int h = 0; h < H; ++h)
#pragma unroll
        for (int t = 0; t < CH; ++t) acc[h][t] = 0.f;
    float zloc = 0.f;

    int beg = indptr[n], deg = indptr[n + 1] - beg;

    // prologue: p for chunk 0
    float p = 0.f;
    if (e_my < deg) {
        int srcm = col[beg + e_my];
        float es0 = esed[srcm * H2 + h_my];
        if constexpr (TWO) es0 += esed2[srcm * H2 + h_my];
        p = expf(lrelu02(es0 + edv));
    }
    int buf = 0;
    for (int base = 0; base < deg; base += EC) {
        zloc += p;
        lds_p[sub][buf][j] = p;
        __builtin_amdgcn_wave_barrier();
        // issue next chunk's attention loads (exp after phase B)
        int ce = base + EC + e_my;
        bool vnext = (ce < deg);
        float esv = 0.f;
        if (vnext) {
            int srcm = col[beg + ce];
            esv = esed[srcm * H2 + h_my];
            if constexpr (TWO) esv += esed2[srcm * H2 + h_my];
        }
        // phase B: pipelined gather with LDS-broadcast alphas
#pragma unroll
        for (int e = 0; e < EC; ++e) {
            int idx = base + e;
            if (idx < deg) {                  // uniform within node group
                int src = col[beg + idx];
                float f[CH];
                if (CH == 2) {
                    __half2 hv = *(const __half2*)(hinf + (size_t)src * KP + c0);
                    float2 ff = __half22float2(hv);
                    f[0] = ff.x; f[1] = ff.y;
                } else {
                    half4v hv = *(const half4v*)(hinf + (size_t)src * KP + c0);
                    f[0] = (float)hv[0]; f[1] = (float)hv[1];
                    f[2] = (float)hv[2]; f[3] = (float)hv[3];
                }
                const float4* ap = (const float4*)&lds_p[sub][buf][e * H];
#pragma unroll
                for (int q4 = 0; q4 < H / 4; ++q4) {
                    float4 a4 = ap[q4];
#pragma unroll
                    for (int t = 0; t < CH; ++t) {
                        acc[4 * q4 + 0][t] += a4.x * f[t];
                        acc[4 * q4 + 1][t] += a4.y * f[t];
                        acc[4 * q4 + 2][t] += a4.z * f[t];
                        acc[4 * q4 + 3][t] += a4.w * f[t];
                    }
                }
            }
        }
        p = vnext ? expf(lrelu02(esv + edv)) : 0.f;
        buf ^= 1;
    }

    // z: reduce across the EC lanes of each head class
#pragma unroll
    for (int off = H; off < TPN; off <<= 1)
        zloc += __shfl_xor(zloc, off, TPN);
    float zinv_my = (1.f / H) / (zloc + 1e-16f);

    __half* gp = g + (size_t)n * (H * KP) + c0;
#pragma unroll
    for (int h = 0; h < H; ++h) {
        float zf = __shfl(zinv_my, h, TPN);   // lane class h holds z for head h
        if (CH == 2) {
            *(__half2*)(gp + h * KP) =
                __floats2half2_rn(acc[h][0] * zf, acc[h][1] * zf);
        } else {
            __half2 lo = __floats2half2_rn(acc[h][0] * zf, acc[h][1] * zf);
            __half2 hi = __floats2half2_rn(acc[h][2] * zf, acc[h][3] * zf);
            union { __half2 h2[2]; float2 f2; } u;
            u.h2[0] = lo; u.h2[1] = hi;
            *(float2*)(gp + h * KP) = u.f2;
        }
    }
}

// -------- layer 4: fused attention + projected gather + output --------------
template <int NPB>
__global__ __launch_bounds__(NPB * 32) void final_attn(
        const float* __restrict__ eyp, const int* __restrict__ indptr,
        const int* __restrict__ col, const float* __restrict__ b5,
        const unsigned* __restrict__ masks, const float* __restrict__ x,
        float* __restrict__ outp, int N) {
    int sub = threadIdx.x >> 5;
    int j   = threadIdx.x & 31;
    int n = blockIdx.x * NPB + sub;
    if (n >= N) return;
    int h = j >> 1;
    float edv = eyp[(size_t)n * 64 + 16 + h];
    int beg = indptr[n], end = indptr[n + 1];
    float z = 0.f, a = 0.f;
    int i = beg;
    for (; i + 1 < end; i += 2) {
        int s0 = col[i], s1 = col[i + 1];
        const float* r0 = eyp + (size_t)s0 * 64;
        const float* r1 = eyp + (size_t)s1 * 64;
        float es0 = r0[h], y0 = r0[32 + j];
        float es1 = r1[h], y1 = r1[32 + j];
        float p0 = expf(lrelu02(es0 + edv));
        float p1 = expf(lrelu02(es1 + edv));
        z += p0; a += p0 * y0;
        z += p1; a += p1 * y1;
    }
    for (; i < end; ++i) {
        const float* r = eyp + (size_t)col[i] * 64;
        float p = expf(lrelu02(r[h] + edv));
        z += p; a += p * r[32 + j];
    }
    float zf = (1.f / 16.f) / (z + 1e-16f);
    float val = a * zf;
#pragma unroll
    for (int off = 2; off <= 16; off <<= 1) val += __shfl_xor(val, off, 32);
    float other = __shfl_xor(val, 1, 32);        // opposite parity's sum
    if (j == 0) {
        unsigned mk = masks[n];
        float v0 = x[n * 10 + 0] + selu_f(val + b5[0]);
        float v1 = x[n * 10 + 1] + selu_f(other + b5[1]);
        if (mk & 2u) v0 = 0.f; else if (mk & 1u) v0 = 1.f;
        if (mk & 8u) v1 = 1.f; else if (mk & 4u) v1 = 0.f;
        outp[n * 2 + 0] = v0;
        outp[n * 2 + 1] = v1;
    }
}

// ---------------- unified 16-row LDS-staged f16 MFMA GEMM -------------------
#define LDP 72
template <int CW, int EOUT>
__global__ __launch_bounds__(256) void gemm16(const __half* __restrict__ A,
                                              const unsigned short* __restrict__ Bhi,
                                              const float* __restrict__ bias,
                                              const unsigned* __restrict__ masks,
                                              __half* __restrict__ O16,
                                              const float* __restrict__ wnext,
                                              float* __restrict__ eout,
                                              int N, int K, int M) {
    const int JT = CW / 64;                 // 1 or 2 col-tiles of 16 per wave
    const int BR = CW / 32;                 // B rows per staging thread (2/4)
    __shared__ __half lA[16 * LDP], lB[CW * LDP];
    __shared__ float vt[EOUT ? 16 : 1][EOUT ? (CW + 4) : 1];
    int tid = threadIdx.x;
    int wave = tid >> 6, lane = tid & 63;
    int ln16 = lane & 15, q = lane >> 4;
    int row0 = blockIdx.x * 16;
    int col0 = blockIdx.y * CW;
    int wc = wave * (CW / 4);

    int arow = tid >> 3;                    // 0..31
    int ac   = (tid & 7) * 8;               // col offset in halves
    const __half* Bp = (const __half*)Bhi;
    const __half* ap = A + (size_t)min(row0 + arow, N - 1) * K + ac;  // tid<128
    const __half* bp[BR];
#pragma unroll
    for (int i = 0; i < BR; ++i)
        bp[i] = Bp + (size_t)(col0 + arow + 32 * i) * K + ac;

    half8 ra;
    if (tid < 128) ra = *(const half8*)(ap);
    half8 rb[BR];
#pragma unroll
    for (int i = 0; i < BR; ++i) rb[i] = *(const half8*)(bp[i]);

    f32x4 acc[JT];
#pragma unroll
    for (int j = 0; j < JT; ++j) acc[j] = (f32x4){0.f, 0.f, 0.f, 0.f};

    for (int kc = 0; kc < K; kc += 64) {
        __syncthreads();
        if (tid < 128) *(half8*)(lA + arow * LDP + ac) = ra;
#pragma unroll
        for (int i = 0; i < BR; ++i)
            *(half8*)(lB + (arow + 32 * i) * LDP + ac) = rb[i];
        __syncthreads();
        int kn = kc + 64;
        if (kn < K) {
            if (tid < 128) ra = *(const half8*)(ap + kn);
#pragma unroll
            for (int i = 0; i < BR; ++i) rb[i] = *(const half8*)(bp[i] + kn);
        }
#pragma unroll
        for (int kk = 0; kk < 2; ++kk) {
            half8 af = *(const half8*)(lA + ln16 * LDP + kk * 32 + q * 8);
#pragma unroll
            for (int j = 0; j < JT; ++j) {
                half8 bf = *(const half8*)(lB + (wc + j * 16 + ln16) * LDP + kk * 32 + q * 8);
                acc[j] = __builtin_amdgcn_mfma_f32_16x16x32_f16(af, bf, acc[j], 0, 0, 0);
            }
        }
    }

#pragma unroll
    for (int j = 0; j < JT; ++j) {
        int cc = col0 + wc + j * 16 + ln16;
        float bv = bias[cc];
#pragma unroll
        for (int r = 0; r < 4; ++r) {
            int rr = row0 + q * 4 + r;
            float v = selu_f(acc[j][r] + bv);
            if (cc < 2 && rr < N) {
                unsigned mk = masks[rr];
                if (cc == 0) { if (mk & 2u) v = 0.f; else if (mk & 1u) v = 1.f; }
                else         { if (mk & 8u) v = 1.f; else if (mk & 4u) v = 0.f; }
            }
            __half hv = __float2half(v);
            if (rr < N) O16[(size_t)rr * M + cc] = hv;
            if constexpr (EOUT > 0)
                vt[q * 4 + r][wc + j * 16 + ln16] = __half2float(hv);
        }
    }

    if constexpr (EOUT > 0) {
        __syncthreads();
        const int NG = 256 / EOUT;          // rows in parallel (16/8/4)
        const int NI = 16 / NG;             // rows per thread (1/2/4)
        int o = tid & (EOUT - 1);
        int ngrp = tid / EOUT;
        const float* wp = wnext + (size_t)col0 * EOUT;
        float* ep = eout + (size_t)blockIdx.y * N * EOUT;
        float s[NI];
#pragma unroll
        for (int i = 0; i < NI; ++i) s[i] = 0.f;
        for (int k = 0; k < CW; ++k) {
            float wk = wp[k * EOUT + o];
#pragma unroll
            for (int i = 0; i < NI; ++i)
                s[i] += vt[ngrp + NG * i][k] * wk;
        }
#pragma unroll
        for (int i = 0; i < NI; ++i) {
            int n = row0 + ngrp + NG * i;
            if (n < N) ep[(size_t)n * EOUT + o] = s[i];
        }
    }
}

// ---------------------------------------------------------------------------
extern "C" void kernel_launch(void* const* d_in, const int* in_sizes, int n_in,
                              void* d_out, int out_size, void* d_ws, size_t ws_size,
                              hipStream_t stream) {
    const float* x   = (const float*)d_in[0];
    const int*   ei  = (const int*)d_in[1];
    const float* cf  = (const float*)d_in[2];
    const float* cw[4] = {(const float*)d_in[3], (const float*)d_in[5],
                          (const float*)d_in[7], (const float*)d_in[9]};
    const float* cb[4] = {(const float*)d_in[4], (const float*)d_in[6],
                          (const float*)d_in[8], (const float*)d_in[10]};
    const float* gw[5], *gas[5], *gad[5], *gb[5];
    for (int i = 0; i < 5; ++i) {
        gw[i]  = (const float*)d_in[11 + 4 * i];
        gas[i] = (const float*)d_in[12 + 4 * i];
        gad[i] = (const float*)d_in[13 + 4 * i];
        gb[i]  = (const float*)d_in[14 + 4 * i];
    }
    const int N = in_sizes[0] / 10;        // 10000
    const int E = in_sizes[1] / 2;         // 160000
    const int EN = E + N;
    const int CB = (EN + 255) / 256;       // 665 CSR blocks

    // ---- workspace carve-up (zero range: c1p..c3p borders + cnt + gfeat) ---
    char* base = (char*)d_ws;
    size_t off = 0;
    auto alloc = [&](size_t bytes) -> char* {
        char* p = base + off;
        off = (off + bytes + 255) & ~(size_t)255;
        return p;
    };
    float* c1p   = (float*)alloc((size_t)16 * PSZ * 4);
    float* c2p   = (float*)alloc((size_t)32 * PSZ * 4);
    float* c3p   = (float*)alloc((size_t)64 * PSZ * 4);
    int*   cnt   = (int*)alloc((size_t)N * 4);
    float* gfeat = (float*)alloc(24 * 4);
    size_t zlen = off;                       // everything above is zeroed
    __half* hA16 = (__half*)alloc((size_t)N * 256 * 2);
    __half* hB16 = (__half*)alloc((size_t)N * 256 * 2);
    __half* g    = (__half*)alloc((size_t)N * 2048 * 2);
    float* esed  = (float*)alloc((size_t)N * 32 * 4);        // also 2x N*16 partials
    float* eyp   = (float*)alloc((size_t)N * 64 * 4);        // L4 [es|ed|y]
    float* wesed = (float*)alloc((size_t)13312 * 4);         // layers 0-4
    float* wcomb = (float*)alloc((size_t)8192 * 4);          // L4 combined weights
    unsigned short* bt = (unsigned short*)alloc((size_t)688128 * 2);  // 4 GEMM layers
    unsigned* masks = (unsigned*)alloc((size_t)N * 4);
    int* indptr = (int*)alloc((size_t)(N + 1) * 4);
    int* cursor = (int*)alloc((size_t)N * 4);
    int* col    = (int*)alloc((size_t)EN * 4);
    (void)ws_size; // ~70 MB

    // ---- single memset: conv borders + cnt + gfeat ----
    hipMemsetAsync(c1p, 0, zlen, stream);

    // ---- prologue combos: prep || CNN chain || CSR chain ----
    comboA<<<508 + CB, 256, 0, stream>>>(cf, cw[0], cb[0], c1p, ei, cnt, E, N,
                                         gw[0], gw[1], gw[2], gw[3], gw[4],
                                         gas[0], gas[1], gas[2], gas[3], gas[4],
                                         gad[0], gad[1], gad[2], gad[3], gad[4],
                                         bt, wesed, wcomb);
    comboB<<<1 + 512, 256, 0, stream>>>(cnt, indptr, cursor, N, EN,
                                        c1p, cw[1], cb[1], c2p);
    comboC<<<CB + 1024, 256, 0, stream>>>(ei, cursor, col, E, N, CB,
                                          c2p, cw[2], cb[2], c3p);
    conv4_pool<<<dim3(16, 24), 256, 0, stream>>>(c3p, cw[3], cb[3], gfeat);

    // ---- h0 (padded to 64, fp16) + masks + fused L0 esed ----
    build_h0<<<(N + 255) / 256, 256, 0, stream>>>(x, gfeat, wesed + 0, hA16, masks,
                                                  esed, N);

    // ---- GAT layers (all esed/eyp hand-offs fused into producers) ----
    int gx16 = (N + 15) / 16;   // 625

    // L0: Kp=64 H=8 C=64 KA=512 ; esed came from build_h0
    gat_fused_lds<8, 64, 4, 16, 0><<<(N + 15) / 16, 256, 0, stream>>>(
        hA16, esed, nullptr, indptr, col, g, N);
    gemm16<64, 32><<<dim3(gx16, 1), 256, 0, stream>>>(g, bt + 0, gb[0], masks, hB16,
                                                      wesed + 1024, esed, N, 512, 64);

    // L1: Kp=64 H=16 C=128 KA=1024 ; esed (H2=32) from L0 gemm
    gat_fused_lds<16, 64, 2, 8, 0><<<(N + 7) / 8, 256, 0, stream>>>(
        hB16, esed, nullptr, indptr, col, g, N);
    gemm16<128, 16><<<dim3(gx16, 1), 256, 0, stream>>>(g, bt + 32768, gb[1], masks, hA16,
                                                       wesed + 3072, esed, N, 1024, 128);

    // L2: Kp=128 H=8 C=256 KA=1024 ; esed (H2=16) from L1 gemm; L3's esed
    // produced as two K-half partials by the two col-blocks (grid.y=2)
    gat_fused_lds<8, 128, 4, 8, 0><<<(N + 7) / 8, 256, 0, stream>>>(
        hA16, esed, nullptr, indptr, col, g, N);
    gemm16<128, 16><<<dim3(gx16, 2), 256, 0, stream>>>(g, bt + 163840, gb[2], masks, hB16,
                                                       wesed + 5120, esed, N, 1024, 256);

    // L3: Kp=256 H=8 C=128 KA=2048 ; esed = partial A + partial B
    gat_fused_lds<8, 256, 4, 4, 1><<<(N + 3) / 4, 256, 0, stream>>>(
        hB16, esed, esed + (size_t)N * 16, indptr, col, g, N);
    gemm16<128, 64><<<dim3(gx16, 1), 256, 0, stream>>>(g, bt + 425984, gb[3], masks, hA16,
                                                       wcomb, eyp, N, 2048, 128);

    // L4: project-first fused final layer
    final_attn<8><<<(N + 7) / 8, 256, 0, stream>>>(eyp, indptr, col, gb[4],
                                                   masks, x, (float*)d_out, N);
}